// Round 1
// baseline (563.736 us; speedup 1.0000x reference)
//
#include <hip/hip_runtime.h>
#include <math.h>

#define N_NODES 50000
#define N_EDGES 800000
#define N_GRAPHS 64
#define D_IN 128
#define HID 64
#define OUT_C 32
#define NEG 0.2f
#define BN_EPS 1e-5f

// ---------------- CSR construction ----------------

__global__ void k_hist(const int* __restrict__ dst, int* __restrict__ counts) {
    int e = blockIdx.x * blockDim.x + threadIdx.x;
    if (e < N_EDGES) atomicAdd(&counts[dst[e]], 1);
}

// single-block hierarchical scan over counts -> exclusive row_start[N+1]
__global__ void k_scan(const int* __restrict__ counts, int* __restrict__ row_start) {
    __shared__ int wsum[16];
    __shared__ int carry_s;
    int tid = threadIdx.x;
    int lane = tid & 63;
    int wid = tid >> 6;
    if (tid == 0) { carry_s = 0; row_start[0] = 0; }
    __syncthreads();
    for (int base = 0; base < N_NODES; base += 1024) {
        int i = base + tid;
        int v = (i < N_NODES) ? counts[i] : 0;
        int incl = v;
        #pragma unroll
        for (int off = 1; off < 64; off <<= 1) {
            int t = __shfl_up(incl, off, 64);
            if (lane >= off) incl += t;
        }
        if (lane == 63) wsum[wid] = incl;
        __syncthreads();
        if (wid == 0 && lane < 16) {
            int w = wsum[lane];
            #pragma unroll
            for (int off = 1; off < 16; off <<= 1) {
                int t = __shfl_up(w, off, 16);
                if ((lane & 15) >= off) w += t;
            }
            wsum[lane] = w;  // inclusive wave totals
        }
        __syncthreads();
        int offs = (wid > 0) ? wsum[wid - 1] : 0;
        int carry = carry_s;
        int inclTotal = incl + offs + carry;
        if (i < N_NODES) row_start[i + 1] = inclTotal;
        __syncthreads();
        if (tid == 1023) carry_s = inclTotal;
        __syncthreads();
    }
}

__global__ void k_fill(const int* __restrict__ src, const int* __restrict__ dst,
                       const int* __restrict__ row_start, int* __restrict__ cursor,
                       int* __restrict__ col) {
    int e = blockIdx.x * blockDim.x + threadIdx.x;
    if (e < N_EDGES) {
        int d = dst[e];
        int pos = atomicAdd(&cursor[d], 1);
        col[row_start[d] + pos] = src[e];
    }
}

// graph start offsets via binary search on sorted batch
__global__ void k_gstart(const int* __restrict__ batch, int* __restrict__ gstart) {
    int g = blockIdx.x * blockDim.x + threadIdx.x;
    if (g > N_GRAPHS) return;
    int lo = 0, hi = N_NODES;
    while (lo < hi) {
        int mid = (lo + hi) >> 1;
        if (batch[mid] < g) lo = mid + 1; else hi = mid;
    }
    gstart[g] = lo;
}

// ---------------- Layer 1: xl1 = x @ W1, es1/ed1 fused ----------------

__global__ void __launch_bounds__(256) k_gemm1(
        const float* __restrict__ x, const float* __restrict__ W1,
        const float* __restrict__ a_src1, const float* __restrict__ a_dst1,
        float* __restrict__ xl1, float* __restrict__ es1, float* __restrict__ ed1) {
    __shared__ float Wl[D_IN * HID];   // 32 KB
    __shared__ float asl[HID], adl[HID];
    int tid = threadIdx.x;
    for (int i = tid; i < D_IN * HID; i += 256) Wl[i] = W1[i];
    if (tid < HID) { asl[tid] = a_src1[tid]; adl[tid] = a_dst1[tid]; }
    __syncthreads();
    int lane = tid & 63, wid = tid >> 6;
    int nwaves = gridDim.x * 4;
    for (int n = blockIdx.x * 4 + wid; n < N_NODES; n += nwaves) {
        float xa = x[n * D_IN + lane];
        float xb = x[n * D_IN + 64 + lane];
        float acc = 0.f;
        #pragma unroll
        for (int k = 0; k < 64; ++k)
            acc = fmaf(__shfl(xa, k, 64), Wl[k * HID + lane], acc);
        #pragma unroll
        for (int k = 0; k < 64; ++k)
            acc = fmaf(__shfl(xb, k, 64), Wl[(64 + k) * HID + lane], acc);
        xl1[n * HID + lane] = acc;
        float ps = acc * asl[lane];
        float pd = acc * adl[lane];
        #pragma unroll
        for (int off = 8; off; off >>= 1) {
            ps += __shfl_xor(ps, off, 16);
            pd += __shfl_xor(pd, off, 16);
        }
        if ((lane & 15) == 0) {
            int h = lane >> 4;
            es1[n * 4 + h] = ps;
            ed1[n * 4 + h] = pd;
        }
    }
}

// ---------------- Layer 1 aggregation: pull, one wave per node ----------------

__global__ void __launch_bounds__(256) k_agg1(
        const float* __restrict__ xl1, const float* __restrict__ es1,
        const float* __restrict__ ed1, const int* __restrict__ row_start,
        const int* __restrict__ col, const float* __restrict__ b1,
        float* __restrict__ h1pre) {
    int wid = threadIdx.x >> 6, lane = threadIdx.x & 63;
    int d = blockIdx.x * 4 + wid;
    if (d >= N_NODES) return;
    int h = lane >> 4;
    float edh = ed1[d * 4 + h];
    // implicit self loop
    float e0 = es1[d * 4 + h] + edh;
    float w0 = __expf(e0 > 0.f ? e0 : NEG * e0);
    float acc = w0 * xl1[d * HID + lane];
    float wsum = w0;
    int js = row_start[d], je = row_start[d + 1];
    for (int j0 = js; j0 < je; j0 += 64) {
        int jj = j0 + lane;
        int sv = (jj < je) ? col[jj] : 0;
        int cnt = min(64, je - j0);
        for (int k = 0; k < cnt; ++k) {
            int s = __shfl(sv, k, 64);
            float e = es1[s * 4 + h] + edh;
            float ww = __expf(e > 0.f ? e : NEG * e);
            acc = fmaf(ww, xl1[s * HID + lane], acc);
            wsum += ww;
        }
    }
    h1pre[d * HID + lane] = acc / wsum + b1[lane];
}

// ---------------- BatchNorm stats (sum, sumsq per channel) ----------------

__global__ void __launch_bounds__(256) k_stats(const float* __restrict__ hpre,
                                               int nch, float* __restrict__ stats) {
    int c = threadIdx.x & (nch - 1);
    int gid = blockIdx.x * blockDim.x + threadIdx.x;
    int r0 = gid / nch;
    int rstride = (gridDim.x * blockDim.x) / nch;
    float s = 0.f, s2 = 0.f;
    for (int n = r0; n < N_NODES; n += rstride) {
        float v = hpre[n * nch + c];
        s += v;
        s2 = fmaf(v, v, s2);
    }
    __shared__ float ls[256], ls2[256];
    ls[threadIdx.x] = s;
    ls2[threadIdx.x] = s2;
    __syncthreads();
    if (threadIdx.x < nch) {
        int rows = 256 / nch;
        float a = 0.f, b = 0.f;
        for (int r = 0; r < rows; ++r) {
            a += ls[r * nch + c];
            b += ls2[r * nch + c];
        }
        atomicAdd(&stats[c], a);
        atomicAdd(&stats[nch + c], b);
    }
}

// ---------------- Layer 2 GEMM: bn1+relu fused, xl2 = h1n @ W2, es2/ed2 ----------------

__global__ void __launch_bounds__(256) k_gemm2(
        const float* __restrict__ h1pre, const float* __restrict__ stats1,
        const float* __restrict__ g1, const float* __restrict__ be1,
        const float* __restrict__ W2, const float* __restrict__ a_src2,
        const float* __restrict__ a_dst2, float* __restrict__ xl2,
        float* __restrict__ es2, float* __restrict__ ed2) {
    __shared__ float Wl[HID * OUT_C];   // 8 KB
    __shared__ float A1[HID], B1[HID], as2[OUT_C], ad2[OUT_C];
    int tid = threadIdx.x;
    for (int i = tid; i < HID * OUT_C; i += 256) Wl[i] = W2[i];
    if (tid < HID) {
        float mu = stats1[tid] * (1.f / N_NODES);
        float var = stats1[HID + tid] * (1.f / N_NODES) - mu * mu;
        float sc = g1[tid] * rsqrtf(var + BN_EPS);
        A1[tid] = sc;
        B1[tid] = be1[tid] - mu * sc;
    }
    if (tid < OUT_C) { as2[tid] = a_src2[tid]; ad2[tid] = a_dst2[tid]; }
    __syncthreads();
    int lane = tid & 63, wid = tid >> 6;
    int nwaves = gridDim.x * 4;
    for (int n = blockIdx.x * 4 + wid; n < N_NODES; n += nwaves) {
        float v = h1pre[n * HID + lane];
        v = fmaf(v, A1[lane], B1[lane]);
        v = v > 0.f ? v : 0.f;          // relu
        int c = lane & 31;
        float acc = 0.f;
        #pragma unroll
        for (int k = 0; k < HID; ++k)
            acc = fmaf(__shfl(v, k, 64), Wl[k * OUT_C + c], acc);
        if (lane < 32) {
            xl2[n * OUT_C + c] = acc;
            float ps = acc * as2[c];
            float pd = acc * ad2[c];
            #pragma unroll
            for (int off = 16; off; off >>= 1) {
                ps += __shfl_xor(ps, off, 32);
                pd += __shfl_xor(pd, off, 32);
            }
            if (c == 0) { es2[n] = ps; ed2[n] = pd; }
        }
    }
}

// ---------------- Layer 2 aggregation: 2 nodes per wave ----------------

__global__ void __launch_bounds__(256) k_agg2(
        const float* __restrict__ xl2, const float* __restrict__ es2,
        const float* __restrict__ ed2, const int* __restrict__ row_start,
        const int* __restrict__ col, const float* __restrict__ b2,
        float* __restrict__ h2pre) {
    int lane = threadIdx.x & 63;
    int half = lane >> 5;
    int c = lane & 31;
    int wid = threadIdx.x >> 6;
    int d = (blockIdx.x * 4 + wid) * 2 + half;
    if (d >= N_NODES) return;
    float edh = ed2[d];
    float e0 = es2[d] + edh;
    float w0 = __expf(e0 > 0.f ? e0 : NEG * e0);
    float acc = w0 * xl2[d * OUT_C + c];
    float wsum = w0;
    int js = row_start[d], je = row_start[d + 1];
    for (int j0 = js; j0 < je; j0 += 32) {
        int jj = j0 + c;
        int sv = (jj < je) ? col[jj] : 0;
        int cnt = min(32, je - j0);
        for (int k = 0; k < cnt; ++k) {
            int s = __shfl(sv, k, 32);   // broadcast within the 32-lane half
            float e = es2[s] + edh;
            float ww = __expf(e > 0.f ? e : NEG * e);
            acc = fmaf(ww, xl2[s * OUT_C + c], acc);
            wsum += ww;
        }
    }
    h2pre[d * OUT_C + c] = acc / wsum + b2[c];
}

// ---------------- BN2 apply -> node_emb (first output chunk) ----------------

__global__ void __launch_bounds__(256) k_bn2(
        const float* __restrict__ h2pre, const float* __restrict__ stats2,
        const float* __restrict__ g2, const float* __restrict__ be2,
        float* __restrict__ out) {
    __shared__ float A2[OUT_C], B2[OUT_C];
    if (threadIdx.x < OUT_C) {
        int cc = threadIdx.x;
        float mu = stats2[cc] * (1.f / N_NODES);
        float var = stats2[OUT_C + cc] * (1.f / N_NODES) - mu * mu;
        float sc = g2[cc] * rsqrtf(var + BN_EPS);
        A2[cc] = sc;
        B2[cc] = be2[cc] - mu * sc;
    }
    __syncthreads();
    int i = blockIdx.x * blockDim.x + threadIdx.x;
    int stride = gridDim.x * blockDim.x;
    for (; i < N_NODES * OUT_C; i += stride) {
        int cc = i & 31;
        out[i] = fmaf(h2pre[i], A2[cc], B2[cc]);
    }
}

// ---------------- Pool: per-graph mean & max over node_emb ----------------

__global__ void __launch_bounds__(256) k_pool(
        const float* __restrict__ node_emb, const int* __restrict__ gstart,
        float* __restrict__ gfeat) {
    int g = blockIdx.x;
    int s = gstart[g], e = gstart[g + 1];
    int c = threadIdx.x & 31, r = threadIdx.x >> 5;   // 8 row-lanes
    float sum = 0.f, mx = -INFINITY;
    for (int n = s + r; n < e; n += 8) {
        float v = node_emb[n * OUT_C + c];
        sum += v;
        mx = fmaxf(mx, v);
    }
    __shared__ float lsum[256], lmax[256];
    lsum[threadIdx.x] = sum;
    lmax[threadIdx.x] = mx;
    __syncthreads();
    if (threadIdx.x < 32) {
        float ts = 0.f, tm = -INFINITY;
        for (int rr = 0; rr < 8; ++rr) {
            ts += lsum[rr * 32 + c];
            tm = fmaxf(tm, lmax[rr * 32 + c]);
        }
        int cnt = e - s;
        float mean = (cnt > 0) ? ts / (float)cnt : 0.f;
        float gm = (cnt > 0) ? tm : 0.f;     // finite whenever cnt>0
        gfeat[g * 64 + c] = mean;
        gfeat[g * 64 + 32 + c] = gm;
    }
}

// ---------------- MLP head -> graph_emb (second output chunk) ----------------

__global__ void __launch_bounds__(256) k_mlp(
        const float* __restrict__ gfeat,
        const float* __restrict__ fcW1, const float* __restrict__ fcb1,
        const float* __restrict__ fcW2, const float* __restrict__ fcb2,
        float* __restrict__ out) {
    __shared__ float gf[N_GRAPHS * 64];     // 16 KB
    __shared__ float t1[N_GRAPHS * OUT_C];  // 8 KB
    int tid = threadIdx.x;
    for (int i = tid; i < N_GRAPHS * 64; i += 256) gf[i] = gfeat[i];
    __syncthreads();
    for (int i = tid; i < N_GRAPHS * OUT_C; i += 256) {
        int g = i >> 5, j = i & 31;
        float a = fcb1[j];
        for (int k = 0; k < 64; ++k) a = fmaf(gf[g * 64 + k], fcW1[k * OUT_C + j], a);
        t1[i] = a > 0.f ? a : 0.f;
    }
    __syncthreads();
    for (int i = tid; i < N_GRAPHS * OUT_C; i += 256) {
        int g = i >> 5, oc = i & 31;
        float a = fcb2[oc];
        for (int k = 0; k < OUT_C; ++k) a = fmaf(t1[g * OUT_C + k], fcW2[k * OUT_C + oc], a);
        out[(size_t)N_NODES * OUT_C + g * OUT_C + oc] = a;
    }
}

// ---------------- launch ----------------

extern "C" void kernel_launch(void* const* d_in, const int* in_sizes, int n_in,
                              void* d_out, int out_size, void* d_ws, size_t ws_size,
                              hipStream_t stream) {
    (void)in_sizes; (void)n_in; (void)out_size; (void)ws_size;
    const float* x      = (const float*)d_in[0];
    const int*   ei     = (const int*)d_in[1];
    const int*   batch  = (const int*)d_in[2];
    const float* W1     = (const float*)d_in[3];
    const float* a_src1 = (const float*)d_in[4];
    const float* a_dst1 = (const float*)d_in[5];
    const float* b1     = (const float*)d_in[6];
    const float* g1     = (const float*)d_in[7];
    const float* be1    = (const float*)d_in[8];
    const float* W2     = (const float*)d_in[9];
    const float* a_src2 = (const float*)d_in[10];
    const float* a_dst2 = (const float*)d_in[11];
    const float* b2     = (const float*)d_in[12];
    const float* g2     = (const float*)d_in[13];
    const float* be2    = (const float*)d_in[14];
    const float* fcW1   = (const float*)d_in[15];
    const float* fcb1   = (const float*)d_in[16];
    const float* fcW2   = (const float*)d_in[17];
    const float* fcb2   = (const float*)d_in[18];
    const int* srcv = ei;
    const int* dstv = ei + N_EDGES;
    float* out = (float*)d_out;

    char* w = (char*)d_ws;
    size_t o = 0;
    int*   counts    = (int*)(w + o);   o += (size_t)N_NODES * 4;
    int*   cursor    = (int*)(w + o);   o += (size_t)N_NODES * 4;
    float* stats1    = (float*)(w + o); o += 128 * 4;
    float* stats2    = (float*)(w + o); o += 64 * 4;
    size_t zero_bytes = o;                       // everything above must start at 0
    int*   row_start = (int*)(w + o);   o += (size_t)(N_NODES + 1) * 4;
    int*   gst       = (int*)(w + o);   o += 66 * 4;
    int*   col       = (int*)(w + o);   o += (size_t)N_EDGES * 4;
    float* xl1       = (float*)(w + o); o += (size_t)N_NODES * HID * 4;
    float* es1       = (float*)(w + o); o += (size_t)N_NODES * 4 * 4;
    float* ed1       = (float*)(w + o); o += (size_t)N_NODES * 4 * 4;
    float* h1pre     = (float*)(w + o); o += (size_t)N_NODES * HID * 4;
    float* gfeat     = (float*)(w + o); o += 64 * 64 * 4;
    // aliases (lifetimes disjoint):
    float* xl2   = xl1;                          // N*32 <= N*64; xl1 dead after k_agg1
    float* es2   = xl1 + (size_t)N_NODES * OUT_C;
    float* ed2   = es2 + N_NODES;
    float* h2pre = h1pre;                        // h1pre dead after k_gemm2/k_stats

    hipMemsetAsync(d_ws, 0, zero_bytes, stream);
    k_hist <<<(N_EDGES + 255) / 256, 256, 0, stream>>>(dstv, counts);
    k_scan <<<1, 1024, 0, stream>>>(counts, row_start);
    k_fill <<<(N_EDGES + 255) / 256, 256, 0, stream>>>(srcv, dstv, row_start, cursor, col);
    k_gstart<<<1, 128, 0, stream>>>(batch, gst);
    k_gemm1<<<256, 256, 0, stream>>>(x, W1, a_src1, a_dst1, xl1, es1, ed1);
    k_agg1 <<<(N_NODES + 3) / 4, 256, 0, stream>>>(xl1, es1, ed1, row_start, col, b1, h1pre);
    k_stats<<<256, 256, 0, stream>>>(h1pre, HID, stats1);
    k_gemm2<<<256, 256, 0, stream>>>(h1pre, stats1, g1, be1, W2, a_src2, a_dst2, xl2, es2, ed2);
    k_agg2 <<<(N_NODES + 7) / 8, 256, 0, stream>>>(xl2, es2, ed2, row_start, col, b2, h2pre);
    k_stats<<<256, 256, 0, stream>>>(h2pre, OUT_C, stats2);
    k_bn2  <<<512, 256, 0, stream>>>(h2pre, stats2, g2, be2, out);
    k_pool <<<N_GRAPHS, 256, 0, stream>>>(out, gst, gfeat);
    k_mlp  <<<1, 256, 0, stream>>>(gfeat, fcW1, fcb1, fcW2, fcb2, out);
}

// Round 2
// 390.169 us; speedup vs baseline: 1.4449x; 1.4449x over previous
//
#include <hip/hip_runtime.h>
#include <math.h>

#define N_NODES 50000
#define N_EDGES 800000
#define N_GRAPHS 64
#define D_IN 128
#define HID 64
#define OUT_C 32
#define NEG 0.2f
#define BN_EPS 1e-5f
#define N_TILES 3125   // N_NODES / 16

typedef __attribute__((ext_vector_type(8))) short short8;
typedef __attribute__((ext_vector_type(4))) float f32x4;

static __device__ inline unsigned short f2bf(float f) {
    unsigned u = __float_as_uint(f);
    u += 0x7FFF + ((u >> 16) & 1);
    return (unsigned short)(u >> 16);
}

// ---------------- CSR construction ----------------

__global__ void k_hist(const int* __restrict__ dst, int* __restrict__ counts) {
    int e = blockIdx.x * blockDim.x + threadIdx.x;
    if (e < N_EDGES) atomicAdd(&counts[dst[e]], 1);
}

// single-block coarsened scan: 1024 threads x 49 elements, one barrier phase
__global__ void __launch_bounds__(1024) k_scan(const int* __restrict__ counts,
                                               int* __restrict__ row_start) {
    const int PER_T = 49;
    int tid = threadIdx.x;
    int base = tid * PER_T;
    int li[PER_T];
    int sum = 0;
    #pragma unroll
    for (int i = 0; i < PER_T; ++i) {
        int idx = base + i;
        int c = (idx < N_NODES) ? counts[idx] : 0;
        sum += c;
        li[i] = sum;                       // local inclusive
    }
    int lane = tid & 63, wid = tid >> 6;   // 16 waves
    int incl = sum;
    #pragma unroll
    for (int off = 1; off < 64; off <<= 1) {
        int t = __shfl_up(incl, off, 64);
        if (lane >= off) incl += t;
    }
    __shared__ int ws[16];
    if (lane == 63) ws[wid] = incl;
    __syncthreads();
    if (tid < 16) {
        int w = ws[tid];
        #pragma unroll
        for (int off = 1; off < 16; off <<= 1) {
            int t = __shfl_up(w, off, 16);
            if ((tid & 15) >= off) w += t;
        }
        ws[tid] = w;
    }
    __syncthreads();
    int texcl = incl - sum + (wid ? ws[wid - 1] : 0);
    #pragma unroll
    for (int i = 0; i < PER_T; ++i) {
        int idx = base + i;
        if (idx < N_NODES) row_start[idx + 1] = texcl + li[i];
    }
    if (tid == 0) row_start[0] = 0;
}

__global__ void k_fill(const int* __restrict__ src, const int* __restrict__ dst,
                       const int* __restrict__ row_start, int* __restrict__ cursor,
                       int* __restrict__ col) {
    int e = blockIdx.x * blockDim.x + threadIdx.x;
    if (e < N_EDGES) {
        int d = dst[e];
        int pos = atomicAdd(&cursor[d], 1);
        col[row_start[d] + pos] = src[e];
    }
}

// ---------------- prep: gstart + V1 = W1@a1 (128x8), V2 = W2@a2 (64x2) ----------------

__global__ void __launch_bounds__(1024) k_prep(
        const int* __restrict__ batch,
        const float* __restrict__ W1, const float* __restrict__ a_src1,
        const float* __restrict__ a_dst1,
        const float* __restrict__ W2, const float* __restrict__ a_src2,
        const float* __restrict__ a_dst2,
        int* __restrict__ gstart, float* __restrict__ Vc1, float* __restrict__ Vc2) {
    int tid = threadIdx.x;
    {   // Vc1[k][i]: i 0..3 = src head i, 4..7 = dst head i-4
        int k = tid >> 3, i = tid & 7;
        int h = i & 3;
        const float* a = (i < 4 ? a_src1 : a_dst1) + h * 16;
        float v = 0.f;
        #pragma unroll
        for (int c = 0; c < 16; ++c) v = fmaf(W1[k * 64 + h * 16 + c], a[c], v);
        Vc1[k * 8 + i] = v;
    }
    if (tid < 128) {   // Vc2[k][i]: i 0 = src, 1 = dst
        int k = tid >> 1, i = tid & 1;
        const float* a = i ? a_dst2 : a_src2;
        float v = 0.f;
        #pragma unroll
        for (int c = 0; c < 32; ++c) v = fmaf(W2[k * 32 + c], a[c], v);
        Vc2[k * 2 + i] = v;
    }
    if (tid <= N_GRAPHS) {
        int g = tid;
        int lo = 0, hi = N_NODES;
        while (lo < hi) {
            int mid = (lo + hi) >> 1;
            if (batch[mid] < g) lo = mid + 1; else hi = mid;
        }
        gstart[g] = lo;
    }
}

// ---------------- Layer 1 GEMM (MFMA): xl1 = x@W1 (bf16), esd1 = x@V1 ----------------
// B-tiles: t=0..3 -> W cols 0..63, t=4 -> [Vsrc(4)|Vdst(4)|zeros(8)]

__global__ void __launch_bounds__(256) k_gemm1(
        const float* __restrict__ x, const float* __restrict__ W1,
        const float* __restrict__ Vc1,
        float* __restrict__ xl1, float* __restrict__ esd1) {
    __shared__ unsigned short Wt[80][144];   // [n][k] bf16, stride 144 (16B-aligned rows)
    int tid = threadIdx.x;
    for (int i = tid; i < 80 * 128; i += 256) {
        int n = i >> 7, k = i & 127;
        float v = (n < 64) ? W1[k * 64 + n] : (n < 72 ? Vc1[k * 8 + (n - 64)] : 0.f);
        Wt[n][k] = f2bf(v);
    }
    __syncthreads();
    int lane = tid & 63, wid = tid >> 6;
    int tile = blockIdx.x * 4 + wid;
    if (tile >= N_TILES) return;
    int m = lane & 15, kg = lane >> 4;
    int base = tile * 16;
    const float* xr = x + (size_t)(base + m) * D_IN + kg * 8;
    f32x4 acc[5];
    #pragma unroll
    for (int t = 0; t < 5; ++t) acc[t] = (f32x4){0.f, 0.f, 0.f, 0.f};
    #pragma unroll
    for (int s = 0; s < 4; ++s) {
        f32x4 p = ((const f32x4*)(xr + s * 32))[0];
        f32x4 q = ((const f32x4*)(xr + s * 32))[1];
        short8 a;
        a[0] = (short)f2bf(p[0]); a[1] = (short)f2bf(p[1]);
        a[2] = (short)f2bf(p[2]); a[3] = (short)f2bf(p[3]);
        a[4] = (short)f2bf(q[0]); a[5] = (short)f2bf(q[1]);
        a[6] = (short)f2bf(q[2]); a[7] = (short)f2bf(q[3]);
        #pragma unroll
        for (int t = 0; t < 5; ++t) {
            short8 b = *(const short8*)&Wt[t * 16 + m][s * 32 + kg * 8];
            acc[t] = __builtin_amdgcn_mfma_f32_16x16x32_bf16(a, b, acc[t], 0, 0, 0);
        }
    }
    // C layout: col = lane&15 (=m), row = kg*4 + r
    #pragma unroll
    for (int r = 0; r < 4; ++r) {
        int node = base + kg * 4 + r;
        #pragma unroll
        for (int t = 0; t < 4; ++t)
            xl1[(size_t)node * HID + t * 16 + m] = acc[t][r];
        if (m < 8) esd1[node * 8 + m] = acc[4][r];
    }
}

// ---------------- Layer 1 aggregation: pull, one wave per node, 4-way MLP ----------------

__global__ void __launch_bounds__(256) k_agg1(
        const float* __restrict__ xl1, const float* __restrict__ esd1,
        const int* __restrict__ row_start, const int* __restrict__ col,
        const float* __restrict__ b1, float* __restrict__ h1pre) {
    int wid = threadIdx.x >> 6, lane = threadIdx.x & 63;
    int d = blockIdx.x * 4 + wid;
    if (d >= N_NODES) return;
    int h = lane >> 4;
    float edh = esd1[d * 8 + 4 + h];
    float e0 = esd1[d * 8 + h] + edh;       // self loop
    float w0 = __expf(e0 > 0.f ? e0 : NEG * e0);
    float acc = w0 * xl1[(size_t)d * HID + lane];
    float wsum = w0;
    int js = row_start[d], je = row_start[d + 1];
    for (int j0 = js; j0 < je; j0 += 64) {
        int jj = j0 + lane;
        int sv = (jj < je) ? col[jj] : -1;
        int cnt = je - j0; if (cnt > 64) cnt = 64;
        for (int k = 0; k < cnt; k += 4) {
            int s0 = __shfl(sv, k, 64);
            int s1 = __shfl(sv, k + 1, 64);
            int s2 = __shfl(sv, k + 2, 64);
            int s3 = __shfl(sv, k + 3, 64);
            int t0 = s0 < 0 ? d : s0, t1 = s1 < 0 ? d : s1;
            int t2 = s2 < 0 ? d : s2, t3 = s3 < 0 ? d : s3;
            float x0 = xl1[(size_t)t0 * HID + lane];
            float x1 = xl1[(size_t)t1 * HID + lane];
            float x2 = xl1[(size_t)t2 * HID + lane];
            float x3 = xl1[(size_t)t3 * HID + lane];
            float e0_ = esd1[t0 * 8 + h] + edh;
            float e1_ = esd1[t1 * 8 + h] + edh;
            float e2_ = esd1[t2 * 8 + h] + edh;
            float e3_ = esd1[t3 * 8 + h] + edh;
            float w_0 = s0 < 0 ? 0.f : __expf(e0_ > 0.f ? e0_ : NEG * e0_);
            float w_1 = s1 < 0 ? 0.f : __expf(e1_ > 0.f ? e1_ : NEG * e1_);
            float w_2 = s2 < 0 ? 0.f : __expf(e2_ > 0.f ? e2_ : NEG * e2_);
            float w_3 = s3 < 0 ? 0.f : __expf(e3_ > 0.f ? e3_ : NEG * e3_);
            acc = fmaf(w_0, x0, acc); wsum += w_0;
            acc = fmaf(w_1, x1, acc); wsum += w_1;
            acc = fmaf(w_2, x2, acc); wsum += w_2;
            acc = fmaf(w_3, x3, acc); wsum += w_3;
        }
    }
    h1pre[(size_t)d * HID + lane] = acc / wsum + b1[lane];
}

// ---------------- BatchNorm stats (sum, sumsq per channel) ----------------

__global__ void __launch_bounds__(256) k_stats(const float* __restrict__ hpre,
                                               int nch, float* __restrict__ stats) {
    int c = threadIdx.x & (nch - 1);
    int gid = blockIdx.x * blockDim.x + threadIdx.x;
    int r0 = gid / nch;
    int rstride = (gridDim.x * blockDim.x) / nch;
    float s = 0.f, s2 = 0.f;
    for (int n = r0; n < N_NODES; n += rstride) {
        float v = hpre[(size_t)n * nch + c];
        s += v;
        s2 = fmaf(v, v, s2);
    }
    __shared__ float ls[256], ls2[256];
    ls[threadIdx.x] = s;
    ls2[threadIdx.x] = s2;
    __syncthreads();
    if (threadIdx.x < nch) {
        int rows = 256 / nch;
        float a = 0.f, b = 0.f;
        for (int r = 0; r < rows; ++r) {
            a += ls[r * nch + c];
            b += ls2[r * nch + c];
        }
        atomicAdd(&stats[c], a);
        atomicAdd(&stats[nch + c], b);
    }
}

// ---------------- Layer 2 GEMM (MFMA): bn1+relu fused; xl2, esd2 ----------------
// B-tiles: t=0,1 -> W2 cols 0..31, t=2 -> [v2src|v2dst|zeros(14)]

__global__ void __launch_bounds__(256) k_gemm2(
        const float* __restrict__ h1pre, const float* __restrict__ stats1,
        const float* __restrict__ g1, const float* __restrict__ be1,
        const float* __restrict__ W2, const float* __restrict__ Vc2,
        float* __restrict__ xl2, float* __restrict__ esd2) {
    __shared__ unsigned short Wt[48][80];   // [n][k] bf16, stride 80 (16B-aligned rows)
    __shared__ float A1s[64], B1s[64];
    int tid = threadIdx.x;
    for (int i = tid; i < 48 * 64; i += 256) {
        int n = i >> 6, k = i & 63;
        float v = (n < 32) ? W2[k * 32 + n]
                : (n == 32) ? Vc2[k * 2] : (n == 33) ? Vc2[k * 2 + 1] : 0.f;
        Wt[n][k] = f2bf(v);
    }
    if (tid < 64) {
        float mu = stats1[tid] * (1.f / N_NODES);
        float var = stats1[64 + tid] * (1.f / N_NODES) - mu * mu;
        float sc = g1[tid] * rsqrtf(var + BN_EPS);
        A1s[tid] = sc;
        B1s[tid] = be1[tid] - mu * sc;
    }
    __syncthreads();
    int lane = tid & 63, wid = tid >> 6;
    int tile = blockIdx.x * 4 + wid;
    if (tile >= N_TILES) return;
    int m = lane & 15, kg = lane >> 4;
    int base = tile * 16;
    const float* hr = h1pre + (size_t)(base + m) * HID + kg * 8;
    f32x4 acc[3];
    #pragma unroll
    for (int t = 0; t < 3; ++t) acc[t] = (f32x4){0.f, 0.f, 0.f, 0.f};
    #pragma unroll
    for (int s = 0; s < 2; ++s) {
        int k0 = s * 32 + kg * 8;
        f32x4 p = ((const f32x4*)(hr + s * 32))[0];
        f32x4 q = ((const f32x4*)(hr + s * 32))[1];
        f32x4 sa = *(const f32x4*)&A1s[k0];
        f32x4 sb = *(const f32x4*)&B1s[k0];
        f32x4 sa2 = *(const f32x4*)&A1s[k0 + 4];
        f32x4 sb2 = *(const f32x4*)&B1s[k0 + 4];
        short8 a;
        #pragma unroll
        for (int j = 0; j < 4; ++j) {
            float v = fmaf(p[j], sa[j], sb[j]);
            a[j] = (short)f2bf(v > 0.f ? v : 0.f);
        }
        #pragma unroll
        for (int j = 0; j < 4; ++j) {
            float v = fmaf(q[j], sa2[j], sb2[j]);
            a[4 + j] = (short)f2bf(v > 0.f ? v : 0.f);
        }
        #pragma unroll
        for (int t = 0; t < 3; ++t) {
            short8 b = *(const short8*)&Wt[t * 16 + m][s * 32 + kg * 8];
            acc[t] = __builtin_amdgcn_mfma_f32_16x16x32_bf16(a, b, acc[t], 0, 0, 0);
        }
    }
    #pragma unroll
    for (int r = 0; r < 4; ++r) {
        int node = base + kg * 4 + r;
        #pragma unroll
        for (int t = 0; t < 2; ++t)
            xl2[(size_t)node * OUT_C + t * 16 + m] = acc[t][r];
        if (m < 2) esd2[node * 2 + m] = acc[2][r];
    }
}

// ---------------- Layer 2 aggregation: 2 nodes per wave, 4-way MLP ----------------

__global__ void __launch_bounds__(256) k_agg2(
        const float* __restrict__ xl2, const float* __restrict__ esd2,
        const int* __restrict__ row_start, const int* __restrict__ col,
        const float* __restrict__ b2, float* __restrict__ h2pre) {
    int lane = threadIdx.x & 63;
    int half = lane >> 5;
    int c = lane & 31;
    int wid = threadIdx.x >> 6;
    int d = (blockIdx.x * 4 + wid) * 2 + half;
    if (d >= N_NODES) return;
    float edh = esd2[d * 2 + 1];
    float e0 = esd2[d * 2] + edh;
    float w0 = __expf(e0 > 0.f ? e0 : NEG * e0);
    float acc = w0 * xl2[(size_t)d * OUT_C + c];
    float wsum = w0;
    int js = row_start[d], je = row_start[d + 1];
    for (int j0 = js; j0 < je; j0 += 32) {
        int jj = j0 + c;
        int sv = (jj < je) ? col[jj] : -1;
        int cnt = je - j0; if (cnt > 32) cnt = 32;
        for (int k = 0; k < cnt; k += 4) {
            int s0 = __shfl(sv, k, 32);
            int s1 = __shfl(sv, k + 1, 32);
            int s2 = __shfl(sv, k + 2, 32);
            int s3 = __shfl(sv, k + 3, 32);
            int t0 = s0 < 0 ? d : s0, t1 = s1 < 0 ? d : s1;
            int t2 = s2 < 0 ? d : s2, t3 = s3 < 0 ? d : s3;
            float x0 = xl2[(size_t)t0 * OUT_C + c];
            float x1 = xl2[(size_t)t1 * OUT_C + c];
            float x2 = xl2[(size_t)t2 * OUT_C + c];
            float x3 = xl2[(size_t)t3 * OUT_C + c];
            float e0_ = esd2[t0 * 2] + edh;
            float e1_ = esd2[t1 * 2] + edh;
            float e2_ = esd2[t2 * 2] + edh;
            float e3_ = esd2[t3 * 2] + edh;
            float w_0 = s0 < 0 ? 0.f : __expf(e0_ > 0.f ? e0_ : NEG * e0_);
            float w_1 = s1 < 0 ? 0.f : __expf(e1_ > 0.f ? e1_ : NEG * e1_);
            float w_2 = s2 < 0 ? 0.f : __expf(e2_ > 0.f ? e2_ : NEG * e2_);
            float w_3 = s3 < 0 ? 0.f : __expf(e3_ > 0.f ? e3_ : NEG * e3_);
            acc = fmaf(w_0, x0, acc); wsum += w_0;
            acc = fmaf(w_1, x1, acc); wsum += w_1;
            acc = fmaf(w_2, x2, acc); wsum += w_2;
            acc = fmaf(w_3, x3, acc); wsum += w_3;
        }
    }
    h2pre[(size_t)d * OUT_C + c] = acc / wsum + b2[c];
}

// ---------------- fused BN2-apply + pool partials ----------------
// grid 256: block = (graph g = blk>>2, part = blk&3). Writes node_emb + pfeat.

__global__ void __launch_bounds__(256) k_bnpool(
        const float* __restrict__ h2pre, const float* __restrict__ stats2,
        const float* __restrict__ g2, const float* __restrict__ be2,
        const int* __restrict__ gstart, float* __restrict__ out,
        float* __restrict__ pfeat) {
    __shared__ float A2[OUT_C], B2[OUT_C];
    if (threadIdx.x < OUT_C) {
        int cc = threadIdx.x;
        float mu = stats2[cc] * (1.f / N_NODES);
        float var = stats2[OUT_C + cc] * (1.f / N_NODES) - mu * mu;
        float sc = g2[cc] * rsqrtf(var + BN_EPS);
        A2[cc] = sc;
        B2[cc] = be2[cc] - mu * sc;
    }
    __syncthreads();
    int g = blockIdx.x >> 2, part = blockIdx.x & 3;
    int s = gstart[g], e = gstart[g + 1];
    int len = e - s;
    int q = (len + 3) >> 2;
    int ps = s + part * q;
    int pe = ps + q; if (pe > e) pe = e;
    int c = threadIdx.x & 31, r = threadIdx.x >> 5;   // 8 row-lanes
    float sum = 0.f, mx = -INFINITY;
    for (int n = ps + r; n < pe; n += 8) {
        float v = fmaf(h2pre[(size_t)n * OUT_C + c], A2[c], B2[c]);
        out[(size_t)n * OUT_C + c] = v;
        sum += v;
        mx = fmaxf(mx, v);
    }
    __shared__ float lsum[256], lmax[256];
    lsum[threadIdx.x] = sum;
    lmax[threadIdx.x] = mx;
    __syncthreads();
    if (threadIdx.x < 32) {
        float ts = 0.f, tm = -INFINITY;
        for (int rr = 0; rr < 8; ++rr) {
            ts += lsum[rr * 32 + c];
            tm = fmaxf(tm, lmax[rr * 32 + c]);
        }
        pfeat[blockIdx.x * 64 + c] = ts;
        pfeat[blockIdx.x * 64 + 32 + c] = tm;
    }
}

// ---------------- MLP head (+pool combine) -> graph_emb ----------------

__global__ void __launch_bounds__(256) k_mlp(
        const float* __restrict__ pfeat, const int* __restrict__ gstart,
        const float* __restrict__ fcW1, const float* __restrict__ fcb1,
        const float* __restrict__ fcW2, const float* __restrict__ fcb2,
        float* __restrict__ out) {
    __shared__ float gf[N_GRAPHS * 64];     // 16 KB
    __shared__ float t1[N_GRAPHS * OUT_C];  // 8 KB
    int tid = threadIdx.x;
    for (int i = tid; i < N_GRAPHS * 32; i += 256) {
        int g = i >> 5, c = i & 31;
        float sm = 0.f, mx = -INFINITY;
        #pragma unroll
        for (int p = 0; p < 4; ++p) {
            sm += pfeat[(g * 4 + p) * 64 + c];
            mx = fmaxf(mx, pfeat[(g * 4 + p) * 64 + 32 + c]);
        }
        int cnt = gstart[g + 1] - gstart[g];
        gf[g * 64 + c] = (cnt > 0) ? sm / (float)cnt : 0.f;
        gf[g * 64 + 32 + c] = (cnt > 0) ? mx : 0.f;
    }
    __syncthreads();
    for (int i = tid; i < N_GRAPHS * OUT_C; i += 256) {
        int g = i >> 5, j = i & 31;
        float a = fcb1[j];
        for (int k = 0; k < 64; ++k) a = fmaf(gf[g * 64 + k], fcW1[k * OUT_C + j], a);
        t1[i] = a > 0.f ? a : 0.f;
    }
    __syncthreads();
    for (int i = tid; i < N_GRAPHS * OUT_C; i += 256) {
        int g = i >> 5, oc = i & 31;
        float a = fcb2[oc];
        for (int k = 0; k < OUT_C; ++k) a = fmaf(t1[g * OUT_C + k], fcW2[k * OUT_C + oc], a);
        out[(size_t)N_NODES * OUT_C + g * OUT_C + oc] = a;
    }
}

// ---------------- launch ----------------

extern "C" void kernel_launch(void* const* d_in, const int* in_sizes, int n_in,
                              void* d_out, int out_size, void* d_ws, size_t ws_size,
                              hipStream_t stream) {
    (void)in_sizes; (void)n_in; (void)out_size; (void)ws_size;
    const float* x      = (const float*)d_in[0];
    const int*   ei     = (const int*)d_in[1];
    const int*   batch  = (const int*)d_in[2];
    const float* W1     = (const float*)d_in[3];
    const float* a_src1 = (const float*)d_in[4];
    const float* a_dst1 = (const float*)d_in[5];
    const float* b1     = (const float*)d_in[6];
    const float* g1     = (const float*)d_in[7];
    const float* be1    = (const float*)d_in[8];
    const float* W2     = (const float*)d_in[9];
    const float* a_src2 = (const float*)d_in[10];
    const float* a_dst2 = (const float*)d_in[11];
    const float* b2     = (const float*)d_in[12];
    const float* g2     = (const float*)d_in[13];
    const float* be2    = (const float*)d_in[14];
    const float* fcW1   = (const float*)d_in[15];
    const float* fcb1   = (const float*)d_in[16];
    const float* fcW2   = (const float*)d_in[17];
    const float* fcb2   = (const float*)d_in[18];
    const int* srcv = ei;
    const int* dstv = ei + N_EDGES;
    float* out = (float*)d_out;

    char* w = (char*)d_ws;
    size_t o = 0;
    int*   counts    = (int*)(w + o);   o += (size_t)N_NODES * 4;
    int*   cursor    = (int*)(w + o);   o += (size_t)N_NODES * 4;
    float* stats1    = (float*)(w + o); o += 128 * 4;
    float* stats2    = (float*)(w + o); o += 64 * 4;
    size_t zero_bytes = o;                       // everything above must start at 0
    int*   row_start = (int*)(w + o);   o += (size_t)(N_NODES + 1) * 4;
    int*   gst       = (int*)(w + o);   o += 66 * 4;
    int*   col       = (int*)(w + o);   o += (size_t)N_EDGES * 4;
    float* Vc1       = (float*)(w + o); o += 128 * 8 * 4;
    float* Vc2       = (float*)(w + o); o += 64 * 2 * 4;
    float* xl1       = (float*)(w + o); o += (size_t)N_NODES * HID * 4;
    float* esd1      = (float*)(w + o); o += (size_t)N_NODES * 8 * 4;
    float* h1pre     = (float*)(w + o); o += (size_t)N_NODES * HID * 4;
    float* pfeat     = (float*)(w + o); o += 256 * 64 * 4;
    // aliases (lifetimes disjoint):
    float* xl2   = xl1;                          // xl1 dead after k_agg1
    float* esd2  = xl1 + (size_t)N_NODES * OUT_C;
    float* h2pre = h1pre;                        // h1pre dead after k_gemm2

    hipMemsetAsync(d_ws, 0, zero_bytes, stream);
    k_hist  <<<(N_EDGES + 255) / 256, 256, 0, stream>>>(dstv, counts);
    k_scan  <<<1, 1024, 0, stream>>>(counts, row_start);
    k_fill  <<<(N_EDGES + 255) / 256, 256, 0, stream>>>(srcv, dstv, row_start, cursor, col);
    k_prep  <<<1, 1024, 0, stream>>>(batch, W1, a_src1, a_dst1, W2, a_src2, a_dst2,
                                     gst, Vc1, Vc2);
    k_gemm1 <<<(N_TILES + 3) / 4, 256, 0, stream>>>(x, W1, Vc1, xl1, esd1);
    k_agg1  <<<(N_NODES + 3) / 4, 256, 0, stream>>>(xl1, esd1, row_start, col, b1, h1pre);
    k_stats <<<256, 256, 0, stream>>>(h1pre, HID, stats1);
    k_gemm2 <<<(N_TILES + 3) / 4, 256, 0, stream>>>(h1pre, stats1, g1, be1, W2, Vc2,
                                                    xl2, esd2);
    k_agg2  <<<(N_NODES + 7) / 8, 256, 0, stream>>>(xl2, esd2, row_start, col, b2, h2pre);
    k_stats <<<256, 256, 0, stream>>>(h2pre, OUT_C, stats2);
    k_bnpool<<<256, 256, 0, stream>>>(h2pre, stats2, g2, be2, gst, out, pfeat);
    k_mlp   <<<1, 256, 0, stream>>>(pfeat, gst, fcW1, fcb1, fcW2, fcb2, out);
}

// Round 3
// 349.261 us; speedup vs baseline: 1.6141x; 1.1171x over previous
//
#include <hip/hip_runtime.h>
#include <math.h>

#define N_NODES 50000
#define N_EDGES 800000
#define N_GRAPHS 64
#define D_IN 128
#define HID 64
#define OUT_C 32
#define NEG 0.2f
#define BN_EPS 1e-5f
#define N_TILES 3125    // N_NODES / 16
#define SCAN_NB 196     // ceil(N_NODES / 256)

typedef __attribute__((ext_vector_type(8))) short short8;
typedef __attribute__((ext_vector_type(4))) float f32x4;

static __device__ inline unsigned short f2bf(float f) {
    unsigned u = __float_as_uint(f);
    u += 0x7FFF + ((u >> 16) & 1);
    return (unsigned short)(u >> 16);
}

// ---------------- CSR construction ----------------

__global__ void k_hist(const int* __restrict__ dst, int* __restrict__ counts) {
    int e = blockIdx.x * blockDim.x + threadIdx.x;
    if (e < N_EDGES) atomicAdd(&counts[dst[e]], 1);
}

// Phase A: per-block inclusive scan of 256 counts; partials into row_start[+1], totals into bsum
__global__ void __launch_bounds__(256) k_scanA(const int* __restrict__ counts,
                                               int* __restrict__ row_start,
                                               int* __restrict__ bsum) {
    int tid = threadIdx.x;
    int i = blockIdx.x * 256 + tid;
    int v = (i < N_NODES) ? counts[i] : 0;
    int lane = tid & 63, wid = tid >> 6;
    int incl = v;
    #pragma unroll
    for (int off = 1; off < 64; off <<= 1) {
        int t = __shfl_up(incl, off, 64);
        if (lane >= off) incl += t;
    }
    __shared__ int ws[4];
    if (lane == 63) ws[wid] = incl;
    __syncthreads();
    if (tid == 0) {
        int a = ws[0];
        #pragma unroll
        for (int j = 1; j < 4; ++j) { a += ws[j]; ws[j] = a; }
        // ws[j] now inclusive across waves (ws[0] unchanged)
    }
    __syncthreads();
    if (wid > 0) incl += ws[wid - 1];
    if (i < N_NODES) row_start[i + 1] = incl;
    if (tid == 255) bsum[blockIdx.x] = incl;
}

// Phase B: exclusive scan of SCAN_NB block totals
__global__ void __launch_bounds__(256) k_scanB(const int* __restrict__ bsum,
                                               int* __restrict__ boff) {
    int tid = threadIdx.x;
    int v = (tid < SCAN_NB) ? bsum[tid] : 0;
    int lane = tid & 63, wid = tid >> 6;
    int incl = v;
    #pragma unroll
    for (int off = 1; off < 64; off <<= 1) {
        int t = __shfl_up(incl, off, 64);
        if (lane >= off) incl += t;
    }
    __shared__ int ws[4];
    if (lane == 63) ws[wid] = incl;
    __syncthreads();
    if (tid == 0) {
        int a = ws[0];
        #pragma unroll
        for (int j = 1; j < 4; ++j) { a += ws[j]; ws[j] = a; }
    }
    __syncthreads();
    if (wid > 0) incl += ws[wid - 1];
    if (tid < SCAN_NB) boff[tid] = incl - v;   // exclusive
}

// Phase C: add block offsets
__global__ void __launch_bounds__(256) k_scanC(int* __restrict__ row_start,
                                               const int* __restrict__ boff) {
    int i = blockIdx.x * 256 + threadIdx.x;
    if (i < N_NODES) row_start[i + 1] += boff[blockIdx.x];
    if (i == 0) row_start[0] = 0;
}

__global__ void k_fill(const int* __restrict__ src, const int* __restrict__ dst,
                       const int* __restrict__ row_start, int* __restrict__ cursor,
                       int* __restrict__ col) {
    int e = blockIdx.x * blockDim.x + threadIdx.x;
    if (e < N_EDGES) {
        int d = dst[e];
        int pos = atomicAdd(&cursor[d], 1);
        col[row_start[d] + pos] = src[e];
    }
}

// ---------------- prep: gstart + V1 = W1@a1 (128x8), V2 = W2@a2 (64x2) ----------------

__global__ void __launch_bounds__(1024) k_prep(
        const int* __restrict__ batch,
        const float* __restrict__ W1, const float* __restrict__ a_src1,
        const float* __restrict__ a_dst1,
        const float* __restrict__ W2, const float* __restrict__ a_src2,
        const float* __restrict__ a_dst2,
        int* __restrict__ gstart, float* __restrict__ Vc1, float* __restrict__ Vc2) {
    int tid = threadIdx.x;
    {   // Vc1[k][i]: i 0..3 = src head i, 4..7 = dst head i-4
        int k = tid >> 3, i = tid & 7;
        int h = i & 3;
        const float* a = (i < 4 ? a_src1 : a_dst1) + h * 16;
        float v = 0.f;
        #pragma unroll
        for (int c = 0; c < 16; ++c) v = fmaf(W1[k * 64 + h * 16 + c], a[c], v);
        Vc1[k * 8 + i] = v;
    }
    if (tid < 128) {   // Vc2[k][i]: i 0 = src, 1 = dst
        int k = tid >> 1, i = tid & 1;
        const float* a = i ? a_dst2 : a_src2;
        float v = 0.f;
        #pragma unroll
        for (int c = 0; c < 32; ++c) v = fmaf(W2[k * 32 + c], a[c], v);
        Vc2[k * 2 + i] = v;
    }
    if (tid <= N_GRAPHS) {
        int g = tid;
        int lo = 0, hi = N_NODES;
        while (lo < hi) {
            int mid = (lo + hi) >> 1;
            if (batch[mid] < g) lo = mid + 1; else hi = mid;
        }
        gstart[g] = lo;
    }
}

// ---------------- Layer 1 GEMM (MFMA): xl1 = x@W1 (bf16), esd1 = x@V1 ----------------

__global__ void __launch_bounds__(256) k_gemm1(
        const float* __restrict__ x, const float* __restrict__ W1,
        const float* __restrict__ Vc1,
        float* __restrict__ xl1, float* __restrict__ esd1) {
    __shared__ unsigned short Wt[80][144];   // [n][k] bf16, stride 144 (16B-aligned rows)
    int tid = threadIdx.x;
    for (int i = tid; i < 80 * 128; i += 256) {
        int n = i >> 7, k = i & 127;
        float v = (n < 64) ? W1[k * 64 + n] : (n < 72 ? Vc1[k * 8 + (n - 64)] : 0.f);
        Wt[n][k] = f2bf(v);
    }
    __syncthreads();
    int lane = tid & 63, wid = tid >> 6;
    int tile = blockIdx.x * 4 + wid;
    if (tile >= N_TILES) return;
    int m = lane & 15, kg = lane >> 4;
    int base = tile * 16;
    const float* xr = x + (size_t)(base + m) * D_IN + kg * 8;
    f32x4 acc[5];
    #pragma unroll
    for (int t = 0; t < 5; ++t) acc[t] = (f32x4){0.f, 0.f, 0.f, 0.f};
    #pragma unroll
    for (int s = 0; s < 4; ++s) {
        f32x4 p = ((const f32x4*)(xr + s * 32))[0];
        f32x4 q = ((const f32x4*)(xr + s * 32))[1];
        short8 a;
        a[0] = (short)f2bf(p[0]); a[1] = (short)f2bf(p[1]);
        a[2] = (short)f2bf(p[2]); a[3] = (short)f2bf(p[3]);
        a[4] = (short)f2bf(q[0]); a[5] = (short)f2bf(q[1]);
        a[6] = (short)f2bf(q[2]); a[7] = (short)f2bf(q[3]);
        #pragma unroll
        for (int t = 0; t < 5; ++t) {
            short8 b = *(const short8*)&Wt[t * 16 + m][s * 32 + kg * 8];
            acc[t] = __builtin_amdgcn_mfma_f32_16x16x32_bf16(a, b, acc[t], 0, 0, 0);
        }
    }
    #pragma unroll
    for (int r = 0; r < 4; ++r) {
        int node = base + kg * 4 + r;
        #pragma unroll
        for (int t = 0; t < 4; ++t)
            xl1[(size_t)node * HID + t * 16 + m] = acc[t][r];
        if (m < 8) esd1[node * 8 + m] = acc[4][r];
    }
}

// ---------------- Layer 1 aggregation: pull, one wave per node, 4-way MLP ----------------

__global__ void __launch_bounds__(256) k_agg1(
        const float* __restrict__ xl1, const float* __restrict__ esd1,
        const int* __restrict__ row_start, const int* __restrict__ col,
        const float* __restrict__ b1, float* __restrict__ h1pre) {
    int wid = threadIdx.x >> 6, lane = threadIdx.x & 63;
    int d = blockIdx.x * 4 + wid;
    if (d >= N_NODES) return;
    int h = lane >> 4;
    float edh = esd1[d * 8 + 4 + h];
    float e0 = esd1[d * 8 + h] + edh;       // self loop
    float w0 = __expf(e0 > 0.f ? e0 : NEG * e0);
    float acc = w0 * xl1[(size_t)d * HID + lane];
    float wsum = w0;
    int js = row_start[d], je = row_start[d + 1];
    for (int j0 = js; j0 < je; j0 += 64) {
        int jj = j0 + lane;
        int sv = (jj < je) ? col[jj] : -1;
        int cnt = je - j0; if (cnt > 64) cnt = 64;
        for (int k = 0; k < cnt; k += 4) {
            int s0 = __shfl(sv, k, 64);
            int s1 = __shfl(sv, k + 1, 64);
            int s2 = __shfl(sv, k + 2, 64);
            int s3 = __shfl(sv, k + 3, 64);
            int t0 = s0 < 0 ? d : s0, t1 = s1 < 0 ? d : s1;
            int t2 = s2 < 0 ? d : s2, t3 = s3 < 0 ? d : s3;
            float x0 = xl1[(size_t)t0 * HID + lane];
            float x1 = xl1[(size_t)t1 * HID + lane];
            float x2 = xl1[(size_t)t2 * HID + lane];
            float x3 = xl1[(size_t)t3 * HID + lane];
            float e0_ = esd1[t0 * 8 + h] + edh;
            float e1_ = esd1[t1 * 8 + h] + edh;
            float e2_ = esd1[t2 * 8 + h] + edh;
            float e3_ = esd1[t3 * 8 + h] + edh;
            float w_0 = s0 < 0 ? 0.f : __expf(e0_ > 0.f ? e0_ : NEG * e0_);
            float w_1 = s1 < 0 ? 0.f : __expf(e1_ > 0.f ? e1_ : NEG * e1_);
            float w_2 = s2 < 0 ? 0.f : __expf(e2_ > 0.f ? e2_ : NEG * e2_);
            float w_3 = s3 < 0 ? 0.f : __expf(e3_ > 0.f ? e3_ : NEG * e3_);
            acc = fmaf(w_0, x0, acc); wsum += w_0;
            acc = fmaf(w_1, x1, acc); wsum += w_1;
            acc = fmaf(w_2, x2, acc); wsum += w_2;
            acc = fmaf(w_3, x3, acc); wsum += w_3;
        }
    }
    h1pre[(size_t)d * HID + lane] = acc / wsum + b1[lane];
}

// ---------------- BatchNorm stats (sum, sumsq per channel) ----------------

__global__ void __launch_bounds__(256) k_stats(const float* __restrict__ hpre,
                                               int nch, float* __restrict__ stats) {
    int c = threadIdx.x & (nch - 1);
    int gid = blockIdx.x * blockDim.x + threadIdx.x;
    int r0 = gid / nch;
    int rstride = (gridDim.x * blockDim.x) / nch;
    float s = 0.f, s2 = 0.f;
    for (int n = r0; n < N_NODES; n += rstride) {
        float v = hpre[(size_t)n * nch + c];
        s += v;
        s2 = fmaf(v, v, s2);
    }
    __shared__ float ls[256], ls2[256];
    ls[threadIdx.x] = s;
    ls2[threadIdx.x] = s2;
    __syncthreads();
    if (threadIdx.x < nch) {
        int rows = 256 / nch;
        float a = 0.f, b = 0.f;
        for (int r = 0; r < rows; ++r) {
            a += ls[r * nch + c];
            b += ls2[r * nch + c];
        }
        atomicAdd(&stats[c], a);
        atomicAdd(&stats[nch + c], b);
    }
}

// ---------------- Layer 2 GEMM (MFMA): bn1+relu fused; xl2, esd2 ----------------

__global__ void __launch_bounds__(256) k_gemm2(
        const float* __restrict__ h1pre, const float* __restrict__ stats1,
        const float* __restrict__ g1, const float* __restrict__ be1,
        const float* __restrict__ W2, const float* __restrict__ Vc2,
        float* __restrict__ xl2, float* __restrict__ esd2) {
    __shared__ unsigned short Wt[48][80];   // [n][k] bf16, stride 80 (16B-aligned rows)
    __shared__ float A1s[64], B1s[64];
    int tid = threadIdx.x;
    for (int i = tid; i < 48 * 64; i += 256) {
        int n = i >> 6, k = i & 63;
        float v = (n < 32) ? W2[k * 32 + n]
                : (n == 32) ? Vc2[k * 2] : (n == 33) ? Vc2[k * 2 + 1] : 0.f;
        Wt[n][k] = f2bf(v);
    }
    if (tid < 64) {
        float mu = stats1[tid] * (1.f / N_NODES);
        float var = stats1[64 + tid] * (1.f / N_NODES) - mu * mu;
        float sc = g1[tid] * rsqrtf(var + BN_EPS);
        A1s[tid] = sc;
        B1s[tid] = be1[tid] - mu * sc;
    }
    __syncthreads();
    int lane = tid & 63, wid = tid >> 6;
    int tile = blockIdx.x * 4 + wid;
    if (tile >= N_TILES) return;
    int m = lane & 15, kg = lane >> 4;
    int base = tile * 16;
    const float* hr = h1pre + (size_t)(base + m) * HID + kg * 8;
    f32x4 acc[3];
    #pragma unroll
    for (int t = 0; t < 3; ++t) acc[t] = (f32x4){0.f, 0.f, 0.f, 0.f};
    #pragma unroll
    for (int s = 0; s < 2; ++s) {
        int k0 = s * 32 + kg * 8;
        f32x4 p = ((const f32x4*)(hr + s * 32))[0];
        f32x4 q = ((const f32x4*)(hr + s * 32))[1];
        f32x4 sa = *(const f32x4*)&A1s[k0];
        f32x4 sb = *(const f32x4*)&B1s[k0];
        f32x4 sa2 = *(const f32x4*)&A1s[k0 + 4];
        f32x4 sb2 = *(const f32x4*)&B1s[k0 + 4];
        short8 a;
        #pragma unroll
        for (int j = 0; j < 4; ++j) {
            float v = fmaf(p[j], sa[j], sb[j]);
            a[j] = (short)f2bf(v > 0.f ? v : 0.f);
        }
        #pragma unroll
        for (int j = 0; j < 4; ++j) {
            float v = fmaf(q[j], sa2[j], sb2[j]);
            a[4 + j] = (short)f2bf(v > 0.f ? v : 0.f);
        }
        #pragma unroll
        for (int t = 0; t < 3; ++t) {
            short8 b = *(const short8*)&Wt[t * 16 + m][s * 32 + kg * 8];
            acc[t] = __builtin_amdgcn_mfma_f32_16x16x32_bf16(a, b, acc[t], 0, 0, 0);
        }
    }
    #pragma unroll
    for (int r = 0; r < 4; ++r) {
        int node = base + kg * 4 + r;
        #pragma unroll
        for (int t = 0; t < 2; ++t)
            xl2[(size_t)node * OUT_C + t * 16 + m] = acc[t][r];
        if (m < 2) esd2[node * 2 + m] = acc[2][r];
    }
}

// ---------------- Layer 2 aggregation: 2 nodes per wave, 4-way MLP ----------------

__global__ void __launch_bounds__(256) k_agg2(
        const float* __restrict__ xl2, const float* __restrict__ esd2,
        const int* __restrict__ row_start, const int* __restrict__ col,
        const float* __restrict__ b2, float* __restrict__ h2pre) {
    int lane = threadIdx.x & 63;
    int half = lane >> 5;
    int c = lane & 31;
    int wid = threadIdx.x >> 6;
    int d = (blockIdx.x * 4 + wid) * 2 + half;
    if (d >= N_NODES) return;
    float edh = esd2[d * 2 + 1];
    float e0 = esd2[d * 2] + edh;
    float w0 = __expf(e0 > 0.f ? e0 : NEG * e0);
    float acc = w0 * xl2[(size_t)d * OUT_C + c];
    float wsum = w0;
    int js = row_start[d], je = row_start[d + 1];
    for (int j0 = js; j0 < je; j0 += 32) {
        int jj = j0 + c;
        int sv = (jj < je) ? col[jj] : -1;
        int cnt = je - j0; if (cnt > 32) cnt = 32;
        for (int k = 0; k < cnt; k += 4) {
            int s0 = __shfl(sv, k, 32);
            int s1 = __shfl(sv, k + 1, 32);
            int s2 = __shfl(sv, k + 2, 32);
            int s3 = __shfl(sv, k + 3, 32);
            int t0 = s0 < 0 ? d : s0, t1 = s1 < 0 ? d : s1;
            int t2 = s2 < 0 ? d : s2, t3 = s3 < 0 ? d : s3;
            float x0 = xl2[(size_t)t0 * OUT_C + c];
            float x1 = xl2[(size_t)t1 * OUT_C + c];
            float x2 = xl2[(size_t)t2 * OUT_C + c];
            float x3 = xl2[(size_t)t3 * OUT_C + c];
            float e0_ = esd2[t0 * 2] + edh;
            float e1_ = esd2[t1 * 2] + edh;
            float e2_ = esd2[t2 * 2] + edh;
            float e3_ = esd2[t3 * 2] + edh;
            float w_0 = s0 < 0 ? 0.f : __expf(e0_ > 0.f ? e0_ : NEG * e0_);
            float w_1 = s1 < 0 ? 0.f : __expf(e1_ > 0.f ? e1_ : NEG * e1_);
            float w_2 = s2 < 0 ? 0.f : __expf(e2_ > 0.f ? e2_ : NEG * e2_);
            float w_3 = s3 < 0 ? 0.f : __expf(e3_ > 0.f ? e3_ : NEG * e3_);
            acc = fmaf(w_0, x0, acc); wsum += w_0;
            acc = fmaf(w_1, x1, acc); wsum += w_1;
            acc = fmaf(w_2, x2, acc); wsum += w_2;
            acc = fmaf(w_3, x3, acc); wsum += w_3;
        }
    }
    h2pre[(size_t)d * OUT_C + c] = acc / wsum + b2[c];
}

// ---------------- fused BN2-apply + pool partials ----------------

__global__ void __launch_bounds__(256) k_bnpool(
        const float* __restrict__ h2pre, const float* __restrict__ stats2,
        const float* __restrict__ g2, const float* __restrict__ be2,
        const int* __restrict__ gstart, float* __restrict__ out,
        float* __restrict__ pfeat) {
    __shared__ float A2[OUT_C], B2[OUT_C];
    if (threadIdx.x < OUT_C) {
        int cc = threadIdx.x;
        float mu = stats2[cc] * (1.f / N_NODES);
        float var = stats2[OUT_C + cc] * (1.f / N_NODES) - mu * mu;
        float sc = g2[cc] * rsqrtf(var + BN_EPS);
        A2[cc] = sc;
        B2[cc] = be2[cc] - mu * sc;
    }
    __syncthreads();
    int g = blockIdx.x >> 2, part = blockIdx.x & 3;
    int s = gstart[g], e = gstart[g + 1];
    int len = e - s;
    int q = (len + 3) >> 2;
    int ps = s + part * q;
    int pe = ps + q; if (pe > e) pe = e;
    int c = threadIdx.x & 31, r = threadIdx.x >> 5;   // 8 row-lanes
    float sum = 0.f, mx = -INFINITY;
    for (int n = ps + r; n < pe; n += 8) {
        float v = fmaf(h2pre[(size_t)n * OUT_C + c], A2[c], B2[c]);
        out[(size_t)n * OUT_C + c] = v;
        sum += v;
        mx = fmaxf(mx, v);
    }
    __shared__ float lsum[256], lmax[256];
    lsum[threadIdx.x] = sum;
    lmax[threadIdx.x] = mx;
    __syncthreads();
    if (threadIdx.x < 32) {
        float ts = 0.f, tm = -INFINITY;
        for (int rr = 0; rr < 8; ++rr) {
            ts += lsum[rr * 32 + c];
            tm = fmaxf(tm, lmax[rr * 32 + c]);
        }
        pfeat[blockIdx.x * 64 + c] = ts;
        pfeat[blockIdx.x * 64 + 32 + c] = tm;
    }
}

// ---------------- MLP head (+pool combine) -> graph_emb ----------------

__global__ void __launch_bounds__(256) k_mlp(
        const float* __restrict__ pfeat, const int* __restrict__ gstart,
        const float* __restrict__ fcW1, const float* __restrict__ fcb1,
        const float* __restrict__ fcW2, const float* __restrict__ fcb2,
        float* __restrict__ out) {
    __shared__ float gf[N_GRAPHS * 64];     // 16 KB
    __shared__ float t1[N_GRAPHS * OUT_C];  // 8 KB
    int tid = threadIdx.x;
    for (int i = tid; i < N_GRAPHS * 32; i += 256) {
        int g = i >> 5, c = i & 31;
        float sm = 0.f, mx = -INFINITY;
        #pragma unroll
        for (int p = 0; p < 4; ++p) {
            sm += pfeat[(g * 4 + p) * 64 + c];
            mx = fmaxf(mx, pfeat[(g * 4 + p) * 64 + 32 + c]);
        }
        int cnt = gstart[g + 1] - gstart[g];
        gf[g * 64 + c] = (cnt > 0) ? sm / (float)cnt : 0.f;
        gf[g * 64 + 32 + c] = (cnt > 0) ? mx : 0.f;
    }
    __syncthreads();
    for (int i = tid; i < N_GRAPHS * OUT_C; i += 256) {
        int g = i >> 5, j = i & 31;
        float a = fcb1[j];
        for (int k = 0; k < 64; ++k) a = fmaf(gf[g * 64 + k], fcW1[k * OUT_C + j], a);
        t1[i] = a > 0.f ? a : 0.f;
    }
    __syncthreads();
    for (int i = tid; i < N_GRAPHS * OUT_C; i += 256) {
        int g = i >> 5, oc = i & 31;
        float a = fcb2[oc];
        for (int k = 0; k < OUT_C; ++k) a = fmaf(t1[g * OUT_C + k], fcW2[k * OUT_C + oc], a);
        out[(size_t)N_NODES * OUT_C + g * OUT_C + oc] = a;
    }
}

// ---------------- launch ----------------

extern "C" void kernel_launch(void* const* d_in, const int* in_sizes, int n_in,
                              void* d_out, int out_size, void* d_ws, size_t ws_size,
                              hipStream_t stream) {
    (void)in_sizes; (void)n_in; (void)out_size; (void)ws_size;
    const float* x      = (const float*)d_in[0];
    const int*   ei     = (const int*)d_in[1];
    const int*   batch  = (const int*)d_in[2];
    const float* W1     = (const float*)d_in[3];
    const float* a_src1 = (const float*)d_in[4];
    const float* a_dst1 = (const float*)d_in[5];
    const float* b1     = (const float*)d_in[6];
    const float* g1     = (const float*)d_in[7];
    const float* be1    = (const float*)d_in[8];
    const float* W2     = (const float*)d_in[9];
    const float* a_src2 = (const float*)d_in[10];
    const float* a_dst2 = (const float*)d_in[11];
    const float* b2     = (const float*)d_in[12];
    const float* g2     = (const float*)d_in[13];
    const float* be2    = (const float*)d_in[14];
    const float* fcW1   = (const float*)d_in[15];
    const float* fcb1   = (const float*)d_in[16];
    const float* fcW2   = (const float*)d_in[17];
    const float* fcb2   = (const float*)d_in[18];
    const int* srcv = ei;
    const int* dstv = ei + N_EDGES;
    float* out = (float*)d_out;

    char* w = (char*)d_ws;
    size_t o = 0;
    int*   counts    = (int*)(w + o);   o += (size_t)N_NODES * 4;
    int*   cursor    = (int*)(w + o);   o += (size_t)N_NODES * 4;
    float* stats1    = (float*)(w + o); o += 128 * 4;
    float* stats2    = (float*)(w + o); o += 64 * 4;
    size_t zero_bytes = o;                       // everything above must start at 0
    int*   row_start = (int*)(w + o);   o += (size_t)(N_NODES + 1) * 4;
    int*   gst       = (int*)(w + o);   o += 66 * 4;
    int*   bsum      = (int*)(w + o);   o += SCAN_NB * 4;
    int*   boff      = (int*)(w + o);   o += SCAN_NB * 4;
    int*   col       = (int*)(w + o);   o += (size_t)N_EDGES * 4;
    float* Vc1       = (float*)(w + o); o += 128 * 8 * 4;
    float* Vc2       = (float*)(w + o); o += 64 * 2 * 4;
    float* xl1       = (float*)(w + o); o += (size_t)N_NODES * HID * 4;
    float* esd1      = (float*)(w + o); o += (size_t)N_NODES * 8 * 4;
    float* h1pre     = (float*)(w + o); o += (size_t)N_NODES * HID * 4;
    float* pfeat     = (float*)(w + o); o += 256 * 64 * 4;
    // aliases (lifetimes disjoint):
    float* xl2   = xl1;                          // xl1 dead after k_agg1
    float* esd2  = xl1 + (size_t)N_NODES * OUT_C;
    float* h2pre = h1pre;                        // h1pre dead after k_gemm2

    hipMemsetAsync(d_ws, 0, zero_bytes, stream);
    k_hist  <<<(N_EDGES + 255) / 256, 256, 0, stream>>>(dstv, counts);
    k_scanA <<<SCAN_NB, 256, 0, stream>>>(counts, row_start, bsum);
    k_scanB <<<1, 256, 0, stream>>>(bsum, boff);
    k_scanC <<<SCAN_NB, 256, 0, stream>>>(row_start, boff);
    k_fill  <<<(N_EDGES + 255) / 256, 256, 0, stream>>>(srcv, dstv, row_start, cursor, col);
    k_prep  <<<1, 1024, 0, stream>>>(batch, W1, a_src1, a_dst1, W2, a_src2, a_dst2,
                                     gst, Vc1, Vc2);
    k_gemm1 <<<(N_TILES + 3) / 4, 256, 0, stream>>>(x, W1, Vc1, xl1, esd1);
    k_agg1  <<<(N_NODES + 3) / 4, 256, 0, stream>>>(xl1, esd1, row_start, col, b1, h1pre);
    k_stats <<<256, 256, 0, stream>>>(h1pre, HID, stats1);
    k_gemm2 <<<(N_TILES + 3) / 4, 256, 0, stream>>>(h1pre, stats1, g1, be1, W2, Vc2,
                                                    xl2, esd2);
    k_agg2  <<<(N_NODES + 7) / 8, 256, 0, stream>>>(xl2, esd2, row_start, col, b2, h2pre);
    k_stats <<<256, 256, 0, stream>>>(h2pre, OUT_C, stats2);
    k_bnpool<<<256, 256, 0, stream>>>(h2pre, stats2, g2, be2, gst, out, pfeat);
    k_mlp   <<<1, 256, 0, stream>>>(pfeat, gst, fcW1, fcb1, fcW2, fcb2, out);
}

// Round 4
// 304.889 us; speedup vs baseline: 1.8490x; 1.1455x over previous
//
#include <hip/hip_runtime.h>
#include <math.h>

#define N_NODES 50000
#define N_EDGES 800000
#define N_GRAPHS 64
#define D_IN 128
#define HID 64
#define OUT_C 32
#define NEG 0.2f
#define BN_EPS 1e-5f
#define N_TILES 3125    // N_NODES / 16
#define SCAN_NB 196     // ceil(N_NODES / 256)
#define N_BUCKETS 196   // ceil(N_NODES / 256), bucket = dst >> 8
#define BIN_CHUNK 4096
#define BIN_NB 196      // ceil(N_EDGES / BIN_CHUNK)
#define BUCKET_CAP 5120 // mean 4082, sd ~64 -> 16 sigma margin

typedef __attribute__((ext_vector_type(8))) short short8;
typedef __attribute__((ext_vector_type(4))) float f32x4;

static __device__ inline unsigned short f2bf(float f) {
    unsigned u = __float_as_uint(f);
    u += 0x7FFF + ((u >> 16) & 1);
    return (unsigned short)(u >> 16);
}

// ---------------- CSR construction: LDS-binned two-pass ----------------
// k_bin: bin edges by bucket (dst>>8) into bucket-partitioned ebuf.
__global__ void __launch_bounds__(256) k_bin(
        const int* __restrict__ src, const int* __restrict__ dst,
        int* __restrict__ gcur, int2* __restrict__ ebuf) {
    __shared__ int cnt[256], lofs[256], dstoff[256];
    __shared__ int stage_s[BIN_CHUNK], stage_d[BIN_CHUNK];
    __shared__ int ws4[4];
    int tid = threadIdx.x;
    cnt[tid] = 0;
    __syncthreads();
    int e0 = blockIdx.x * BIN_CHUNK;
    int ne = N_EDGES - e0; if (ne > BIN_CHUNK) ne = BIN_CHUNK;
    int s[16], d[16], lp[16];
    #pragma unroll
    for (int j = 0; j < 16; ++j) {
        int r = j * 256 + tid;
        if (r < ne) {
            int e = e0 + r;
            s[j] = src[e]; d[j] = dst[e];
            lp[j] = atomicAdd(&cnt[d[j] >> 8], 1);
        } else d[j] = -1;
    }
    __syncthreads();
    // block-wide exclusive scan of cnt -> lofs
    int v = cnt[tid];
    int lane = tid & 63, wid = tid >> 6;
    int incl = v;
    #pragma unroll
    for (int off = 1; off < 64; off <<= 1) {
        int t = __shfl_up(incl, off, 64);
        if (lane >= off) incl += t;
    }
    if (lane == 63) ws4[wid] = incl;
    __syncthreads();
    if (tid == 0) {
        int a = ws4[0];
        #pragma unroll
        for (int j = 1; j < 4; ++j) { a += ws4[j]; ws4[j] = a; }
    }
    __syncthreads();
    if (wid > 0) incl += ws4[wid - 1];
    lofs[tid] = incl - v;
    __syncthreads();
    // stage records sorted by bucket
    #pragma unroll
    for (int j = 0; j < 16; ++j) {
        if (d[j] >= 0) {
            int idx = lofs[d[j] >> 8] + lp[j];
            stage_s[idx] = s[j];
            stage_d[idx] = d[j];
        }
    }
    // reserve global space per bucket
    if (tid < N_BUCKETS && cnt[tid] > 0) {
        int g = atomicAdd(&gcur[tid], cnt[tid]);
        dstoff[tid] = tid * BUCKET_CAP + g - lofs[tid];
    }
    __syncthreads();
    // burst-copy groups to ebuf (consecutive i -> mostly consecutive addresses)
    for (int i = tid; i < ne; i += 256) {
        int dd = stage_d[i];
        int b = dd >> 8;
        ebuf[dstoff[b] + i] = make_int2(stage_s[i], dd);
    }
}

// k_count: per-bucket node histogram (replaces global-atomic k_hist)
__global__ void __launch_bounds__(256) k_count(
        const int2* __restrict__ ebuf, const int* __restrict__ gcur,
        int* __restrict__ counts) {
    __shared__ int lcnt[256];
    int tid = threadIdx.x, b = blockIdx.x;
    lcnt[tid] = 0;
    __syncthreads();
    int ne = gcur[b];
    const int2* eb = ebuf + (size_t)b * BUCKET_CAP;
    for (int i = tid; i < ne; i += 256)
        atomicAdd(&lcnt[eb[i].y & 255], 1);
    __syncthreads();
    int node = b * 256 + tid;
    if (node < N_NODES) counts[node] = lcnt[tid];
}

// Phase A: per-block inclusive scan of 256 counts
__global__ void __launch_bounds__(256) k_scanA(const int* __restrict__ counts,
                                               int* __restrict__ row_start,
                                               int* __restrict__ bsum) {
    int tid = threadIdx.x;
    int i = blockIdx.x * 256 + tid;
    int v = (i < N_NODES) ? counts[i] : 0;
    int lane = tid & 63, wid = tid >> 6;
    int incl = v;
    #pragma unroll
    for (int off = 1; off < 64; off <<= 1) {
        int t = __shfl_up(incl, off, 64);
        if (lane >= off) incl += t;
    }
    __shared__ int ws[4];
    if (lane == 63) ws[wid] = incl;
    __syncthreads();
    if (tid == 0) {
        int a = ws[0];
        #pragma unroll
        for (int j = 1; j < 4; ++j) { a += ws[j]; ws[j] = a; }
    }
    __syncthreads();
    if (wid > 0) incl += ws[wid - 1];
    if (i < N_NODES) row_start[i + 1] = incl;
    if (tid == 255) bsum[blockIdx.x] = incl;
}

// Phase B: exclusive scan of SCAN_NB block totals
__global__ void __launch_bounds__(256) k_scanB(const int* __restrict__ bsum,
                                               int* __restrict__ boff) {
    int tid = threadIdx.x;
    int v = (tid < SCAN_NB) ? bsum[tid] : 0;
    int lane = tid & 63, wid = tid >> 6;
    int incl = v;
    #pragma unroll
    for (int off = 1; off < 64; off <<= 1) {
        int t = __shfl_up(incl, off, 64);
        if (lane >= off) incl += t;
    }
    __shared__ int ws[4];
    if (lane == 63) ws[wid] = incl;
    __syncthreads();
    if (tid == 0) {
        int a = ws[0];
        #pragma unroll
        for (int j = 1; j < 4; ++j) { a += ws[j]; ws[j] = a; }
    }
    __syncthreads();
    if (wid > 0) incl += ws[wid - 1];
    if (tid < SCAN_NB) boff[tid] = incl - v;   // exclusive
}

// Phase C: add block offsets
__global__ void __launch_bounds__(256) k_scanC(int* __restrict__ row_start,
                                               const int* __restrict__ boff) {
    int i = blockIdx.x * 256 + threadIdx.x;
    if (i < N_NODES) row_start[i + 1] += boff[blockIdx.x];
    if (i == 0) row_start[0] = 0;
}

// k_fill2: per-bucket fill; col writes stay in a ~16KB L2-hot window
__global__ void __launch_bounds__(256) k_fill2(
        const int2* __restrict__ ebuf, const int* __restrict__ gcur,
        const int* __restrict__ row_start, int* __restrict__ col) {
    __shared__ int lcur[256], rs[256];
    int tid = threadIdx.x, b = blockIdx.x;
    lcur[tid] = 0;
    int node = b * 256 + tid;
    rs[tid] = (node < N_NODES) ? row_start[node] : 0;
    __syncthreads();
    int ne = gcur[b];
    const int2* eb = ebuf + (size_t)b * BUCKET_CAP;
    for (int i = tid; i < ne; i += 256) {
        int2 e = eb[i];
        int li = e.y & 255;
        int p = atomicAdd(&lcur[li], 1);
        col[rs[li] + p] = e.x;
    }
}

// ---------------- prep: gstart + V1 = W1@a1 (128x8), V2 = W2@a2 (64x2) ----------------

__global__ void __launch_bounds__(1024) k_prep(
        const int* __restrict__ batch,
        const float* __restrict__ W1, const float* __restrict__ a_src1,
        const float* __restrict__ a_dst1,
        const float* __restrict__ W2, const float* __restrict__ a_src2,
        const float* __restrict__ a_dst2,
        int* __restrict__ gstart, float* __restrict__ Vc1, float* __restrict__ Vc2) {
    int tid = threadIdx.x;
    {   // Vc1[k][i]: i 0..3 = src head i, 4..7 = dst head i-4
        int k = tid >> 3, i = tid & 7;
        int h = i & 3;
        const float* a = (i < 4 ? a_src1 : a_dst1) + h * 16;
        float v = 0.f;
        #pragma unroll
        for (int c = 0; c < 16; ++c) v = fmaf(W1[k * 64 + h * 16 + c], a[c], v);
        Vc1[k * 8 + i] = v;
    }
    if (tid < 128) {   // Vc2[k][i]: i 0 = src, 1 = dst
        int k = tid >> 1, i = tid & 1;
        const float* a = i ? a_dst2 : a_src2;
        float v = 0.f;
        #pragma unroll
        for (int c = 0; c < 32; ++c) v = fmaf(W2[k * 32 + c], a[c], v);
        Vc2[k * 2 + i] = v;
    }
    if (tid <= N_GRAPHS) {
        int g = tid;
        int lo = 0, hi = N_NODES;
        while (lo < hi) {
            int mid = (lo + hi) >> 1;
            if (batch[mid] < g) lo = mid + 1; else hi = mid;
        }
        gstart[g] = lo;
    }
}

// ---------------- Layer 1 GEMM (MFMA): xl1 = x@W1 (bf16), esd1 = x@V1 ----------------

__global__ void __launch_bounds__(256) k_gemm1(
        const float* __restrict__ x, const float* __restrict__ W1,
        const float* __restrict__ Vc1,
        float* __restrict__ xl1, float* __restrict__ esd1) {
    __shared__ unsigned short Wt[80][144];   // [n][k] bf16, stride 144 (16B-aligned rows)
    int tid = threadIdx.x;
    for (int i = tid; i < 80 * 128; i += 256) {
        int n = i >> 7, k = i & 127;
        float v = (n < 64) ? W1[k * 64 + n] : (n < 72 ? Vc1[k * 8 + (n - 64)] : 0.f);
        Wt[n][k] = f2bf(v);
    }
    __syncthreads();
    int lane = tid & 63, wid = tid >> 6;
    int tile = blockIdx.x * 4 + wid;
    if (tile >= N_TILES) return;
    int m = lane & 15, kg = lane >> 4;
    int base = tile * 16;
    const float* xr = x + (size_t)(base + m) * D_IN + kg * 8;
    f32x4 acc[5];
    #pragma unroll
    for (int t = 0; t < 5; ++t) acc[t] = (f32x4){0.f, 0.f, 0.f, 0.f};
    #pragma unroll
    for (int s = 0; s < 4; ++s) {
        f32x4 p = ((const f32x4*)(xr + s * 32))[0];
        f32x4 q = ((const f32x4*)(xr + s * 32))[1];
        short8 a;
        a[0] = (short)f2bf(p[0]); a[1] = (short)f2bf(p[1]);
        a[2] = (short)f2bf(p[2]); a[3] = (short)f2bf(p[3]);
        a[4] = (short)f2bf(q[0]); a[5] = (short)f2bf(q[1]);
        a[6] = (short)f2bf(q[2]); a[7] = (short)f2bf(q[3]);
        #pragma unroll
        for (int t = 0; t < 5; ++t) {
            short8 b = *(const short8*)&Wt[t * 16 + m][s * 32 + kg * 8];
            acc[t] = __builtin_amdgcn_mfma_f32_16x16x32_bf16(a, b, acc[t], 0, 0, 0);
        }
    }
    #pragma unroll
    for (int r = 0; r < 4; ++r) {
        int node = base + kg * 4 + r;
        #pragma unroll
        for (int t = 0; t < 4; ++t)
            xl1[(size_t)node * HID + t * 16 + m] = acc[t][r];
        if (m < 8) esd1[node * 8 + m] = acc[4][r];
    }
}

// ---------------- Layer 1 aggregation: pull, one wave per node, 4-way MLP ----------------

__global__ void __launch_bounds__(256) k_agg1(
        const float* __restrict__ xl1, const float* __restrict__ esd1,
        const int* __restrict__ row_start, const int* __restrict__ col,
        const float* __restrict__ b1, float* __restrict__ h1pre) {
    int wid = threadIdx.x >> 6, lane = threadIdx.x & 63;
    int d = blockIdx.x * 4 + wid;
    if (d >= N_NODES) return;
    int h = lane >> 4;
    float edh = esd1[d * 8 + 4 + h];
    float e0 = esd1[d * 8 + h] + edh;       // self loop
    float w0 = __expf(e0 > 0.f ? e0 : NEG * e0);
    float acc = w0 * xl1[(size_t)d * HID + lane];
    float wsum = w0;
    int js = row_start[d], je = row_start[d + 1];
    for (int j0 = js; j0 < je; j0 += 64) {
        int jj = j0 + lane;
        int sv = (jj < je) ? col[jj] : -1;
        int cnt = je - j0; if (cnt > 64) cnt = 64;
        for (int k = 0; k < cnt; k += 4) {
            int s0 = __shfl(sv, k, 64);
            int s1 = __shfl(sv, k + 1, 64);
            int s2 = __shfl(sv, k + 2, 64);
            int s3 = __shfl(sv, k + 3, 64);
            int t0 = s0 < 0 ? d : s0, t1 = s1 < 0 ? d : s1;
            int t2 = s2 < 0 ? d : s2, t3 = s3 < 0 ? d : s3;
            float x0 = xl1[(size_t)t0 * HID + lane];
            float x1 = xl1[(size_t)t1 * HID + lane];
            float x2 = xl1[(size_t)t2 * HID + lane];
            float x3 = xl1[(size_t)t3 * HID + lane];
            float e0_ = esd1[t0 * 8 + h] + edh;
            float e1_ = esd1[t1 * 8 + h] + edh;
            float e2_ = esd1[t2 * 8 + h] + edh;
            float e3_ = esd1[t3 * 8 + h] + edh;
            float w_0 = s0 < 0 ? 0.f : __expf(e0_ > 0.f ? e0_ : NEG * e0_);
            float w_1 = s1 < 0 ? 0.f : __expf(e1_ > 0.f ? e1_ : NEG * e1_);
            float w_2 = s2 < 0 ? 0.f : __expf(e2_ > 0.f ? e2_ : NEG * e2_);
            float w_3 = s3 < 0 ? 0.f : __expf(e3_ > 0.f ? e3_ : NEG * e3_);
            acc = fmaf(w_0, x0, acc); wsum += w_0;
            acc = fmaf(w_1, x1, acc); wsum += w_1;
            acc = fmaf(w_2, x2, acc); wsum += w_2;
            acc = fmaf(w_3, x3, acc); wsum += w_3;
        }
    }
    h1pre[(size_t)d * HID + lane] = acc / wsum + b1[lane];
}

// ---------------- BatchNorm stats (sum, sumsq per channel) ----------------

__global__ void __launch_bounds__(256) k_stats(const float* __restrict__ hpre,
                                               int nch, float* __restrict__ stats) {
    int c = threadIdx.x & (nch - 1);
    int gid = blockIdx.x * blockDim.x + threadIdx.x;
    int r0 = gid / nch;
    int rstride = (gridDim.x * blockDim.x) / nch;
    float s = 0.f, s2 = 0.f;
    for (int n = r0; n < N_NODES; n += rstride) {
        float v = hpre[(size_t)n * nch + c];
        s += v;
        s2 = fmaf(v, v, s2);
    }
    __shared__ float ls[256], ls2[256];
    ls[threadIdx.x] = s;
    ls2[threadIdx.x] = s2;
    __syncthreads();
    if (threadIdx.x < nch) {
        int rows = 256 / nch;
        float a = 0.f, b = 0.f;
        for (int r = 0; r < rows; ++r) {
            a += ls[r * nch + c];
            b += ls2[r * nch + c];
        }
        atomicAdd(&stats[c], a);
        atomicAdd(&stats[nch + c], b);
    }
}

// ---------------- Layer 2 GEMM (MFMA): bn1+relu fused; xl2, esd2 ----------------

__global__ void __launch_bounds__(256) k_gemm2(
        const float* __restrict__ h1pre, const float* __restrict__ stats1,
        const float* __restrict__ g1, const float* __restrict__ be1,
        const float* __restrict__ W2, const float* __restrict__ Vc2,
        float* __restrict__ xl2, float* __restrict__ esd2) {
    __shared__ unsigned short Wt[48][80];   // [n][k] bf16, stride 80 (16B-aligned rows)
    __shared__ float A1s[64], B1s[64];
    int tid = threadIdx.x;
    for (int i = tid; i < 48 * 64; i += 256) {
        int n = i >> 6, k = i & 63;
        float v = (n < 32) ? W2[k * 32 + n]
                : (n == 32) ? Vc2[k * 2] : (n == 33) ? Vc2[k * 2 + 1] : 0.f;
        Wt[n][k] = f2bf(v);
    }
    if (tid < 64) {
        float mu = stats1[tid] * (1.f / N_NODES);
        float var = stats1[64 + tid] * (1.f / N_NODES) - mu * mu;
        float sc = g1[tid] * rsqrtf(var + BN_EPS);
        A1s[tid] = sc;
        B1s[tid] = be1[tid] - mu * sc;
    }
    __syncthreads();
    int lane = tid & 63, wid = tid >> 6;
    int tile = blockIdx.x * 4 + wid;
    if (tile >= N_TILES) return;
    int m = lane & 15, kg = lane >> 4;
    int base = tile * 16;
    const float* hr = h1pre + (size_t)(base + m) * HID + kg * 8;
    f32x4 acc[3];
    #pragma unroll
    for (int t = 0; t < 3; ++t) acc[t] = (f32x4){0.f, 0.f, 0.f, 0.f};
    #pragma unroll
    for (int s = 0; s < 2; ++s) {
        int k0 = s * 32 + kg * 8;
        f32x4 p = ((const f32x4*)(hr + s * 32))[0];
        f32x4 q = ((const f32x4*)(hr + s * 32))[1];
        f32x4 sa = *(const f32x4*)&A1s[k0];
        f32x4 sb = *(const f32x4*)&B1s[k0];
        f32x4 sa2 = *(const f32x4*)&A1s[k0 + 4];
        f32x4 sb2 = *(const f32x4*)&B1s[k0 + 4];
        short8 a;
        #pragma unroll
        for (int j = 0; j < 4; ++j) {
            float v = fmaf(p[j], sa[j], sb[j]);
            a[j] = (short)f2bf(v > 0.f ? v : 0.f);
        }
        #pragma unroll
        for (int j = 0; j < 4; ++j) {
            float v = fmaf(q[j], sa2[j], sb2[j]);
            a[4 + j] = (short)f2bf(v > 0.f ? v : 0.f);
        }
        #pragma unroll
        for (int t = 0; t < 3; ++t) {
            short8 b = *(const short8*)&Wt[t * 16 + m][s * 32 + kg * 8];
            acc[t] = __builtin_amdgcn_mfma_f32_16x16x32_bf16(a, b, acc[t], 0, 0, 0);
        }
    }
    #pragma unroll
    for (int r = 0; r < 4; ++r) {
        int node = base + kg * 4 + r;
        #pragma unroll
        for (int t = 0; t < 2; ++t)
            xl2[(size_t)node * OUT_C + t * 16 + m] = acc[t][r];
        if (m < 2) esd2[node * 2 + m] = acc[2][r];
    }
}

// ---------------- Layer 2 aggregation: 2 nodes per wave, 4-way MLP ----------------

__global__ void __launch_bounds__(256) k_agg2(
        const float* __restrict__ xl2, const float* __restrict__ esd2,
        const int* __restrict__ row_start, const int* __restrict__ col,
        const float* __restrict__ b2, float* __restrict__ h2pre) {
    int lane = threadIdx.x & 63;
    int half = lane >> 5;
    int c = lane & 31;
    int wid = threadIdx.x >> 6;
    int d = (blockIdx.x * 4 + wid) * 2 + half;
    if (d >= N_NODES) return;
    float edh = esd2[d * 2 + 1];
    float e0 = esd2[d * 2] + edh;
    float w0 = __expf(e0 > 0.f ? e0 : NEG * e0);
    float acc = w0 * xl2[(size_t)d * OUT_C + c];
    float wsum = w0;
    int js = row_start[d], je = row_start[d + 1];
    for (int j0 = js; j0 < je; j0 += 32) {
        int jj = j0 + c;
        int sv = (jj < je) ? col[jj] : -1;
        int cnt = je - j0; if (cnt > 32) cnt = 32;
        for (int k = 0; k < cnt; k += 4) {
            int s0 = __shfl(sv, k, 32);
            int s1 = __shfl(sv, k + 1, 32);
            int s2 = __shfl(sv, k + 2, 32);
            int s3 = __shfl(sv, k + 3, 32);
            int t0 = s0 < 0 ? d : s0, t1 = s1 < 0 ? d : s1;
            int t2 = s2 < 0 ? d : s2, t3 = s3 < 0 ? d : s3;
            float x0 = xl2[(size_t)t0 * OUT_C + c];
            float x1 = xl2[(size_t)t1 * OUT_C + c];
            float x2 = xl2[(size_t)t2 * OUT_C + c];
            float x3 = xl2[(size_t)t3 * OUT_C + c];
            float e0_ = esd2[t0 * 2] + edh;
            float e1_ = esd2[t1 * 2] + edh;
            float e2_ = esd2[t2 * 2] + edh;
            float e3_ = esd2[t3 * 2] + edh;
            float w_0 = s0 < 0 ? 0.f : __expf(e0_ > 0.f ? e0_ : NEG * e0_);
            float w_1 = s1 < 0 ? 0.f : __expf(e1_ > 0.f ? e1_ : NEG * e1_);
            float w_2 = s2 < 0 ? 0.f : __expf(e2_ > 0.f ? e2_ : NEG * e2_);
            float w_3 = s3 < 0 ? 0.f : __expf(e3_ > 0.f ? e3_ : NEG * e3_);
            acc = fmaf(w_0, x0, acc); wsum += w_0;
            acc = fmaf(w_1, x1, acc); wsum += w_1;
            acc = fmaf(w_2, x2, acc); wsum += w_2;
            acc = fmaf(w_3, x3, acc); wsum += w_3;
        }
    }
    h2pre[(size_t)d * OUT_C + c] = acc / wsum + b2[c];
}

// ---------------- fused BN2-apply + pool partials ----------------

__global__ void __launch_bounds__(256) k_bnpool(
        const float* __restrict__ h2pre, const float* __restrict__ stats2,
        const float* __restrict__ g2, const float* __restrict__ be2,
        const int* __restrict__ gstart, float* __restrict__ out,
        float* __restrict__ pfeat) {
    __shared__ float A2[OUT_C], B2[OUT_C];
    if (threadIdx.x < OUT_C) {
        int cc = threadIdx.x;
        float mu = stats2[cc] * (1.f / N_NODES);
        float var = stats2[OUT_C + cc] * (1.f / N_NODES) - mu * mu;
        float sc = g2[cc] * rsqrtf(var + BN_EPS);
        A2[cc] = sc;
        B2[cc] = be2[cc] - mu * sc;
    }
    __syncthreads();
    int g = blockIdx.x >> 2, part = blockIdx.x & 3;
    int s = gstart[g], e = gstart[g + 1];
    int len = e - s;
    int q = (len + 3) >> 2;
    int ps = s + part * q;
    int pe = ps + q; if (pe > e) pe = e;
    int c = threadIdx.x & 31, r = threadIdx.x >> 5;   // 8 row-lanes
    float sum = 0.f, mx = -INFINITY;
    for (int n = ps + r; n < pe; n += 8) {
        float v = fmaf(h2pre[(size_t)n * OUT_C + c], A2[c], B2[c]);
        out[(size_t)n * OUT_C + c] = v;
        sum += v;
        mx = fmaxf(mx, v);
    }
    __shared__ float lsum[256], lmax[256];
    lsum[threadIdx.x] = sum;
    lmax[threadIdx.x] = mx;
    __syncthreads();
    if (threadIdx.x < 32) {
        float ts = 0.f, tm = -INFINITY;
        for (int rr = 0; rr < 8; ++rr) {
            ts += lsum[rr * 32 + c];
            tm = fmaxf(tm, lmax[rr * 32 + c]);
        }
        pfeat[blockIdx.x * 64 + c] = ts;
        pfeat[blockIdx.x * 64 + 32 + c] = tm;
    }
}

// ---------------- MLP head (+pool combine) -> graph_emb ----------------

__global__ void __launch_bounds__(256) k_mlp(
        const float* __restrict__ pfeat, const int* __restrict__ gstart,
        const float* __restrict__ fcW1, const float* __restrict__ fcb1,
        const float* __restrict__ fcW2, const float* __restrict__ fcb2,
        float* __restrict__ out) {
    __shared__ float gf[N_GRAPHS * 64];     // 16 KB
    __shared__ float t1[N_GRAPHS * OUT_C];  // 8 KB
    int tid = threadIdx.x;
    for (int i = tid; i < N_GRAPHS * 32; i += 256) {
        int g = i >> 5, c = i & 31;
        float sm = 0.f, mx = -INFINITY;
        #pragma unroll
        for (int p = 0; p < 4; ++p) {
            sm += pfeat[(g * 4 + p) * 64 + c];
            mx = fmaxf(mx, pfeat[(g * 4 + p) * 64 + 32 + c]);
        }
        int cnt = gstart[g + 1] - gstart[g];
        gf[g * 64 + c] = (cnt > 0) ? sm / (float)cnt : 0.f;
        gf[g * 64 + 32 + c] = (cnt > 0) ? mx : 0.f;
    }
    __syncthreads();
    for (int i = tid; i < N_GRAPHS * OUT_C; i += 256) {
        int g = i >> 5, j = i & 31;
        float a = fcb1[j];
        for (int k = 0; k < 64; ++k) a = fmaf(gf[g * 64 + k], fcW1[k * OUT_C + j], a);
        t1[i] = a > 0.f ? a : 0.f;
    }
    __syncthreads();
    for (int i = tid; i < N_GRAPHS * OUT_C; i += 256) {
        int g = i >> 5, oc = i & 31;
        float a = fcb2[oc];
        for (int k = 0; k < OUT_C; ++k) a = fmaf(t1[g * OUT_C + k], fcW2[k * OUT_C + oc], a);
        out[(size_t)N_NODES * OUT_C + g * OUT_C + oc] = a;
    }
}

// ---------------- launch ----------------

extern "C" void kernel_launch(void* const* d_in, const int* in_sizes, int n_in,
                              void* d_out, int out_size, void* d_ws, size_t ws_size,
                              hipStream_t stream) {
    (void)in_sizes; (void)n_in; (void)out_size; (void)ws_size;
    const float* x      = (const float*)d_in[0];
    const int*   ei     = (const int*)d_in[1];
    const int*   batch  = (const int*)d_in[2];
    const float* W1     = (const float*)d_in[3];
    const float* a_src1 = (const float*)d_in[4];
    const float* a_dst1 = (const float*)d_in[5];
    const float* b1     = (const float*)d_in[6];
    const float* g1     = (const float*)d_in[7];
    const float* be1    = (const float*)d_in[8];
    const float* W2     = (const float*)d_in[9];
    const float* a_src2 = (const float*)d_in[10];
    const float* a_dst2 = (const float*)d_in[11];
    const float* b2     = (const float*)d_in[12];
    const float* g2     = (const float*)d_in[13];
    const float* be2    = (const float*)d_in[14];
    const float* fcW1   = (const float*)d_in[15];
    const float* fcb1   = (const float*)d_in[16];
    const float* fcW2   = (const float*)d_in[17];
    const float* fcb2   = (const float*)d_in[18];
    const int* srcv = ei;
    const int* dstv = ei + N_EDGES;
    float* out = (float*)d_out;

    char* w = (char*)d_ws;
    size_t o = 0;
    #define ALLOC(nbytes) (w + o); o = (o + (size_t)(nbytes) + 15) & ~(size_t)15
    int*   gcur      = (int*)ALLOC(N_BUCKETS * 4);
    float* stats1    = (float*)ALLOC(128 * 4);
    float* stats2    = (float*)ALLOC(64 * 4);
    size_t zero_bytes = o;                       // everything above must start at 0
    int*   counts    = (int*)ALLOC((size_t)N_NODES * 4);
    int*   row_start = (int*)ALLOC((size_t)(N_NODES + 2) * 4);
    int*   gst       = (int*)ALLOC(66 * 4);
    int*   bsum      = (int*)ALLOC(SCAN_NB * 4);
    int*   boff      = (int*)ALLOC(SCAN_NB * 4);
    int*   col       = (int*)ALLOC((size_t)N_EDGES * 4);
    float* Vc1       = (float*)ALLOC(128 * 8 * 4);
    float* Vc2       = (float*)ALLOC(64 * 2 * 4);
    float* xl1       = (float*)ALLOC((size_t)N_NODES * HID * 4);
    float* esd1      = (float*)ALLOC((size_t)N_NODES * 8 * 4);
    float* h1pre     = (float*)ALLOC((size_t)N_NODES * HID * 4);
    float* pfeat     = (float*)ALLOC(256 * 64 * 4);
    #undef ALLOC
    // aliases (lifetimes disjoint):
    int2*  ebuf  = (int2*)xl1;                   // 8.03MB <= 12.8MB; dead before k_gemm1
    float* xl2   = xl1;                          // xl1 dead after k_agg1
    float* esd2  = xl1 + (size_t)N_NODES * OUT_C;
    float* h2pre = h1pre;                        // h1pre dead after k_gemm2

    hipMemsetAsync(d_ws, 0, zero_bytes, stream);
    k_bin   <<<BIN_NB, 256, 0, stream>>>(srcv, dstv, gcur, ebuf);
    k_count <<<N_BUCKETS, 256, 0, stream>>>(ebuf, gcur, counts);
    k_scanA <<<SCAN_NB, 256, 0, stream>>>(counts, row_start, bsum);
    k_scanB <<<1, 256, 0, stream>>>(bsum, boff);
    k_scanC <<<SCAN_NB, 256, 0, stream>>>(row_start, boff);
    k_fill2 <<<N_BUCKETS, 256, 0, stream>>>(ebuf, gcur, row_start, col);
    k_prep  <<<1, 1024, 0, stream>>>(batch, W1, a_src1, a_dst1, W2, a_src2, a_dst2,
                                     gst, Vc1, Vc2);
    k_gemm1 <<<(N_TILES + 3) / 4, 256, 0, stream>>>(x, W1, Vc1, xl1, esd1);
    k_agg1  <<<(N_NODES + 3) / 4, 256, 0, stream>>>(xl1, esd1, row_start, col, b1, h1pre);
    k_stats <<<256, 256, 0, stream>>>(h1pre, HID, stats1);
    k_gemm2 <<<(N_TILES + 3) / 4, 256, 0, stream>>>(h1pre, stats1, g1, be1, W2, Vc2,
                                                    xl2, esd2);
    k_agg2  <<<(N_NODES + 7) / 8, 256, 0, stream>>>(xl2, esd2, row_start, col, b2, h2pre);
    k_stats <<<256, 256, 0, stream>>>(h2pre, OUT_C, stats2);
    k_bnpool<<<256, 256, 0, stream>>>(h2pre, stats2, g2, be2, gst, out, pfeat);
    k_mlp   <<<1, 256, 0, stream>>>(pfeat, gst, fcW1, fcb1, fcW2, fcb2, out);
}

// Round 5
// 282.318 us; speedup vs baseline: 1.9968x; 1.0799x over previous
//
#include <hip/hip_runtime.h>
#include <math.h>

#define N_NODES 50000
#define N_EDGES 800000
#define N_GRAPHS 64
#define D_IN 128
#define HID 64
#define OUT_C 32
#define NEG 0.2f
#define BN_EPS 1e-5f
#define N_TILES 3125    // N_NODES / 16
#define SCAN_NB 196     // ceil(N_NODES / 256)
#define N_BUCKETS 196   // bucket = dst >> 8
#define BIN_CHUNK 4096
#define BIN_NB 196      // ceil(N_EDGES / BIN_CHUNK)
#define BUCKET_CAP 5120 // mean 4082, sd ~64 -> 16 sigma margin
#define PHANTOM N_NODES // sentinel node: xl rows = 0, esd = -1e30 -> weight 0

typedef __attribute__((ext_vector_type(8))) short short8;
typedef __attribute__((ext_vector_type(4))) float f32x4;

static __device__ inline unsigned short f2bf(float f) {
    unsigned u = __float_as_uint(f);
    u += 0x7FFF + ((u >> 16) & 1);
    return (unsigned short)(u >> 16);
}
static __device__ inline float bf2f(unsigned short u) {
    return __uint_as_float((unsigned)u << 16);
}

// ---------------- CSR construction: LDS-binned two-pass, 4B records ----------------
// record = (src << 8) | (dst & 255); bucket = dst >> 8. src < 65536 so this fits.

__global__ void __launch_bounds__(256) k_bin(
        const int* __restrict__ src, const int* __restrict__ dst,
        int* __restrict__ gcur, unsigned* __restrict__ ebuf) {
    __shared__ int cnt[256], lofs[256], dstoff[256];
    __shared__ unsigned stage[BIN_CHUNK];    // 16 KB
    __shared__ int ws4[4];
    int tid = threadIdx.x;
    cnt[tid] = 0;
    __syncthreads();
    int e0 = blockIdx.x * BIN_CHUNK;
    int ne = N_EDGES - e0; if (ne > BIN_CHUNK) ne = BIN_CHUNK;
    unsigned rec[16]; int bkt[16], lp[16];
    #pragma unroll
    for (int j = 0; j < 16; ++j) {
        int r = j * 256 + tid;
        if (r < ne) {
            int e = e0 + r;
            int s = src[e], d = dst[e];
            rec[j] = ((unsigned)s << 8) | (unsigned)(d & 255);
            bkt[j] = d >> 8;
            lp[j] = atomicAdd(&cnt[bkt[j]], 1);
        } else bkt[j] = -1;
    }
    __syncthreads();
    // block-wide exclusive scan of cnt -> lofs
    int v = cnt[tid];
    int lane = tid & 63, wid = tid >> 6;
    int incl = v;
    #pragma unroll
    for (int off = 1; off < 64; off <<= 1) {
        int t = __shfl_up(incl, off, 64);
        if (lane >= off) incl += t;
    }
    if (lane == 63) ws4[wid] = incl;
    __syncthreads();
    if (tid == 0) {
        int a = ws4[0];
        #pragma unroll
        for (int j = 1; j < 4; ++j) { a += ws4[j]; ws4[j] = a; }
    }
    __syncthreads();
    if (wid > 0) incl += ws4[wid - 1];
    lofs[tid] = incl - v;
    __syncthreads();
    #pragma unroll
    for (int j = 0; j < 16; ++j)
        if (bkt[j] >= 0) stage[lofs[bkt[j]] + lp[j]] = rec[j];
    if (tid < N_BUCKETS && cnt[tid] > 0) {
        int g = atomicAdd(&gcur[tid], cnt[tid]);
        dstoff[tid] = tid * BUCKET_CAP + g - lofs[tid];
    }
    __syncthreads();
    for (int i = tid; i < ne; i += 256) {
        unsigned r = stage[i];
        // bucket of this record: find via its position -> use dst low byte? need bucket.
        // position i is within the contiguous group of its bucket; recover bucket by
        // binary search is overkill: recompute from lofs is not direct. Instead store
        // bucket in unused high bits? src<<8 uses bits 8..24; bits 25..31 free only if
        // src<2^17 (yes). But bucket needs 8 bits. Use separate approach: group id via
        // lofs table scan is costly; simplest: stage dst low byte + bucket:
        // we instead re-derive: NOT POSSIBLE from rec alone. Use second stage array.
        (void)r;
    }
    // NOTE: fallthrough replaced below (see stage_b)
}

// The above k_bin needs bucket per staged record for the scatter; use a compact
// second stage array of bucket bytes.
__global__ void __launch_bounds__(256) k_bin2(
        const int* __restrict__ src, const int* __restrict__ dst,
        int* __restrict__ gcur, unsigned* __restrict__ ebuf) {
    __shared__ int cnt[256], lofs[256], dstoff[256];
    __shared__ unsigned stage[BIN_CHUNK];          // 16 KB
    __shared__ unsigned char stage_b[BIN_CHUNK];   // 4 KB bucket ids
    __shared__ int ws4[4];
    int tid = threadIdx.x;
    cnt[tid] = 0;
    __syncthreads();
    int e0 = blockIdx.x * BIN_CHUNK;
    int ne = N_EDGES - e0; if (ne > BIN_CHUNK) ne = BIN_CHUNK;
    unsigned rec[16]; int bkt[16], lp[16];
    #pragma unroll
    for (int j = 0; j < 16; ++j) {
        int r = j * 256 + tid;
        if (r < ne) {
            int e = e0 + r;
            int s = src[e], d = dst[e];
            rec[j] = ((unsigned)s << 8) | (unsigned)(d & 255);
            bkt[j] = d >> 8;
            lp[j] = atomicAdd(&cnt[bkt[j]], 1);
        } else bkt[j] = -1;
    }
    __syncthreads();
    int v = cnt[tid];
    int lane = tid & 63, wid = tid >> 6;
    int incl = v;
    #pragma unroll
    for (int off = 1; off < 64; off <<= 1) {
        int t = __shfl_up(incl, off, 64);
        if (lane >= off) incl += t;
    }
    if (lane == 63) ws4[wid] = incl;
    __syncthreads();
    if (tid == 0) {
        int a = ws4[0];
        #pragma unroll
        for (int j = 1; j < 4; ++j) { a += ws4[j]; ws4[j] = a; }
    }
    __syncthreads();
    if (wid > 0) incl += ws4[wid - 1];
    lofs[tid] = incl - v;
    __syncthreads();
    #pragma unroll
    for (int j = 0; j < 16; ++j) {
        if (bkt[j] >= 0) {
            int idx = lofs[bkt[j]] + lp[j];
            stage[idx] = rec[j];
            stage_b[idx] = (unsigned char)bkt[j];
        }
    }
    if (tid < N_BUCKETS && cnt[tid] > 0) {
        int g = atomicAdd(&gcur[tid], cnt[tid]);
        dstoff[tid] = tid * BUCKET_CAP + g - lofs[tid];
    }
    __syncthreads();
    for (int i = tid; i < ne; i += 256) {
        int b = stage_b[i];
        ebuf[dstoff[b] + i] = stage[i];
    }
}

// k_count: per-bucket node histogram
__global__ void __launch_bounds__(256) k_count(
        const unsigned* __restrict__ ebuf, const int* __restrict__ gcur,
        int* __restrict__ counts) {
    __shared__ int lcnt[256];
    int tid = threadIdx.x, b = blockIdx.x;
    lcnt[tid] = 0;
    __syncthreads();
    int ne = gcur[b];
    const unsigned* eb = ebuf + (size_t)b * BUCKET_CAP;
    for (int i = tid; i < ne; i += 256)
        atomicAdd(&lcnt[eb[i] & 255u], 1);
    __syncthreads();
    int node = b * 256 + tid;
    if (node < N_NODES) counts[node] = lcnt[tid];
}

// Phase A: per-block inclusive scan of PADDED counts (rounded up to multiple of 4)
__global__ void __launch_bounds__(256) k_scanA(const int* __restrict__ counts,
                                               int* __restrict__ row_start,
                                               int* __restrict__ bsum) {
    int tid = threadIdx.x;
    int i = blockIdx.x * 256 + tid;
    int v = (i < N_NODES) ? ((counts[i] + 3) & ~3) : 0;
    int lane = tid & 63, wid = tid >> 6;
    int incl = v;
    #pragma unroll
    for (int off = 1; off < 64; off <<= 1) {
        int t = __shfl_up(incl, off, 64);
        if (lane >= off) incl += t;
    }
    __shared__ int ws[4];
    if (lane == 63) ws[wid] = incl;
    __syncthreads();
    if (tid == 0) {
        int a = ws[0];
        #pragma unroll
        for (int j = 1; j < 4; ++j) { a += ws[j]; ws[j] = a; }
    }
    __syncthreads();
    if (wid > 0) incl += ws[wid - 1];
    if (i < N_NODES) row_start[i + 1] = incl;
    if (tid == 255) bsum[blockIdx.x] = incl;
}

__global__ void __launch_bounds__(256) k_scanB(const int* __restrict__ bsum,
                                               int* __restrict__ boff) {
    int tid = threadIdx.x;
    int v = (tid < SCAN_NB) ? bsum[tid] : 0;
    int lane = tid & 63, wid = tid >> 6;
    int incl = v;
    #pragma unroll
    for (int off = 1; off < 64; off <<= 1) {
        int t = __shfl_up(incl, off, 64);
        if (lane >= off) incl += t;
    }
    __shared__ int ws[4];
    if (lane == 63) ws[wid] = incl;
    __syncthreads();
    if (tid == 0) {
        int a = ws[0];
        #pragma unroll
        for (int j = 1; j < 4; ++j) { a += ws[j]; ws[j] = a; }
    }
    __syncthreads();
    if (wid > 0) incl += ws[wid - 1];
    if (tid < SCAN_NB) boff[tid] = incl - v;
}

__global__ void __launch_bounds__(256) k_scanC(int* __restrict__ row_start,
                                               const int* __restrict__ boff) {
    int i = blockIdx.x * 256 + threadIdx.x;
    if (i < N_NODES) row_start[i + 1] += boff[blockIdx.x];
    if (i == 0) row_start[0] = 0;
}

// k_fill2: per-bucket fill; pad slots get PHANTOM
__global__ void __launch_bounds__(256) k_fill2(
        const unsigned* __restrict__ ebuf, const int* __restrict__ gcur,
        const int* __restrict__ row_start, const int* __restrict__ counts,
        int* __restrict__ col) {
    __shared__ int lcur[256], rs[256];
    int tid = threadIdx.x, b = blockIdx.x;
    lcur[tid] = 0;
    int node = b * 256 + tid;
    int myrs = (node < N_NODES) ? row_start[node] : 0;
    rs[tid] = myrs;
    __syncthreads();
    int ne = gcur[b];
    const unsigned* eb = ebuf + (size_t)b * BUCKET_CAP;
    for (int i = tid; i < ne; i += 256) {
        unsigned e = eb[i];
        int li = e & 255u;
        int p = atomicAdd(&lcur[li], 1);
        col[rs[li] + p] = (int)(e >> 8);
    }
    // pad to multiple of 4 with phantom node (weight underflows to 0)
    if (node < N_NODES) {
        int cnt = counts[node];
        int pe = (cnt + 3) & ~3;
        for (int j = cnt; j < pe; ++j) col[myrs + j] = PHANTOM;
    }
}

// ---------------- prep: gstart + V1/V2 + phantom rows for layer 1 ----------------

__global__ void __launch_bounds__(1024) k_prep(
        const int* __restrict__ batch,
        const float* __restrict__ W1, const float* __restrict__ a_src1,
        const float* __restrict__ a_dst1,
        const float* __restrict__ W2, const float* __restrict__ a_src2,
        const float* __restrict__ a_dst2,
        int* __restrict__ gstart, float* __restrict__ Vc1, float* __restrict__ Vc2,
        unsigned short* __restrict__ xl1b, float* __restrict__ esd1) {
    int tid = threadIdx.x;
    {   // Vc1[k][i]: i 0..3 = src head i, 4..7 = dst head i-4
        int k = tid >> 3, i = tid & 7;
        int h = i & 3;
        const float* a = (i < 4 ? a_src1 : a_dst1) + h * 16;
        float v = 0.f;
        #pragma unroll
        for (int c = 0; c < 16; ++c) v = fmaf(W1[k * 64 + h * 16 + c], a[c], v);
        Vc1[k * 8 + i] = v;
    }
    if (tid < 128) {   // Vc2[k][i]: i 0 = src, 1 = dst
        int k = tid >> 1, i = tid & 1;
        const float* a = i ? a_dst2 : a_src2;
        float v = 0.f;
        #pragma unroll
        for (int c = 0; c < 32; ++c) v = fmaf(W2[k * 32 + c], a[c], v);
        Vc2[k * 2 + i] = v;
    }
    if (tid <= N_GRAPHS) {
        int g = tid;
        int lo = 0, hi = N_NODES;
        while (lo < hi) {
            int mid = (lo + hi) >> 1;
            if (batch[mid] < g) lo = mid + 1; else hi = mid;
        }
        gstart[g] = lo;
    }
    // phantom rows (layer 1)
    if (tid < HID) xl1b[(size_t)PHANTOM * HID + tid] = 0;
    if (tid >= 1016) esd1[(size_t)PHANTOM * 8 + (tid - 1016)] = -1e30f;
}

// ---------------- Layer 1 GEMM (MFMA): xl1b (bf16) = x@W1, esd1 = x@V1 ----------------

__global__ void __launch_bounds__(256) k_gemm1(
        const float* __restrict__ x, const float* __restrict__ W1,
        const float* __restrict__ Vc1,
        unsigned short* __restrict__ xl1b, float* __restrict__ esd1) {
    __shared__ unsigned short Wt[80][144];
    int tid = threadIdx.x;
    for (int i = tid; i < 80 * 128; i += 256) {
        int n = i >> 7, k = i & 127;
        float v = (n < 64) ? W1[k * 64 + n] : (n < 72 ? Vc1[k * 8 + (n - 64)] : 0.f);
        Wt[n][k] = f2bf(v);
    }
    __syncthreads();
    int lane = tid & 63, wid = tid >> 6;
    int tile = blockIdx.x * 4 + wid;
    if (tile >= N_TILES) return;
    int m = lane & 15, kg = lane >> 4;
    int base = tile * 16;
    const float* xr = x + (size_t)(base + m) * D_IN + kg * 8;
    f32x4 acc[5];
    #pragma unroll
    for (int t = 0; t < 5; ++t) acc[t] = (f32x4){0.f, 0.f, 0.f, 0.f};
    #pragma unroll
    for (int s = 0; s < 4; ++s) {
        f32x4 p = ((const f32x4*)(xr + s * 32))[0];
        f32x4 q = ((const f32x4*)(xr + s * 32))[1];
        short8 a;
        a[0] = (short)f2bf(p[0]); a[1] = (short)f2bf(p[1]);
        a[2] = (short)f2bf(p[2]); a[3] = (short)f2bf(p[3]);
        a[4] = (short)f2bf(q[0]); a[5] = (short)f2bf(q[1]);
        a[6] = (short)f2bf(q[2]); a[7] = (short)f2bf(q[3]);
        #pragma unroll
        for (int t = 0; t < 5; ++t) {
            short8 b = *(const short8*)&Wt[t * 16 + m][s * 32 + kg * 8];
            acc[t] = __builtin_amdgcn_mfma_f32_16x16x32_bf16(a, b, acc[t], 0, 0, 0);
        }
    }
    #pragma unroll
    for (int r = 0; r < 4; ++r) {
        int node = base + kg * 4 + r;
        #pragma unroll
        for (int t = 0; t < 4; ++t)
            xl1b[(size_t)node * HID + t * 16 + m] = f2bf(acc[t][r]);
        if (m < 8) esd1[node * 8 + m] = acc[4][r];
    }
}

// ---------------- Layer 1 aggregation: wave/node, padded rows, bf16 gather ----------------

__global__ void __launch_bounds__(256) k_agg1(
        const unsigned short* __restrict__ xl1b, const float* __restrict__ esd1,
        const int* __restrict__ row_start, const int* __restrict__ col,
        const float* __restrict__ b1, float* __restrict__ h1pre) {
    int wid = threadIdx.x >> 6, lane = threadIdx.x & 63;
    int d = blockIdx.x * 4 + wid;
    if (d >= N_NODES) return;
    int h = lane >> 4;
    float edh = esd1[d * 8 + 4 + h];
    float e0 = esd1[d * 8 + h] + edh;       // self loop
    float l0 = fmaxf(e0, NEG * e0);
    float w0 = __expf(l0);
    float acc = w0 * bf2f(xl1b[(size_t)d * HID + lane]);
    float wsum = w0;
    int js = row_start[d], je = row_start[d + 1];   // padded length, %4 == 0
    for (int j0 = js; j0 < je; j0 += 64) {
        int sv = col[j0 + lane];                     // slack-allocated: safe overread
        int cnt = je - j0; if (cnt > 64) cnt = 64;
        for (int k = 0; k < cnt; k += 4) {
            int s0 = __shfl(sv, k, 64);
            int s1 = __shfl(sv, k + 1, 64);
            int s2 = __shfl(sv, k + 2, 64);
            int s3 = __shfl(sv, k + 3, 64);
            float x0 = bf2f(xl1b[(size_t)s0 * HID + lane]);
            float x1 = bf2f(xl1b[(size_t)s1 * HID + lane]);
            float x2 = bf2f(xl1b[(size_t)s2 * HID + lane]);
            float x3 = bf2f(xl1b[(size_t)s3 * HID + lane]);
            float e0_ = esd1[s0 * 8 + h] + edh;
            float e1_ = esd1[s1 * 8 + h] + edh;
            float e2_ = esd1[s2 * 8 + h] + edh;
            float e3_ = esd1[s3 * 8 + h] + edh;
            float w_0 = __expf(fmaxf(e0_, NEG * e0_));
            float w_1 = __expf(fmaxf(e1_, NEG * e1_));
            float w_2 = __expf(fmaxf(e2_, NEG * e2_));
            float w_3 = __expf(fmaxf(e3_, NEG * e3_));
            acc = fmaf(w_0, x0, acc); wsum += w_0;
            acc = fmaf(w_1, x1, acc); wsum += w_1;
            acc = fmaf(w_2, x2, acc); wsum += w_2;
            acc = fmaf(w_3, x3, acc); wsum += w_3;
        }
    }
    h1pre[(size_t)d * HID + lane] = acc / wsum + b1[lane];
}

// ---------------- BatchNorm stats ----------------

__global__ void __launch_bounds__(256) k_stats(const float* __restrict__ hpre,
                                               int nch, float* __restrict__ stats) {
    int c = threadIdx.x & (nch - 1);
    int gid = blockIdx.x * blockDim.x + threadIdx.x;
    int r0 = gid / nch;
    int rstride = (gridDim.x * blockDim.x) / nch;
    float s = 0.f, s2 = 0.f;
    for (int n = r0; n < N_NODES; n += rstride) {
        float v = hpre[(size_t)n * nch + c];
        s += v;
        s2 = fmaf(v, v, s2);
    }
    __shared__ float ls[256], ls2[256];
    ls[threadIdx.x] = s;
    ls2[threadIdx.x] = s2;
    __syncthreads();
    if (threadIdx.x < nch) {
        int rows = 256 / nch;
        float a = 0.f, b = 0.f;
        for (int r = 0; r < rows; ++r) {
            a += ls[r * nch + c];
            b += ls2[r * nch + c];
        }
        atomicAdd(&stats[c], a);
        atomicAdd(&stats[nch + c], b);
    }
}

// ---------------- Layer 2 GEMM (MFMA): bn1+relu fused; xl2b (bf16), esd2 ----------------

__global__ void __launch_bounds__(256) k_gemm2(
        const float* __restrict__ h1pre, const float* __restrict__ stats1,
        const float* __restrict__ g1, const float* __restrict__ be1,
        const float* __restrict__ W2, const float* __restrict__ Vc2,
        unsigned short* __restrict__ xl2b, float* __restrict__ esd2) {
    __shared__ unsigned short Wt[48][80];
    __shared__ float A1s[64], B1s[64];
    int tid = threadIdx.x;
    for (int i = tid; i < 48 * 64; i += 256) {
        int n = i >> 6, k = i & 63;
        float v = (n < 32) ? W2[k * 32 + n]
                : (n == 32) ? Vc2[k * 2] : (n == 33) ? Vc2[k * 2 + 1] : 0.f;
        Wt[n][k] = f2bf(v);
    }
    if (tid < 64) {
        float mu = stats1[tid] * (1.f / N_NODES);
        float var = stats1[64 + tid] * (1.f / N_NODES) - mu * mu;
        float sc = g1[tid] * rsqrtf(var + BN_EPS);
        A1s[tid] = sc;
        B1s[tid] = be1[tid] - mu * sc;
    }
    if (blockIdx.x == 0) {   // phantom rows (layer 2)
        if (tid < OUT_C) xl2b[(size_t)PHANTOM * OUT_C + tid] = 0;
        if (tid >= 254) esd2[(size_t)PHANTOM * 2 + (tid - 254)] = -1e30f;
    }
    __syncthreads();
    int lane = tid & 63, wid = tid >> 6;
    int tile = blockIdx.x * 4 + wid;
    if (tile >= N_TILES) return;
    int m = lane & 15, kg = lane >> 4;
    int base = tile * 16;
    const float* hr = h1pre + (size_t)(base + m) * HID + kg * 8;
    f32x4 acc[3];
    #pragma unroll
    for (int t = 0; t < 3; ++t) acc[t] = (f32x4){0.f, 0.f, 0.f, 0.f};
    #pragma unroll
    for (int s = 0; s < 2; ++s) {
        int k0 = s * 32 + kg * 8;
        f32x4 p = ((const f32x4*)(hr + s * 32))[0];
        f32x4 q = ((const f32x4*)(hr + s * 32))[1];
        f32x4 sa = *(const f32x4*)&A1s[k0];
        f32x4 sb = *(const f32x4*)&B1s[k0];
        f32x4 sa2 = *(const f32x4*)&A1s[k0 + 4];
        f32x4 sb2 = *(const f32x4*)&B1s[k0 + 4];
        short8 a;
        #pragma unroll
        for (int j = 0; j < 4; ++j) {
            float v = fmaf(p[j], sa[j], sb[j]);
            a[j] = (short)f2bf(v > 0.f ? v : 0.f);
        }
        #pragma unroll
        for (int j = 0; j < 4; ++j) {
            float v = fmaf(q[j], sa2[j], sb2[j]);
            a[4 + j] = (short)f2bf(v > 0.f ? v : 0.f);
        }
        #pragma unroll
        for (int t = 0; t < 3; ++t) {
            short8 b = *(const short8*)&Wt[t * 16 + m][s * 32 + kg * 8];
            acc[t] = __builtin_amdgcn_mfma_f32_16x16x32_bf16(a, b, acc[t], 0, 0, 0);
        }
    }
    #pragma unroll
    for (int r = 0; r < 4; ++r) {
        int node = base + kg * 4 + r;
        #pragma unroll
        for (int t = 0; t < 2; ++t)
            xl2b[(size_t)node * OUT_C + t * 16 + m] = f2bf(acc[t][r]);
        if (m < 2) esd2[node * 2 + m] = acc[2][r];
    }
}

// ---------------- Layer 2 aggregation: 2 nodes/wave, padded, bf16 gather ----------------

__global__ void __launch_bounds__(256) k_agg2(
        const unsigned short* __restrict__ xl2b, const float* __restrict__ esd2,
        const int* __restrict__ row_start, const int* __restrict__ col,
        const float* __restrict__ b2, float* __restrict__ h2pre) {
    int lane = threadIdx.x & 63;
    int half = lane >> 5;
    int c = lane & 31;
    int wid = threadIdx.x >> 6;
    int d = (blockIdx.x * 4 + wid) * 2 + half;
    if (d >= N_NODES) return;
    float edh = esd2[d * 2 + 1];
    float e0 = esd2[d * 2] + edh;
    float w0 = __expf(fmaxf(e0, NEG * e0));
    float acc = w0 * bf2f(xl2b[(size_t)d * OUT_C + c]);
    float wsum = w0;
    int js = row_start[d], je = row_start[d + 1];
    for (int j0 = js; j0 < je; j0 += 32) {
        int sv = col[j0 + c];
        int cnt = je - j0; if (cnt > 32) cnt = 32;
        for (int k = 0; k < cnt; k += 4) {
            int s0 = __shfl(sv, k, 32);
            int s1 = __shfl(sv, k + 1, 32);
            int s2 = __shfl(sv, k + 2, 32);
            int s3 = __shfl(sv, k + 3, 32);
            float x0 = bf2f(xl2b[(size_t)s0 * OUT_C + c]);
            float x1 = bf2f(xl2b[(size_t)s1 * OUT_C + c]);
            float x2 = bf2f(xl2b[(size_t)s2 * OUT_C + c]);
            float x3 = bf2f(xl2b[(size_t)s3 * OUT_C + c]);
            float e0_ = esd2[s0 * 2] + edh;
            float e1_ = esd2[s1 * 2] + edh;
            float e2_ = esd2[s2 * 2] + edh;
            float e3_ = esd2[s3 * 2] + edh;
            float w_0 = __expf(fmaxf(e0_, NEG * e0_));
            float w_1 = __expf(fmaxf(e1_, NEG * e1_));
            float w_2 = __expf(fmaxf(e2_, NEG * e2_));
            float w_3 = __expf(fmaxf(e3_, NEG * e3_));
            acc = fmaf(w_0, x0, acc); wsum += w_0;
            acc = fmaf(w_1, x1, acc); wsum += w_1;
            acc = fmaf(w_2, x2, acc); wsum += w_2;
            acc = fmaf(w_3, x3, acc); wsum += w_3;
        }
    }
    h2pre[(size_t)d * OUT_C + c] = acc / wsum + b2[c];
}

// ---------------- fused BN2-apply + pool partials ----------------

__global__ void __launch_bounds__(256) k_bnpool(
        const float* __restrict__ h2pre, const float* __restrict__ stats2,
        const float* __restrict__ g2, const float* __restrict__ be2,
        const int* __restrict__ gstart, float* __restrict__ out,
        float* __restrict__ pfeat) {
    __shared__ float A2[OUT_C], B2[OUT_C];
    if (threadIdx.x < OUT_C) {
        int cc = threadIdx.x;
        float mu = stats2[cc] * (1.f / N_NODES);
        float var = stats2[OUT_C + cc] * (1.f / N_NODES) - mu * mu;
        float sc = g2[cc] * rsqrtf(var + BN_EPS);
        A2[cc] = sc;
        B2[cc] = be2[cc] - mu * sc;
    }
    __syncthreads();
    int g = blockIdx.x >> 2, part = blockIdx.x & 3;
    int s = gstart[g], e = gstart[g + 1];
    int len = e - s;
    int q = (len + 3) >> 2;
    int ps = s + part * q;
    int pe = ps + q; if (pe > e) pe = e;
    int c = threadIdx.x & 31, r = threadIdx.x >> 5;
    float sum = 0.f, mx = -INFINITY;
    for (int n = ps + r; n < pe; n += 8) {
        float v = fmaf(h2pre[(size_t)n * OUT_C + c], A2[c], B2[c]);
        out[(size_t)n * OUT_C + c] = v;
        sum += v;
        mx = fmaxf(mx, v);
    }
    __shared__ float lsum[256], lmax[256];
    lsum[threadIdx.x] = sum;
    lmax[threadIdx.x] = mx;
    __syncthreads();
    if (threadIdx.x < 32) {
        float ts = 0.f, tm = -INFINITY;
        for (int rr = 0; rr < 8; ++rr) {
            ts += lsum[rr * 32 + c];
            tm = fmaxf(tm, lmax[rr * 32 + c]);
        }
        pfeat[blockIdx.x * 64 + c] = ts;
        pfeat[blockIdx.x * 64 + 32 + c] = tm;
    }
}

// ---------------- MLP head (+pool combine) -> graph_emb ----------------

__global__ void __launch_bounds__(256) k_mlp(
        const float* __restrict__ pfeat, const int* __restrict__ gstart,
        const float* __restrict__ fcW1, const float* __restrict__ fcb1,
        const float* __restrict__ fcW2, const float* __restrict__ fcb2,
        float* __restrict__ out) {
    __shared__ float gf[N_GRAPHS * 64];
    __shared__ float t1[N_GRAPHS * OUT_C];
    int tid = threadIdx.x;
    for (int i = tid; i < N_GRAPHS * 32; i += 256) {
        int g = i >> 5, c = i & 31;
        float sm = 0.f, mx = -INFINITY;
        #pragma unroll
        for (int p = 0; p < 4; ++p) {
            sm += pfeat[(g * 4 + p) * 64 + c];
            mx = fmaxf(mx, pfeat[(g * 4 + p) * 64 + 32 + c]);
        }
        int cnt = gstart[g + 1] - gstart[g];
        gf[g * 64 + c] = (cnt > 0) ? sm / (float)cnt : 0.f;
        gf[g * 64 + 32 + c] = (cnt > 0) ? mx : 0.f;
    }
    __syncthreads();
    for (int i = tid; i < N_GRAPHS * OUT_C; i += 256) {
        int g = i >> 5, j = i & 31;
        float a = fcb1[j];
        for (int k = 0; k < 64; ++k) a = fmaf(gf[g * 64 + k], fcW1[k * OUT_C + j], a);
        t1[i] = a > 0.f ? a : 0.f;
    }
    __syncthreads();
    for (int i = tid; i < N_GRAPHS * OUT_C; i += 256) {
        int g = i >> 5, oc = i & 31;
        float a = fcb2[oc];
        for (int k = 0; k < OUT_C; ++k) a = fmaf(t1[g * OUT_C + k], fcW2[k * OUT_C + oc], a);
        out[(size_t)N_NODES * OUT_C + g * OUT_C + oc] = a;
    }
}

// ---------------- launch ----------------

extern "C" void kernel_launch(void* const* d_in, const int* in_sizes, int n_in,
                              void* d_out, int out_size, void* d_ws, size_t ws_size,
                              hipStream_t stream) {
    (void)in_sizes; (void)n_in; (void)out_size; (void)ws_size;
    const float* x      = (const float*)d_in[0];
    const int*   ei     = (const int*)d_in[1];
    const int*   batch  = (const int*)d_in[2];
    const float* W1     = (const float*)d_in[3];
    const float* a_src1 = (const float*)d_in[4];
    const float* a_dst1 = (const float*)d_in[5];
    const float* b1     = (const float*)d_in[6];
    const float* g1     = (const float*)d_in[7];
    const float* be1    = (const float*)d_in[8];
    const float* W2     = (const float*)d_in[9];
    const float* a_src2 = (const float*)d_in[10];
    const float* a_dst2 = (const float*)d_in[11];
    const float* b2     = (const float*)d_in[12];
    const float* g2     = (const float*)d_in[13];
    const float* be2    = (const float*)d_in[14];
    const float* fcW1   = (const float*)d_in[15];
    const float* fcb1   = (const float*)d_in[16];
    const float* fcW2   = (const float*)d_in[17];
    const float* fcb2   = (const float*)d_in[18];
    const int* srcv = ei;
    const int* dstv = ei + N_EDGES;
    float* out = (float*)d_out;

    char* w = (char*)d_ws;
    size_t o = 0;
    #define ALLOC(nbytes) (w + o); o = (o + (size_t)(nbytes) + 15) & ~(size_t)15
    int*   gcur      = (int*)ALLOC(N_BUCKETS * 4);
    float* stats1    = (float*)ALLOC(128 * 4);
    float* stats2    = (float*)ALLOC(64 * 4);
    size_t zero_bytes = o;                       // everything above must start at 0
    int*   counts    = (int*)ALLOC((size_t)N_NODES * 4);
    int*   row_start = (int*)ALLOC((size_t)(N_NODES + 2) * 4);
    int*   gst       = (int*)ALLOC(66 * 4);
    int*   bsum      = (int*)ALLOC(SCAN_NB * 4);
    int*   boff      = (int*)ALLOC(SCAN_NB * 4);
    int*   col       = (int*)ALLOC(((size_t)N_EDGES + 3 * N_NODES + 256) * 4);
    unsigned* ebuf   = (unsigned*)ALLOC((size_t)N_BUCKETS * BUCKET_CAP * 4);
    float* Vc1       = (float*)ALLOC(128 * 8 * 4);
    float* Vc2       = (float*)ALLOC(64 * 2 * 4);
    unsigned short* xl1b = (unsigned short*)ALLOC((size_t)(N_NODES + 1) * HID * 2);
    float* esd1      = (float*)ALLOC((size_t)(N_NODES + 1) * 8 * 4);
    float* h1pre     = (float*)ALLOC((size_t)N_NODES * HID * 4);
    unsigned short* xl2b = (unsigned short*)ALLOC((size_t)(N_NODES + 1) * OUT_C * 2);
    float* esd2      = (float*)ALLOC((size_t)(N_NODES + 1) * 2 * 4);
    float* pfeat     = (float*)ALLOC(256 * 64 * 4);
    #undef ALLOC
    float* h2pre = h1pre;   // h1pre dead after k_gemm2

    hipMemsetAsync(d_ws, 0, zero_bytes, stream);
    k_bin2  <<<BIN_NB, 256, 0, stream>>>(srcv, dstv, gcur, ebuf);
    k_count <<<N_BUCKETS, 256, 0, stream>>>(ebuf, gcur, counts);
    k_scanA <<<SCAN_NB, 256, 0, stream>>>(counts, row_start, bsum);
    k_scanB <<<1, 256, 0, stream>>>(bsum, boff);
    k_scanC <<<SCAN_NB, 256, 0, stream>>>(row_start, boff);
    k_fill2 <<<N_BUCKETS, 256, 0, stream>>>(ebuf, gcur, row_start, counts, col);
    k_prep  <<<1, 1024, 0, stream>>>(batch, W1, a_src1, a_dst1, W2, a_src2, a_dst2,
                                     gst, Vc1, Vc2, xl1b, esd1);
    k_gemm1 <<<(N_TILES + 3) / 4, 256, 0, stream>>>(x, W1, Vc1, xl1b, esd1);
    k_agg1  <<<(N_NODES + 3) / 4, 256, 0, stream>>>(xl1b, esd1, row_start, col, b1, h1pre);
    k_stats <<<256, 256, 0, stream>>>(h1pre, HID, stats1);
    k_gemm2 <<<(N_TILES + 3) / 4, 256, 0, stream>>>(h1pre, stats1, g1, be1, W2, Vc2,
                                                    xl2b, esd2);
    k_agg2  <<<(N_NODES + 7) / 8, 256, 0, stream>>>(xl2b, esd2, row_start, col, b2, h2pre);
    k_stats <<<256, 256, 0, stream>>>(h2pre, OUT_C, stats2);
    k_bnpool<<<256, 256, 0, stream>>>(h2pre, stats2, g2, be2, gst, out, pfeat);
    k_mlp   <<<1, 256, 0, stream>>>(pfeat, gst, fcW1, fcb1, fcW2, fcb2, out);
}

// Round 6
// 272.607 us; speedup vs baseline: 2.0679x; 1.0356x over previous
//
#include <hip/hip_runtime.h>
#include <math.h>

#define N_NODES 50000
#define N_EDGES 800000
#define N_GRAPHS 64
#define D_IN 128
#define HID 64
#define OUT_C 32
#define NEG 0.2f
#define BN_EPS 1e-5f
#define N_TILES 3125    // N_NODES / 16
#define N_BUCKETS 196   // bucket = dst >> 8
#define BIN_CHUNK 4096
#define BIN_NB 196      // ceil(N_EDGES / BIN_CHUNK)
#define GEMM1_NB 782    // ceil(N_TILES / 4)
#define BUCKET_CAP 5120 // mean 4082, sd ~64 -> 16 sigma margin
#define PHANTOM N_NODES // sentinel node: xl rows = 0, esd = -1e30 -> weight 0

typedef __attribute__((ext_vector_type(8))) short short8;
typedef __attribute__((ext_vector_type(4))) float f32x4;

static __device__ inline unsigned short f2bf(float f) {
    unsigned u = __float_as_uint(f);
    u += 0x7FFF + ((u >> 16) & 1);
    return (unsigned short)(u >> 16);
}
static __device__ inline float bfl(unsigned u) { return __uint_as_float(u << 16); }
static __device__ inline float bfh(unsigned u) { return __uint_as_float(u & 0xFFFF0000u); }

// =============== K1: fused front (bin | gemm1 | misc), role by blockIdx ===============
// bin:  blocks [0, 196)           — LDS-binned edge partition into ebuf (4B records)
// gemm: blocks [196, 196+782)     — xl1b = bf16(x@W1), esd1 = x@[W1@a_src1 | W1@a_dst1]
// misc: block 978                 — gstart binary search + phantom rows (both layers)

__global__ void __launch_bounds__(256) k_front(
        const int* __restrict__ src, const int* __restrict__ dst,
        int* __restrict__ gcur, unsigned* __restrict__ ebuf,
        const float* __restrict__ x, const float* __restrict__ W1,
        const float* __restrict__ a_src1, const float* __restrict__ a_dst1,
        unsigned short* __restrict__ xl1b, float* __restrict__ esd1,
        unsigned short* __restrict__ xl2b, float* __restrict__ esd2,
        const int* __restrict__ batch, int* __restrict__ gstart) {
    __shared__ __align__(16) char smem[23616];
    int tid = threadIdx.x;
    int blk = blockIdx.x;

    if (blk < BIN_NB) {
        // ---- bin role ----
        int* cnt = (int*)smem;                 // 256
        int* lofs = cnt + 256;                 // 256
        int* dstoff = lofs + 256;              // 256
        int* ws4 = dstoff + 256;               // 4
        unsigned* stage = (unsigned*)(ws4 + 4);        // 4096
        unsigned char* stage_b = (unsigned char*)(stage + BIN_CHUNK); // 4096
        cnt[tid] = 0;
        __syncthreads();
        int e0 = blk * BIN_CHUNK;
        int ne = N_EDGES - e0; if (ne > BIN_CHUNK) ne = BIN_CHUNK;
        unsigned rec[16]; int bkt[16], lp[16];
        #pragma unroll
        for (int j = 0; j < 16; ++j) {
            int r = j * 256 + tid;
            if (r < ne) {
                int e = e0 + r;
                int s = src[e], d = dst[e];
                rec[j] = ((unsigned)s << 8) | (unsigned)(d & 255);
                bkt[j] = d >> 8;
                lp[j] = atomicAdd(&cnt[bkt[j]], 1);
            } else bkt[j] = -1;
        }
        __syncthreads();
        int v = cnt[tid];
        int lane = tid & 63, wid = tid >> 6;
        int incl = v;
        #pragma unroll
        for (int off = 1; off < 64; off <<= 1) {
            int t = __shfl_up(incl, off, 64);
            if (lane >= off) incl += t;
        }
        if (lane == 63) ws4[wid] = incl;
        __syncthreads();
        if (tid == 0) {
            int a = ws4[0];
            #pragma unroll
            for (int j = 1; j < 4; ++j) { a += ws4[j]; ws4[j] = a; }
        }
        __syncthreads();
        if (wid > 0) incl += ws4[wid - 1];
        lofs[tid] = incl - v;
        __syncthreads();
        #pragma unroll
        for (int j = 0; j < 16; ++j) {
            if (bkt[j] >= 0) {
                int idx = lofs[bkt[j]] + lp[j];
                stage[idx] = rec[j];
                stage_b[idx] = (unsigned char)bkt[j];
            }
        }
        if (tid < N_BUCKETS && cnt[tid] > 0) {
            int g = atomicAdd(&gcur[tid], cnt[tid]);
            dstoff[tid] = tid * BUCKET_CAP + g - lofs[tid];
        }
        __syncthreads();
        for (int i = tid; i < ne; i += 256) {
            int b = stage_b[i];
            ebuf[dstoff[b] + i] = stage[i];
        }
        return;
    }

    if (blk < BIN_NB + GEMM1_NB) {
        // ---- gemm1 role ----
        typedef unsigned short WtRow[144];
        WtRow* Wt = (WtRow*)smem;   // [80][144]
        for (int i = tid; i < 80 * 128; i += 256) {
            int n = i >> 7, k = i & 127;
            float v;
            if (n < 64) v = W1[k * 64 + n];
            else if (n < 72) {
                int hh = (n - 64) & 3;
                const float* a = ((n - 64) < 4 ? a_src1 : a_dst1) + hh * 16;
                v = 0.f;
                #pragma unroll
                for (int c = 0; c < 16; ++c) v = fmaf(W1[k * 64 + hh * 16 + c], a[c], v);
            } else v = 0.f;
            Wt[n][k] = f2bf(v);
        }
        __syncthreads();
        int lane = tid & 63, wid = tid >> 6;
        int tile = (blk - BIN_NB) * 4 + wid;
        if (tile >= N_TILES) return;
        int m = lane & 15, kg = lane >> 4;
        int base = tile * 16;
        const float* xr = x + (size_t)(base + m) * D_IN + kg * 8;
        f32x4 acc[5];
        #pragma unroll
        for (int t = 0; t < 5; ++t) acc[t] = (f32x4){0.f, 0.f, 0.f, 0.f};
        #pragma unroll
        for (int s = 0; s < 4; ++s) {
            f32x4 p = ((const f32x4*)(xr + s * 32))[0];
            f32x4 q = ((const f32x4*)(xr + s * 32))[1];
            short8 a;
            a[0] = (short)f2bf(p[0]); a[1] = (short)f2bf(p[1]);
            a[2] = (short)f2bf(p[2]); a[3] = (short)f2bf(p[3]);
            a[4] = (short)f2bf(q[0]); a[5] = (short)f2bf(q[1]);
            a[6] = (short)f2bf(q[2]); a[7] = (short)f2bf(q[3]);
            #pragma unroll
            for (int t = 0; t < 5; ++t) {
                short8 b = *(const short8*)&Wt[t * 16 + m][s * 32 + kg * 8];
                acc[t] = __builtin_amdgcn_mfma_f32_16x16x32_bf16(a, b, acc[t], 0, 0, 0);
            }
        }
        #pragma unroll
        for (int r = 0; r < 4; ++r) {
            int node = base + kg * 4 + r;
            #pragma unroll
            for (int t = 0; t < 4; ++t)
                xl1b[(size_t)node * HID + t * 16 + m] = f2bf(acc[t][r]);
            if (m < 8) esd1[node * 8 + m] = acc[4][r];
        }
        return;
    }

    // ---- misc role (one block) ----
    if (tid <= N_GRAPHS) {
        int g = tid;
        int lo = 0, hi = N_NODES;
        while (lo < hi) {
            int mid = (lo + hi) >> 1;
            if (batch[mid] < g) lo = mid + 1; else hi = mid;
        }
        gstart[g] = lo;
    }
    if (tid >= 128 && tid < 192) xl1b[(size_t)PHANTOM * HID + (tid - 128)] = 0;
    if (tid >= 192 && tid < 200) esd1[(size_t)PHANTOM * 8 + (tid - 192)] = -1e30f;
    if (tid >= 200 && tid < 232) xl2b[(size_t)PHANTOM * OUT_C + (tid - 200)] = 0;
    if (tid >= 232 && tid < 234) esd2[(size_t)PHANTOM * 2 + (tid - 232)] = -1e30f;
}

// =============== K2: per-bucket count + intra-bucket padded scan ===============
// writes: counts[node] (raw), row_start[node+1] (intra-bucket padded inclusive),
//         bsum[bucket] (padded total)

__global__ void __launch_bounds__(256) k_countscan(
        const unsigned* __restrict__ ebuf, const int* __restrict__ gcur,
        int* __restrict__ counts, int* __restrict__ row_start,
        int* __restrict__ bsum) {
    __shared__ int lcnt[256];
    __shared__ int ws[4];
    int tid = threadIdx.x, b = blockIdx.x;
    lcnt[tid] = 0;
    __syncthreads();
    int ne = gcur[b];
    const unsigned* eb = ebuf + (size_t)b * BUCKET_CAP;
    for (int i = tid; i < ne; i += 256)
        atomicAdd(&lcnt[eb[i] & 255u], 1);
    __syncthreads();
    int node = b * 256 + tid;
    int raw = lcnt[tid];
    if (node < N_NODES) counts[node] = raw;
    int v = (node < N_NODES) ? ((raw + 3) & ~3) : 0;
    int lane = tid & 63, wid = tid >> 6;
    int incl = v;
    #pragma unroll
    for (int off = 1; off < 64; off <<= 1) {
        int t = __shfl_up(incl, off, 64);
        if (lane >= off) incl += t;
    }
    if (lane == 63) ws[wid] = incl;
    __syncthreads();
    if (tid == 0) {
        int a = ws[0];
        #pragma unroll
        for (int j = 1; j < 4; ++j) { a += ws[j]; ws[j] = a; }
    }
    __syncthreads();
    if (wid > 0) incl += ws[wid - 1];
    if (node < N_NODES) row_start[node + 1] = incl;
    if (tid == 255) bsum[b] = incl;
}

// =============== K3: finalize row_start (+bucket offset) and fill col ===============

__global__ void __launch_bounds__(256) k_fillrs(
        const unsigned* __restrict__ ebuf, const int* __restrict__ gcur,
        const int* __restrict__ bsum, const int* __restrict__ counts,
        int* __restrict__ row_start, int* __restrict__ col) {
    __shared__ int lcur[256], rs[256];
    __shared__ int wsum4[4];
    __shared__ int btot;
    int tid = threadIdx.x, b = blockIdx.x;
    int lane = tid & 63, wid = tid >> 6;
    // boff = sum(bsum[0..b-1])
    int v = (tid < b) ? bsum[tid] : 0;
    #pragma unroll
    for (int off = 32; off; off >>= 1) v += __shfl_down(v, off, 64);
    if (lane == 0) wsum4[wid] = v;
    __syncthreads();
    if (tid == 0) btot = wsum4[0] + wsum4[1] + wsum4[2] + wsum4[3];
    __syncthreads();
    int boffv = btot;
    int node = b * 256 + tid;
    int intra = (tid == 0) ? 0 : row_start[node];   // written by K2 (same bucket)
    int rsf = boffv + intra;
    if (node < N_NODES) {
        row_start[node] = rsf;
        rs[tid] = rsf;
        if (node == N_NODES - 1)
            row_start[N_NODES] = rsf + ((counts[node] + 3) & ~3);
    } else rs[tid] = 0;
    lcur[tid] = 0;
    __syncthreads();
    int ne = gcur[b];
    const unsigned* eb = ebuf + (size_t)b * BUCKET_CAP;
    for (int i = tid; i < ne; i += 256) {
        unsigned e = eb[i];
        int li = e & 255u;
        int p = atomicAdd(&lcur[li], 1);
        col[rs[li] + p] = (int)(e >> 8);
    }
    if (node < N_NODES) {
        int cnt = counts[node];
        int pe = (cnt + 3) & ~3;
        for (int j = cnt; j < pe; ++j) col[rsf + j] = PHANTOM;
    }
}

// =============== K4: layer-1 aggregation (2 ch/lane, 2 edges per wave-half) ===============

__global__ void __launch_bounds__(256) k_agg1(
        const unsigned* __restrict__ xl1r, const float* __restrict__ esd1,
        const int* __restrict__ row_start, const int* __restrict__ col,
        const float* __restrict__ b1, float* __restrict__ h1pre) {
    int wid = threadIdx.x >> 6, lane = threadIdx.x & 63;
    int d = blockIdx.x * 4 + wid;
    if (d >= N_NODES) return;
    int c2 = lane & 31, half = lane >> 5;
    int h = c2 >> 3;
    float edh = esd1[d * 8 + 4 + h];
    float ax = 0.f, ay = 0.f, wsum = 0.f;
    if (half == 0) {   // self loop on half 0 only
        float e0 = esd1[d * 8 + h] + edh;
        float w0 = __expf(fmaxf(e0, NEG * e0));
        unsigned u = xl1r[(size_t)d * 32 + c2];
        ax = w0 * bfl(u); ay = w0 * bfh(u); wsum = w0;
    }
    int js = row_start[d], je = row_start[d + 1];   // padded %4
    for (int j0 = js; j0 < je; j0 += 64) {
        int sv = col[j0 + lane];                     // slack alloc: safe overread
        int cnt = je - j0; if (cnt > 64) cnt = 64;
        for (int k = 0; k < cnt; k += 4) {
            int sa = __shfl(sv, k + half, 64);       // half0:k, half1:k+1
            int sb = __shfl(sv, k + 2 + half, 64);   // half0:k+2, half1:k+3
            unsigned ua = xl1r[(size_t)sa * 32 + c2];
            unsigned ub = xl1r[(size_t)sb * 32 + c2];
            float ea = esd1[sa * 8 + h] + edh;
            float eb = esd1[sb * 8 + h] + edh;
            float wa = __expf(fmaxf(ea, NEG * ea));
            float wb = __expf(fmaxf(eb, NEG * eb));
            ax = fmaf(wa, bfl(ua), ax); ay = fmaf(wa, bfh(ua), ay);
            ax = fmaf(wb, bfl(ub), ax); ay = fmaf(wb, bfh(ub), ay);
            wsum += wa + wb;
        }
    }
    ax += __shfl_xor(ax, 32, 64);
    ay += __shfl_xor(ay, 32, 64);
    wsum += __shfl_xor(wsum, 32, 64);
    if (half == 0) {
        float2 bb = ((const float2*)b1)[c2];
        float inv = 1.f / wsum;
        float2 r;
        r.x = ax * inv + bb.x;
        r.y = ay * inv + bb.y;
        ((float2*)h1pre)[(size_t)d * 32 + c2] = r;
    }
}

// =============== BatchNorm stats (sum, sumsq per channel) ===============

__global__ void __launch_bounds__(256) k_stats(const float* __restrict__ hpre,
                                               int nch, float* __restrict__ stats) {
    int c = threadIdx.x & (nch - 1);
    int gid = blockIdx.x * blockDim.x + threadIdx.x;
    int r0 = gid / nch;
    int rstride = (gridDim.x * blockDim.x) / nch;
    float s = 0.f, s2 = 0.f;
    for (int n = r0; n < N_NODES; n += rstride) {
        float v = hpre[(size_t)n * nch + c];
        s += v;
        s2 = fmaf(v, v, s2);
    }
    __shared__ float ls[256], ls2[256];
    ls[threadIdx.x] = s;
    ls2[threadIdx.x] = s2;
    __syncthreads();
    if (threadIdx.x < nch) {
        int rows = 256 / nch;
        float a = 0.f, b = 0.f;
        for (int r = 0; r < rows; ++r) {
            a += ls[r * nch + c];
            b += ls2[r * nch + c];
        }
        atomicAdd(&stats[c], a);
        atomicAdd(&stats[nch + c], b);
    }
}

// =============== K6: layer-2 GEMM (bn1+relu fused; V-cols computed inline) ===============

__global__ void __launch_bounds__(256) k_gemm2(
        const float* __restrict__ h1pre, const float* __restrict__ stats1,
        const float* __restrict__ g1, const float* __restrict__ be1,
        const float* __restrict__ W2, const float* __restrict__ a_src2,
        const float* __restrict__ a_dst2,
        unsigned short* __restrict__ xl2b, float* __restrict__ esd2) {
    __shared__ unsigned short Wt[48][80];
    __shared__ float A1s[64], B1s[64];
    int tid = threadIdx.x;
    for (int i = tid; i < 48 * 64; i += 256) {
        int n = i >> 6, k = i & 63;
        float v;
        if (n < 32) v = W2[k * 32 + n];
        else if (n < 34) {
            const float* a = (n == 32) ? a_src2 : a_dst2;
            v = 0.f;
            #pragma unroll
            for (int c = 0; c < 32; ++c) v = fmaf(W2[k * 32 + c], a[c], v);
        } else v = 0.f;
        Wt[n][k] = f2bf(v);
    }
    if (tid < 64) {
        float mu = stats1[tid] * (1.f / N_NODES);
        float var = stats1[64 + tid] * (1.f / N_NODES) - mu * mu;
        float sc = g1[tid] * rsqrtf(var + BN_EPS);
        A1s[tid] = sc;
        B1s[tid] = be1[tid] - mu * sc;
    }
    __syncthreads();
    int lane = tid & 63, wid = tid >> 6;
    int tile = blockIdx.x * 4 + wid;
    if (tile >= N_TILES) return;
    int m = lane & 15, kg = lane >> 4;
    int base = tile * 16;
    const float* hr = h1pre + (size_t)(base + m) * HID + kg * 8;
    f32x4 acc[3];
    #pragma unroll
    for (int t = 0; t < 3; ++t) acc[t] = (f32x4){0.f, 0.f, 0.f, 0.f};
    #pragma unroll
    for (int s = 0; s < 2; ++s) {
        int k0 = s * 32 + kg * 8;
        f32x4 p = ((const f32x4*)(hr + s * 32))[0];
        f32x4 q = ((const f32x4*)(hr + s * 32))[1];
        f32x4 sa = *(const f32x4*)&A1s[k0];
        f32x4 sb = *(const f32x4*)&B1s[k0];
        f32x4 sa2 = *(const f32x4*)&A1s[k0 + 4];
        f32x4 sb2 = *(const f32x4*)&B1s[k0 + 4];
        short8 a;
        #pragma unroll
        for (int j = 0; j < 4; ++j) {
            float v = fmaf(p[j], sa[j], sb[j]);
            a[j] = (short)f2bf(v > 0.f ? v : 0.f);
        }
        #pragma unroll
        for (int j = 0; j < 4; ++j) {
            float v = fmaf(q[j], sa2[j], sb2[j]);
            a[4 + j] = (short)f2bf(v > 0.f ? v : 0.f);
        }
        #pragma unroll
        for (int t = 0; t < 3; ++t) {
            short8 b = *(const short8*)&Wt[t * 16 + m][s * 32 + kg * 8];
            acc[t] = __builtin_amdgcn_mfma_f32_16x16x32_bf16(a, b, acc[t], 0, 0, 0);
        }
    }
    #pragma unroll
    for (int r = 0; r < 4; ++r) {
        int node = base + kg * 4 + r;
        #pragma unroll
        for (int t = 0; t < 2; ++t)
            xl2b[(size_t)node * OUT_C + t * 16 + m] = f2bf(acc[t][r]);
        if (m < 2) esd2[node * 2 + m] = acc[2][r];
    }
}

// =============== K7: layer-2 aggregation (2 ch/lane, 4 edges/wave) ===============

__global__ void __launch_bounds__(256) k_agg2(
        const unsigned* __restrict__ xl2r, const float* __restrict__ esd2,
        const int* __restrict__ row_start, const int* __restrict__ col,
        const float* __restrict__ b2, float* __restrict__ h2pre) {
    int wid = threadIdx.x >> 6, lane = threadIdx.x & 63;
    int d = blockIdx.x * 4 + wid;
    if (d >= N_NODES) return;
    int c2 = lane & 15, q = lane >> 4;   // channel pair, edge-quarter
    float edh = esd2[d * 2 + 1];
    float ax = 0.f, ay = 0.f, wsum = 0.f;
    if (q == 0) {   // self loop on quarter 0 only
        float e0 = esd2[d * 2] + edh;
        float w0 = __expf(fmaxf(e0, NEG * e0));
        unsigned u = xl2r[(size_t)d * 16 + c2];
        ax = w0 * bfl(u); ay = w0 * bfh(u); wsum = w0;
    }
    int js = row_start[d], je = row_start[d + 1];   // padded %4
    for (int j0 = js; j0 < je; j0 += 32) {
        int sv = col[j0 + (lane & 31)];
        int cnt = je - j0; if (cnt > 32) cnt = 32;
        for (int k = 0; k < cnt; k += 4) {
            int s = __shfl(sv, k + q, 64);           // quarter q takes edge k+q
            unsigned u = xl2r[(size_t)s * 16 + c2];
            float e = esd2[s * 2] + edh;
            float wv = __expf(fmaxf(e, NEG * e));
            ax = fmaf(wv, bfl(u), ax);
            ay = fmaf(wv, bfh(u), ay);
            wsum += wv;
        }
    }
    ax += __shfl_xor(ax, 16, 64); ax += __shfl_xor(ax, 32, 64);
    ay += __shfl_xor(ay, 16, 64); ay += __shfl_xor(ay, 32, 64);
    wsum += __shfl_xor(wsum, 16, 64); wsum += __shfl_xor(wsum, 32, 64);
    if (lane < 16) {
        float2 bb = ((const float2*)b2)[c2];
        float inv = 1.f / wsum;
        float2 r;
        r.x = ax * inv + bb.x;
        r.y = ay * inv + bb.y;
        ((float2*)h2pre)[(size_t)d * 16 + c2] = r;
    }
}

// =============== K9: fused BN2-apply + pool partials ===============

__global__ void __launch_bounds__(256) k_bnpool(
        const float* __restrict__ h2pre, const float* __restrict__ stats2,
        const float* __restrict__ g2, const float* __restrict__ be2,
        const int* __restrict__ gstart, float* __restrict__ out,
        float* __restrict__ pfeat) {
    __shared__ float A2[OUT_C], B2[OUT_C];
    if (threadIdx.x < OUT_C) {
        int cc = threadIdx.x;
        float mu = stats2[cc] * (1.f / N_NODES);
        float var = stats2[OUT_C + cc] * (1.f / N_NODES) - mu * mu;
        float sc = g2[cc] * rsqrtf(var + BN_EPS);
        A2[cc] = sc;
        B2[cc] = be2[cc] - mu * sc;
    }
    __syncthreads();
    int g = blockIdx.x >> 2, part = blockIdx.x & 3;
    int s = gstart[g], e = gstart[g + 1];
    int len = e - s;
    int qq = (len + 3) >> 2;
    int ps = s + part * qq;
    int pe = ps + qq; if (pe > e) pe = e;
    int c = threadIdx.x & 31, r = threadIdx.x >> 5;
    float sum = 0.f, mx = -INFINITY;
    for (int n = ps + r; n < pe; n += 8) {
        float v = fmaf(h2pre[(size_t)n * OUT_C + c], A2[c], B2[c]);
        out[(size_t)n * OUT_C + c] = v;
        sum += v;
        mx = fmaxf(mx, v);
    }
    __shared__ float lsum[256], lmax[256];
    lsum[threadIdx.x] = sum;
    lmax[threadIdx.x] = mx;
    __syncthreads();
    if (threadIdx.x < 32) {
        float ts = 0.f, tm = -INFINITY;
        for (int rr = 0; rr < 8; ++rr) {
            ts += lsum[rr * 32 + c];
            tm = fmaxf(tm, lmax[rr * 32 + c]);
        }
        pfeat[blockIdx.x * 64 + c] = ts;
        pfeat[blockIdx.x * 64 + 32 + c] = tm;
    }
}

// =============== K10: MLP head (+pool combine) -> graph_emb ===============

__global__ void __launch_bounds__(256) k_mlp(
        const float* __restrict__ pfeat, const int* __restrict__ gstart,
        const float* __restrict__ fcW1, const float* __restrict__ fcb1,
        const float* __restrict__ fcW2, const float* __restrict__ fcb2,
        float* __restrict__ out) {
    __shared__ float gf[N_GRAPHS * 64];
    __shared__ float t1[N_GRAPHS * OUT_C];
    int tid = threadIdx.x;
    for (int i = tid; i < N_GRAPHS * 32; i += 256) {
        int g = i >> 5, c = i & 31;
        float sm = 0.f, mx = -INFINITY;
        #pragma unroll
        for (int p = 0; p < 4; ++p) {
            sm += pfeat[(g * 4 + p) * 64 + c];
            mx = fmaxf(mx, pfeat[(g * 4 + p) * 64 + 32 + c]);
        }
        int cnt = gstart[g + 1] - gstart[g];
        gf[g * 64 + c] = (cnt > 0) ? sm / (float)cnt : 0.f;
        gf[g * 64 + 32 + c] = (cnt > 0) ? mx : 0.f;
    }
    __syncthreads();
    for (int i = tid; i < N_GRAPHS * OUT_C; i += 256) {
        int g = i >> 5, j = i & 31;
        float a = fcb1[j];
        for (int k = 0; k < 64; ++k) a = fmaf(gf[g * 64 + k], fcW1[k * OUT_C + j], a);
        t1[i] = a > 0.f ? a : 0.f;
    }
    __syncthreads();
    for (int i = tid; i < N_GRAPHS * OUT_C; i += 256) {
        int g = i >> 5, oc = i & 31;
        float a = fcb2[oc];
        for (int k = 0; k < OUT_C; ++k) a = fmaf(t1[g * OUT_C + k], fcW2[k * OUT_C + oc], a);
        out[(size_t)N_NODES * OUT_C + g * OUT_C + oc] = a;
    }
}

// =============== launch ===============

extern "C" void kernel_launch(void* const* d_in, const int* in_sizes, int n_in,
                              void* d_out, int out_size, void* d_ws, size_t ws_size,
                              hipStream_t stream) {
    (void)in_sizes; (void)n_in; (void)out_size; (void)ws_size;
    const float* x      = (const float*)d_in[0];
    const int*   ei     = (const int*)d_in[1];
    const int*   batch  = (const int*)d_in[2];
    const float* W1     = (const float*)d_in[3];
    const float* a_src1 = (const float*)d_in[4];
    const float* a_dst1 = (const float*)d_in[5];
    const float* b1     = (const float*)d_in[6];
    const float* g1     = (const float*)d_in[7];
    const float* be1    = (const float*)d_in[8];
    const float* W2     = (const float*)d_in[9];
    const float* a_src2 = (const float*)d_in[10];
    const float* a_dst2 = (const float*)d_in[11];
    const float* b2     = (const float*)d_in[12];
    const float* g2     = (const float*)d_in[13];
    const float* be2    = (const float*)d_in[14];
    const float* fcW1   = (const float*)d_in[15];
    const float* fcb1   = (const float*)d_in[16];
    const float* fcW2   = (const float*)d_in[17];
    const float* fcb2   = (const float*)d_in[18];
    const int* srcv = ei;
    const int* dstv = ei + N_EDGES;
    float* out = (float*)d_out;

    char* w = (char*)d_ws;
    size_t o = 0;
    #define ALLOC(nbytes) (w + o); o = (o + (size_t)(nbytes) + 15) & ~(size_t)15
    int*   gcur      = (int*)ALLOC(N_BUCKETS * 4);
    float* stats1    = (float*)ALLOC(128 * 4);
    float* stats2    = (float*)ALLOC(64 * 4);
    size_t zero_bytes = o;                       // everything above must start at 0
    int*   counts    = (int*)ALLOC((size_t)N_NODES * 4);
    int*   row_start = (int*)ALLOC((size_t)(N_NODES + 2) * 4);
    int*   gst       = (int*)ALLOC(66 * 4);
    int*   bsum      = (int*)ALLOC(N_BUCKETS * 4);
    int*   col       = (int*)ALLOC(((size_t)N_EDGES + 3 * N_NODES + 256) * 4);
    unsigned* ebuf   = (unsigned*)ALLOC((size_t)N_BUCKETS * BUCKET_CAP * 4);
    unsigned short* xl1b = (unsigned short*)ALLOC((size_t)(N_NODES + 1) * HID * 2);
    float* esd1      = (float*)ALLOC((size_t)(N_NODES + 1) * 8 * 4);
    float* h1pre     = (float*)ALLOC((size_t)N_NODES * HID * 4);
    unsigned short* xl2b = (unsigned short*)ALLOC((size_t)(N_NODES + 1) * OUT_C * 2);
    float* esd2      = (float*)ALLOC((size_t)(N_NODES + 1) * 2 * 4);
    float* pfeat     = (float*)ALLOC(256 * 64 * 4);
    #undef ALLOC
    float* h2pre = h1pre;   // h1pre dead after k_gemm2

    hipMemsetAsync(d_ws, 0, zero_bytes, stream);
    k_front    <<<BIN_NB + GEMM1_NB + 1, 256, 0, stream>>>(
        srcv, dstv, gcur, ebuf, x, W1, a_src1, a_dst1,
        xl1b, esd1, xl2b, esd2, batch, gst);
    k_countscan<<<N_BUCKETS, 256, 0, stream>>>(ebuf, gcur, counts, row_start, bsum);
    k_fillrs   <<<N_BUCKETS, 256, 0, stream>>>(ebuf, gcur, bsum, counts, row_start, col);
    k_agg1     <<<(N_NODES + 3) / 4, 256, 0, stream>>>(
        (const unsigned*)xl1b, esd1, row_start, col, b1, h1pre);
    k_stats    <<<256, 256, 0, stream>>>(h1pre, HID, stats1);
    k_gemm2    <<<(N_TILES + 3) / 4, 256, 0, stream>>>(
        h1pre, stats1, g1, be1, W2, a_src2, a_dst2, xl2b, esd2);
    k_agg2     <<<(N_NODES + 3) / 4, 256, 0, stream>>>(
        (const unsigned*)xl2b, esd2, row_start, col, b2, h2pre);
    k_stats    <<<256, 256, 0, stream>>>(h2pre, OUT_C, stats2);
    k_bnpool   <<<256, 256, 0, stream>>>(h2pre, stats2, g2, be2, gst, out, pfeat);
    k_mlp      <<<1, 256, 0, stream>>>(pfeat, gst, fcW1, fcb1, fcW2, fcb2, out);
}

// Round 7
// 268.181 us; speedup vs baseline: 2.1021x; 1.0165x over previous
//
#include <hip/hip_runtime.h>
#include <math.h>

#define N_NODES 50000
#define N_EDGES 800000
#define N_GRAPHS 64
#define D_IN 128
#define HID 64
#define OUT_C 32
#define NEG 0.2f
#define BN_EPS 1e-5f
#define N_TILES 3125    // N_NODES / 16
#define N_BUCKETS 196   // bucket = dst >> 8
#define BIN_CHUNK 4096
#define BIN_NB 196      // ceil(N_EDGES / BIN_CHUNK)
#define GEMM1_NB 782    // ceil(N_TILES / 4)
#define BUCKET_CAP 5120 // mean 4082, sd ~64 -> 16 sigma margin
#define CAP_PAD 6144    // fixed col region per bucket (5120 + 768 pad max, rounded)
#define PHANTOM N_NODES // sentinel node: xl rows = 0, esd = -1e30 -> weight 0

typedef __attribute__((ext_vector_type(8))) short short8;
typedef __attribute__((ext_vector_type(4))) float f32x4;

static __device__ inline unsigned short f2bf(float f) {
    unsigned u = __float_as_uint(f);
    u += 0x7FFF + ((u >> 16) & 1);
    return (unsigned short)(u >> 16);
}
static __device__ inline float bfl(unsigned u) { return __uint_as_float(u << 16); }
static __device__ inline float bfh(unsigned u) { return __uint_as_float(u & 0xFFFF0000u); }

// =============== K1: fused front (bin | gemm1 | misc), role by blockIdx ===============

__global__ void __launch_bounds__(256) k_front(
        const int* __restrict__ src, const int* __restrict__ dst,
        int* __restrict__ gcur, unsigned* __restrict__ ebuf,
        const float* __restrict__ x, const float* __restrict__ W1,
        const float* __restrict__ a_src1, const float* __restrict__ a_dst1,
        unsigned short* __restrict__ xl1b, float* __restrict__ esd1,
        unsigned short* __restrict__ xl2b, float* __restrict__ esd2,
        const int* __restrict__ batch, int* __restrict__ gstart,
        float* __restrict__ sp1, float* __restrict__ sp2) {
    __shared__ __align__(16) char smem[23616];
    int tid = threadIdx.x;
    int blk = blockIdx.x;

    if (blk < BIN_NB) {
        // ---- bin role: LDS-binned edge partition into ebuf (4B records) ----
        int* cnt = (int*)smem;
        int* lofs = cnt + 256;
        int* dstoff = lofs + 256;
        int* ws4 = dstoff + 256;
        unsigned* stage = (unsigned*)(ws4 + 4);
        unsigned char* stage_b = (unsigned char*)(stage + BIN_CHUNK);
        cnt[tid] = 0;
        __syncthreads();
        int e0 = blk * BIN_CHUNK;
        int ne = N_EDGES - e0; if (ne > BIN_CHUNK) ne = BIN_CHUNK;
        unsigned rec[16]; int bkt[16], lp[16];
        #pragma unroll
        for (int j = 0; j < 16; ++j) {
            int r = j * 256 + tid;
            if (r < ne) {
                int e = e0 + r;
                int s = src[e], d = dst[e];
                rec[j] = ((unsigned)s << 8) | (unsigned)(d & 255);
                bkt[j] = d >> 8;
                lp[j] = atomicAdd(&cnt[bkt[j]], 1);
            } else bkt[j] = -1;
        }
        __syncthreads();
        int v = cnt[tid];
        int lane = tid & 63, wid = tid >> 6;
        int incl = v;
        #pragma unroll
        for (int off = 1; off < 64; off <<= 1) {
            int t = __shfl_up(incl, off, 64);
            if (lane >= off) incl += t;
        }
        if (lane == 63) ws4[wid] = incl;
        __syncthreads();
        if (tid == 0) {
            int a = ws4[0];
            #pragma unroll
            for (int j = 1; j < 4; ++j) { a += ws4[j]; ws4[j] = a; }
        }
        __syncthreads();
        if (wid > 0) incl += ws4[wid - 1];
        lofs[tid] = incl - v;
        __syncthreads();
        #pragma unroll
        for (int j = 0; j < 16; ++j) {
            if (bkt[j] >= 0) {
                int idx = lofs[bkt[j]] + lp[j];
                stage[idx] = rec[j];
                stage_b[idx] = (unsigned char)bkt[j];
            }
        }
        if (tid < N_BUCKETS && cnt[tid] > 0) {
            int g = atomicAdd(&gcur[tid], cnt[tid]);
            dstoff[tid] = tid * BUCKET_CAP + g - lofs[tid];
        }
        __syncthreads();
        for (int i = tid; i < ne; i += 256) {
            int b = stage_b[i];
            ebuf[dstoff[b] + i] = stage[i];
        }
        return;
    }

    if (blk < BIN_NB + GEMM1_NB) {
        // ---- gemm1 role: xl1b = bf16(x@W1), esd1 = x@[W1 a_src1 | W1 a_dst1] ----
        typedef unsigned short WtRow[144];
        WtRow* Wt = (WtRow*)smem;   // [80][144]
        for (int i = tid; i < 80 * 128; i += 256) {
            int n = i >> 7, k = i & 127;
            float v;
            if (n < 64) v = W1[k * 64 + n];
            else if (n < 72) {
                int hh = (n - 64) & 3;
                const float* a = ((n - 64) < 4 ? a_src1 : a_dst1) + hh * 16;
                v = 0.f;
                #pragma unroll
                for (int c = 0; c < 16; ++c) v = fmaf(W1[k * 64 + hh * 16 + c], a[c], v);
            } else v = 0.f;
            Wt[n][k] = f2bf(v);
        }
        __syncthreads();
        int lane = tid & 63, wid = tid >> 6;
        int tile = (blk - BIN_NB) * 4 + wid;
        if (tile >= N_TILES) return;
        int m = lane & 15, kg = lane >> 4;
        int base = tile * 16;
        const float* xr = x + (size_t)(base + m) * D_IN + kg * 8;
        f32x4 acc[5];
        #pragma unroll
        for (int t = 0; t < 5; ++t) acc[t] = (f32x4){0.f, 0.f, 0.f, 0.f};
        #pragma unroll
        for (int s = 0; s < 4; ++s) {
            f32x4 p = ((const f32x4*)(xr + s * 32))[0];
            f32x4 q = ((const f32x4*)(xr + s * 32))[1];
            short8 a;
            a[0] = (short)f2bf(p[0]); a[1] = (short)f2bf(p[1]);
            a[2] = (short)f2bf(p[2]); a[3] = (short)f2bf(p[3]);
            a[4] = (short)f2bf(q[0]); a[5] = (short)f2bf(q[1]);
            a[6] = (short)f2bf(q[2]); a[7] = (short)f2bf(q[3]);
            #pragma unroll
            for (int t = 0; t < 5; ++t) {
                short8 b = *(const short8*)&Wt[t * 16 + m][s * 32 + kg * 8];
                acc[t] = __builtin_amdgcn_mfma_f32_16x16x32_bf16(a, b, acc[t], 0, 0, 0);
            }
        }
        #pragma unroll
        for (int r = 0; r < 4; ++r) {
            int node = base + kg * 4 + r;
            #pragma unroll
            for (int t = 0; t < 4; ++t)
                xl1b[(size_t)node * HID + t * 16 + m] = f2bf(acc[t][r]);
            if (m < 8) esd1[node * 8 + m] = acc[4][r];
        }
        return;
    }

    // ---- misc role (one block): gstart, phantoms, zero stats partials ----
    if (tid <= N_GRAPHS) {
        int g = tid;
        int lo = 0, hi = N_NODES;
        while (lo < hi) {
            int mid = (lo + hi) >> 1;
            if (batch[mid] < g) lo = mid + 1; else hi = mid;
        }
        gstart[g] = lo;
    }
    if (tid >= 128 && tid < 192) xl1b[(size_t)PHANTOM * HID + (tid - 128)] = 0;
    if (tid >= 192 && tid < 200) esd1[(size_t)PHANTOM * 8 + (tid - 192)] = -1e30f;
    if (tid >= 200 && tid < 232) xl2b[(size_t)PHANTOM * OUT_C + (tid - 200)] = 0;
    if (tid >= 232 && tid < 234) esd2[(size_t)PHANTOM * 2 + (tid - 232)] = -1e30f;
    for (int i = tid; i < 64 * 128; i += 256) sp1[i] = 0.f;
    for (int i = tid; i < 64 * 64; i += 256) sp2[i] = 0.f;
}

// =============== K2: merged CSR build (count + intra-bucket scan + fill) ===============
// Fixed col region per bucket: row_start = b*CAP_PAD + intra. rowinfo[d] = {js, je}.

__global__ void __launch_bounds__(256) k_csr(
        const unsigned* __restrict__ ebuf, const int* __restrict__ gcur,
        int2* __restrict__ rowinfo, int* __restrict__ col) {
    __shared__ int lcnt[256], lofs[256], lcur[256];
    __shared__ int ws[4];
    int tid = threadIdx.x, b = blockIdx.x;
    lcnt[tid] = 0;
    __syncthreads();
    int ne = gcur[b];
    const unsigned* eb = ebuf + (size_t)b * BUCKET_CAP;
    for (int i = tid; i < ne; i += 256)
        atomicAdd(&lcnt[eb[i] & 255u], 1);
    __syncthreads();
    int raw = lcnt[tid];
    int v = (raw + 3) & ~3;
    int lane = tid & 63, wid = tid >> 6;
    int incl = v;
    #pragma unroll
    for (int off = 1; off < 64; off <<= 1) {
        int t = __shfl_up(incl, off, 64);
        if (lane >= off) incl += t;
    }
    if (lane == 63) ws[wid] = incl;
    __syncthreads();
    if (tid == 0) {
        int a = ws[0];
        #pragma unroll
        for (int j = 1; j < 4; ++j) { a += ws[j]; ws[j] = a; }
    }
    __syncthreads();
    if (wid > 0) incl += ws[wid - 1];
    int js = b * CAP_PAD + (incl - v);
    int node = b * 256 + tid;
    if (node < N_NODES) rowinfo[node] = make_int2(js, js + v);
    lofs[tid] = js;
    lcur[tid] = 0;
    __syncthreads();
    for (int i = tid; i < ne; i += 256) {
        unsigned e = eb[i];
        int li = e & 255u;
        int p = atomicAdd(&lcur[li], 1);
        col[lofs[li] + p] = (int)(e >> 8);
    }
    for (int j = raw; j < v; ++j) col[js + j] = PHANTOM;
}

// =============== K3: layer-1 aggregation + BN1 stats partials ===============

__global__ void __launch_bounds__(256) k_agg1(
        const unsigned* __restrict__ xl1r, const float* __restrict__ esd1,
        const int2* __restrict__ rowinfo, const int* __restrict__ col,
        const float* __restrict__ b1, float* __restrict__ h1pre,
        float* __restrict__ sp1) {
    __shared__ float ps[64], pq[64];
    int tid = threadIdx.x;
    if (tid < 64) { ps[tid] = 0.f; pq[tid] = 0.f; }
    __syncthreads();
    int wid = tid >> 6, lane = tid & 63;
    int d = blockIdx.x * 4 + wid;               // grid exact: d < N_NODES always
    int c2 = lane & 31, half = lane >> 5;
    int h = c2 >> 3;
    float edh = esd1[d * 8 + 4 + h];
    float ax = 0.f, ay = 0.f, wsum = 0.f;
    if (half == 0) {   // self loop on half 0 only
        float e0 = esd1[d * 8 + h] + edh;
        float w0 = __expf(fmaxf(e0, NEG * e0));
        unsigned u = xl1r[(size_t)d * 32 + c2];
        ax = w0 * bfl(u); ay = w0 * bfh(u); wsum = w0;
    }
    int2 ri = rowinfo[d];
    int js = ri.x, je = ri.y;                   // padded %4
    for (int j0 = js; j0 < je; j0 += 64) {
        int sv = col[j0 + lane];                // slack alloc: safe overread
        int cnt = je - j0; if (cnt > 64) cnt = 64;
        for (int k = 0; k < cnt; k += 4) {
            int sa = __shfl(sv, k + half, 64);
            int sb = __shfl(sv, k + 2 + half, 64);
            unsigned ua = xl1r[(size_t)sa * 32 + c2];
            unsigned ub = xl1r[(size_t)sb * 32 + c2];
            float ea = esd1[sa * 8 + h] + edh;
            float eb = esd1[sb * 8 + h] + edh;
            float wa = __expf(fmaxf(ea, NEG * ea));
            float wb = __expf(fmaxf(eb, NEG * eb));
            ax = fmaf(wa, bfl(ua), ax); ay = fmaf(wa, bfh(ua), ay);
            ax = fmaf(wb, bfl(ub), ax); ay = fmaf(wb, bfh(ub), ay);
            wsum += wa + wb;
        }
    }
    ax += __shfl_xor(ax, 32, 64);
    ay += __shfl_xor(ay, 32, 64);
    wsum += __shfl_xor(wsum, 32, 64);
    if (half == 0) {
        float2 bb = ((const float2*)b1)[c2];
        float inv = 1.f / wsum;
        float2 r;
        r.x = ax * inv + bb.x;
        r.y = ay * inv + bb.y;
        ((float2*)h1pre)[(size_t)d * 32 + c2] = r;
        atomicAdd(&ps[c2 * 2], r.x);     atomicAdd(&ps[c2 * 2 + 1], r.y);
        atomicAdd(&pq[c2 * 2], r.x * r.x); atomicAdd(&pq[c2 * 2 + 1], r.y * r.y);
    }
    __syncthreads();
    int slot = (blockIdx.x & 63) * 128;
    if (tid < 64) atomicAdd(&sp1[slot + tid], ps[tid]);
    else if (tid < 128) atomicAdd(&sp1[slot + tid], pq[tid - 64]);
}

// =============== K4: layer-2 GEMM (bn1+relu fused; stats reduced inline) ===============

__global__ void __launch_bounds__(256) k_gemm2(
        const float* __restrict__ h1pre, const float* __restrict__ sp1,
        const float* __restrict__ g1, const float* __restrict__ be1,
        const float* __restrict__ W2, const float* __restrict__ a_src2,
        const float* __restrict__ a_dst2,
        unsigned short* __restrict__ xl2b, float* __restrict__ esd2) {
    __shared__ unsigned short Wt[48][80];
    __shared__ float A1s[64], B1s[64], red[128];
    int tid = threadIdx.x;
    for (int i = tid; i < 48 * 64; i += 256) {
        int n = i >> 6, k = i & 63;
        float v;
        if (n < 32) v = W2[k * 32 + n];
        else if (n < 34) {
            const float* a = (n == 32) ? a_src2 : a_dst2;
            v = 0.f;
            #pragma unroll
            for (int c = 0; c < 32; ++c) v = fmaf(W2[k * 32 + c], a[c], v);
        } else v = 0.f;
        Wt[n][k] = f2bf(v);
    }
    if (tid < 128) {
        float s = 0.f;
        for (int j = 0; j < 64; ++j) s += sp1[j * 128 + tid];
        red[tid] = s;
    }
    __syncthreads();
    if (tid < 64) {
        float mu = red[tid] * (1.f / N_NODES);
        float var = red[64 + tid] * (1.f / N_NODES) - mu * mu;
        float sc = g1[tid] * rsqrtf(var + BN_EPS);
        A1s[tid] = sc;
        B1s[tid] = be1[tid] - mu * sc;
    }
    __syncthreads();
    int lane = tid & 63, wid = tid >> 6;
    int tile = blockIdx.x * 4 + wid;
    if (tile >= N_TILES) return;
    int m = lane & 15, kg = lane >> 4;
    int base = tile * 16;
    const float* hr = h1pre + (size_t)(base + m) * HID + kg * 8;
    f32x4 acc[3];
    #pragma unroll
    for (int t = 0; t < 3; ++t) acc[t] = (f32x4){0.f, 0.f, 0.f, 0.f};
    #pragma unroll
    for (int s = 0; s < 2; ++s) {
        int k0 = s * 32 + kg * 8;
        f32x4 p = ((const f32x4*)(hr + s * 32))[0];
        f32x4 q = ((const f32x4*)(hr + s * 32))[1];
        f32x4 sa = *(const f32x4*)&A1s[k0];
        f32x4 sb = *(const f32x4*)&B1s[k0];
        f32x4 sa2 = *(const f32x4*)&A1s[k0 + 4];
        f32x4 sb2 = *(const f32x4*)&B1s[k0 + 4];
        short8 a;
        #pragma unroll
        for (int j = 0; j < 4; ++j) {
            float v = fmaf(p[j], sa[j], sb[j]);
            a[j] = (short)f2bf(v > 0.f ? v : 0.f);
        }
        #pragma unroll
        for (int j = 0; j < 4; ++j) {
            float v = fmaf(q[j], sa2[j], sb2[j]);
            a[4 + j] = (short)f2bf(v > 0.f ? v : 0.f);
        }
        #pragma unroll
        for (int t = 0; t < 3; ++t) {
            short8 b = *(const short8*)&Wt[t * 16 + m][s * 32 + kg * 8];
            acc[t] = __builtin_amdgcn_mfma_f32_16x16x32_bf16(a, b, acc[t], 0, 0, 0);
        }
    }
    #pragma unroll
    for (int r = 0; r < 4; ++r) {
        int node = base + kg * 4 + r;
        #pragma unroll
        for (int t = 0; t < 2; ++t)
            xl2b[(size_t)node * OUT_C + t * 16 + m] = f2bf(acc[t][r]);
        if (m < 2) esd2[node * 2 + m] = acc[2][r];
    }
}

// =============== K5: layer-2 aggregation + BN2 stats partials ===============

__global__ void __launch_bounds__(256) k_agg2(
        const unsigned* __restrict__ xl2r, const float* __restrict__ esd2,
        const int2* __restrict__ rowinfo, const int* __restrict__ col,
        const float* __restrict__ b2, float* __restrict__ h2pre,
        float* __restrict__ sp2) {
    __shared__ float ps[32], pq[32];
    int tid = threadIdx.x;
    if (tid < 32) { ps[tid] = 0.f; pq[tid] = 0.f; }
    __syncthreads();
    int wid = tid >> 6, lane = tid & 63;
    int d = blockIdx.x * 4 + wid;               // grid exact
    int c2 = lane & 15, q = lane >> 4;
    float edh = esd2[d * 2 + 1];
    float ax = 0.f, ay = 0.f, wsum = 0.f;
    if (q == 0) {
        float e0 = esd2[d * 2] + edh;
        float w0 = __expf(fmaxf(e0, NEG * e0));
        unsigned u = xl2r[(size_t)d * 16 + c2];
        ax = w0 * bfl(u); ay = w0 * bfh(u); wsum = w0;
    }
    int2 ri = rowinfo[d];
    int js = ri.x, je = ri.y;
    for (int j0 = js; j0 < je; j0 += 32) {
        int sv = col[j0 + (lane & 31)];
        int cnt = je - j0; if (cnt > 32) cnt = 32;
        for (int k = 0; k < cnt; k += 4) {
            int s = __shfl(sv, k + q, 64);
            unsigned u = xl2r[(size_t)s * 16 + c2];
            float e = esd2[s * 2] + edh;
            float wv = __expf(fmaxf(e, NEG * e));
            ax = fmaf(wv, bfl(u), ax);
            ay = fmaf(wv, bfh(u), ay);
            wsum += wv;
        }
    }
    ax += __shfl_xor(ax, 16, 64); ax += __shfl_xor(ax, 32, 64);
    ay += __shfl_xor(ay, 16, 64); ay += __shfl_xor(ay, 32, 64);
    wsum += __shfl_xor(wsum, 16, 64); wsum += __shfl_xor(wsum, 32, 64);
    if (lane < 16) {
        float2 bb = ((const float2*)b2)[c2];
        float inv = 1.f / wsum;
        float2 r;
        r.x = ax * inv + bb.x;
        r.y = ay * inv + bb.y;
        ((float2*)h2pre)[(size_t)d * 16 + c2] = r;
        atomicAdd(&ps[c2 * 2], r.x);       atomicAdd(&ps[c2 * 2 + 1], r.y);
        atomicAdd(&pq[c2 * 2], r.x * r.x); atomicAdd(&pq[c2 * 2 + 1], r.y * r.y);
    }
    __syncthreads();
    int slot = (blockIdx.x & 63) * 64;
    if (tid < 32) atomicAdd(&sp2[slot + tid], ps[tid]);
    else if (tid < 64) atomicAdd(&sp2[slot + tid], pq[tid - 32]);
}

// =============== K6: fused BN2-apply + pool partials (stats reduced inline) ===============

__global__ void __launch_bounds__(256) k_bnpool(
        const float* __restrict__ h2pre, const float* __restrict__ sp2,
        const float* __restrict__ g2, const float* __restrict__ be2,
        const int* __restrict__ gstart, float* __restrict__ out,
        float* __restrict__ pfeat) {
    __shared__ float A2[OUT_C], B2[OUT_C], red[64];
    int tid = threadIdx.x;
    if (tid < 64) {
        float s = 0.f;
        for (int j = 0; j < 64; ++j) s += sp2[j * 64 + tid];
        red[tid] = s;
    }
    __syncthreads();
    if (tid < 32) {
        float mu = red[tid] * (1.f / N_NODES);
        float var = red[32 + tid] * (1.f / N_NODES) - mu * mu;
        float sc = g2[tid] * rsqrtf(var + BN_EPS);
        A2[tid] = sc;
        B2[tid] = be2[tid] - mu * sc;
    }
    __syncthreads();
    int g = blockIdx.x >> 2, part = blockIdx.x & 3;
    int s = gstart[g], e = gstart[g + 1];
    int len = e - s;
    int qq = (len + 3) >> 2;
    int ps = s + part * qq;
    int pe = ps + qq; if (pe > e) pe = e;
    int c = tid & 31, r = tid >> 5;
    float sum = 0.f, mx = -INFINITY;
    for (int n = ps + r; n < pe; n += 8) {
        float v = fmaf(h2pre[(size_t)n * OUT_C + c], A2[c], B2[c]);
        out[(size_t)n * OUT_C + c] = v;
        sum += v;
        mx = fmaxf(mx, v);
    }
    __shared__ float lsum[256], lmax[256];
    lsum[tid] = sum;
    lmax[tid] = mx;
    __syncthreads();
    if (tid < 32) {
        float ts = 0.f, tm = -INFINITY;
        for (int rr = 0; rr < 8; ++rr) {
            ts += lsum[rr * 32 + c];
            tm = fmaxf(tm, lmax[rr * 32 + c]);
        }
        pfeat[blockIdx.x * 64 + c] = ts;
        pfeat[blockIdx.x * 64 + 32 + c] = tm;
    }
}

// =============== K7: MLP head (+pool combine) -> graph_emb ===============

__global__ void __launch_bounds__(256) k_mlp(
        const float* __restrict__ pfeat, const int* __restrict__ gstart,
        const float* __restrict__ fcW1, const float* __restrict__ fcb1,
        const float* __restrict__ fcW2, const float* __restrict__ fcb2,
        float* __restrict__ out) {
    __shared__ float gf[N_GRAPHS * 64];
    __shared__ float t1[N_GRAPHS * OUT_C];
    int tid = threadIdx.x;
    for (int i = tid; i < N_GRAPHS * 32; i += 256) {
        int g = i >> 5, c = i & 31;
        float sm = 0.f, mx = -INFINITY;
        #pragma unroll
        for (int p = 0; p < 4; ++p) {
            sm += pfeat[(g * 4 + p) * 64 + c];
            mx = fmaxf(mx, pfeat[(g * 4 + p) * 64 + 32 + c]);
        }
        int cnt = gstart[g + 1] - gstart[g];
        gf[g * 64 + c] = (cnt > 0) ? sm / (float)cnt : 0.f;
        gf[g * 64 + 32 + c] = (cnt > 0) ? mx : 0.f;
    }
    __syncthreads();
    for (int i = tid; i < N_GRAPHS * OUT_C; i += 256) {
        int g = i >> 5, j = i & 31;
        float a = fcb1[j];
        for (int k = 0; k < 64; ++k) a = fmaf(gf[g * 64 + k], fcW1[k * OUT_C + j], a);
        t1[i] = a > 0.f ? a : 0.f;
    }
    __syncthreads();
    for (int i = tid; i < N_GRAPHS * OUT_C; i += 256) {
        int g = i >> 5, oc = i & 31;
        float a = fcb2[oc];
        for (int k = 0; k < OUT_C; ++k) a = fmaf(t1[g * OUT_C + k], fcW2[k * OUT_C + oc], a);
        out[(size_t)N_NODES * OUT_C + g * OUT_C + oc] = a;
    }
}

// =============== launch ===============

extern "C" void kernel_launch(void* const* d_in, const int* in_sizes, int n_in,
                              void* d_out, int out_size, void* d_ws, size_t ws_size,
                              hipStream_t stream) {
    (void)in_sizes; (void)n_in; (void)out_size; (void)ws_size;
    const float* x      = (const float*)d_in[0];
    const int*   ei     = (const int*)d_in[1];
    const int*   batch  = (const int*)d_in[2];
    const float* W1     = (const float*)d_in[3];
    const float* a_src1 = (const float*)d_in[4];
    const float* a_dst1 = (const float*)d_in[5];
    const float* b1     = (const float*)d_in[6];
    const float* g1     = (const float*)d_in[7];
    const float* be1    = (const float*)d_in[8];
    const float* W2     = (const float*)d_in[9];
    const float* a_src2 = (const float*)d_in[10];
    const float* a_dst2 = (const float*)d_in[11];
    const float* b2     = (const float*)d_in[12];
    const float* g2     = (const float*)d_in[13];
    const float* be2    = (const float*)d_in[14];
    const float* fcW1   = (const float*)d_in[15];
    const float* fcb1   = (const float*)d_in[16];
    const float* fcW2   = (const float*)d_in[17];
    const float* fcb2   = (const float*)d_in[18];
    const int* srcv = ei;
    const int* dstv = ei + N_EDGES;
    float* out = (float*)d_out;

    char* w = (char*)d_ws;
    size_t o = 0;
    #define ALLOC(nbytes) (w + o); o = (o + (size_t)(nbytes) + 15) & ~(size_t)15
    int*   gcur      = (int*)ALLOC(N_BUCKETS * 4);
    size_t zero_bytes = o;                       // only gcur needs pre-zero
    float* sp1       = (float*)ALLOC(64 * 128 * 4);   // zeroed by k_front misc
    float* sp2       = (float*)ALLOC(64 * 64 * 4);    // zeroed by k_front misc
    int2*  rowinfo   = (int2*)ALLOC((size_t)N_NODES * 8);
    int*   gst       = (int*)ALLOC(66 * 4);
    int*   col       = (int*)ALLOC(((size_t)N_BUCKETS * CAP_PAD + 256) * 4);
    unsigned* ebuf   = (unsigned*)ALLOC((size_t)N_BUCKETS * BUCKET_CAP * 4);
    unsigned short* xl1b = (unsigned short*)ALLOC((size_t)(N_NODES + 1) * HID * 2);
    float* esd1      = (float*)ALLOC((size_t)(N_NODES + 1) * 8 * 4);
    float* h1pre     = (float*)ALLOC((size_t)N_NODES * HID * 4);
    unsigned short* xl2b = (unsigned short*)ALLOC((size_t)(N_NODES + 1) * OUT_C * 2);
    float* esd2      = (float*)ALLOC((size_t)(N_NODES + 1) * 2 * 4);
    float* pfeat     = (float*)ALLOC(256 * 64 * 4);
    #undef ALLOC
    float* h2pre = h1pre;   // h1pre dead after k_gemm2

    hipMemsetAsync(d_ws, 0, zero_bytes, stream);
    k_front <<<BIN_NB + GEMM1_NB + 1, 256, 0, stream>>>(
        srcv, dstv, gcur, ebuf, x, W1, a_src1, a_dst1,
        xl1b, esd1, xl2b, esd2, batch, gst, sp1, sp2);
    k_csr   <<<N_BUCKETS, 256, 0, stream>>>(ebuf, gcur, rowinfo, col);
    k_agg1  <<<N_NODES / 4, 256, 0, stream>>>(
        (const unsigned*)xl1b, esd1, rowinfo, col, b1, h1pre, sp1);
    k_gemm2 <<<(N_TILES + 3) / 4, 256, 0, stream>>>(
        h1pre, sp1, g1, be1, W2, a_src2, a_dst2, xl2b, esd2);
    k_agg2  <<<N_NODES / 4, 256, 0, stream>>>(
        (const unsigned*)xl2b, esd2, rowinfo, col, b2, h2pre, sp2);
    k_bnpool<<<256, 256, 0, stream>>>(h2pre, sp2, g2, be2, gst, out, pfeat);
    k_mlp   <<<1, 256, 0, stream>>>(pfeat, gst, fcW1, fcb1, fcW2, fcb2, out);
}

// Round 8
// 263.929 us; speedup vs baseline: 2.1359x; 1.0161x over previous
//
#include <hip/hip_runtime.h>
#include <math.h>

#define N_NODES 50000
#define N_EDGES 800000
#define N_GRAPHS 64
#define D_IN 128
#define HID 64
#define OUT_C 32
#define NEG 0.2f
#define BN_EPS 1e-5f
#define N_TILES 3125    // N_NODES / 16
#define N_BUCKETS 196   // bucket = dst >> 8
#define BIN_CHUNK 4096
#define BIN_NB 196      // ceil(N_EDGES / BIN_CHUNK)
#define GEMM1_NB 782    // ceil(N_TILES / 4)
#define BUCKET_CAP 5120 // mean 4082, sd ~64 -> 16 sigma margin
#define CAP_PAD 6144    // fixed col region per bucket
#define PHANTOM N_NODES // sentinel node: xl rows = 0, esd = -1e30 -> weight 0

typedef __attribute__((ext_vector_type(8))) short short8;
typedef __attribute__((ext_vector_type(4))) float f32x4;

static __device__ inline unsigned short f2bf(float f) {
    unsigned u = __float_as_uint(f);
    u += 0x7FFF + ((u >> 16) & 1);
    return (unsigned short)(u >> 16);
}
static __device__ inline float bfus(unsigned short u) {
    return __uint_as_float((unsigned)u << 16);
}

// =============== K1: fused front (bin | gemm1 | misc), role by blockIdx ===============

__global__ void __launch_bounds__(256) k_front(
        const int* __restrict__ src, const int* __restrict__ dst,
        int* __restrict__ gcur, unsigned* __restrict__ ebuf,
        const float* __restrict__ x, const float* __restrict__ W1,
        const float* __restrict__ a_src1, const float* __restrict__ a_dst1,
        unsigned short* __restrict__ xl1b, float* __restrict__ esd1,
        unsigned short* __restrict__ xl2b, float* __restrict__ esd2,
        const int* __restrict__ batch, int* __restrict__ gstart,
        float* __restrict__ sp1, float* __restrict__ sp2) {
    __shared__ __align__(16) char smem[23616];
    int tid = threadIdx.x;
    int blk = blockIdx.x;

    if (blk < BIN_NB) {
        // ---- bin role: LDS-binned edge partition into ebuf (4B records) ----
        int* cnt = (int*)smem;
        int* lofs = cnt + 256;
        int* dstoff = lofs + 256;
        int* ws4 = dstoff + 256;
        unsigned* stage = (unsigned*)(ws4 + 4);
        unsigned char* stage_b = (unsigned char*)(stage + BIN_CHUNK);
        cnt[tid] = 0;
        __syncthreads();
        int e0 = blk * BIN_CHUNK;
        int ne = N_EDGES - e0; if (ne > BIN_CHUNK) ne = BIN_CHUNK;
        unsigned rec[16]; int bkt[16], lp[16];
        #pragma unroll
        for (int j = 0; j < 16; ++j) {
            int r = j * 256 + tid;
            if (r < ne) {
                int e = e0 + r;
                int s = src[e], d = dst[e];
                rec[j] = ((unsigned)s << 8) | (unsigned)(d & 255);
                bkt[j] = d >> 8;
                lp[j] = atomicAdd(&cnt[bkt[j]], 1);
            } else bkt[j] = -1;
        }
        __syncthreads();
        int v = cnt[tid];
        int lane = tid & 63, wid = tid >> 6;
        int incl = v;
        #pragma unroll
        for (int off = 1; off < 64; off <<= 1) {
            int t = __shfl_up(incl, off, 64);
            if (lane >= off) incl += t;
        }
        if (lane == 63) ws4[wid] = incl;
        __syncthreads();
        if (tid == 0) {
            int a = ws4[0];
            #pragma unroll
            for (int j = 1; j < 4; ++j) { a += ws4[j]; ws4[j] = a; }
        }
        __syncthreads();
        if (wid > 0) incl += ws4[wid - 1];
        lofs[tid] = incl - v;
        __syncthreads();
        #pragma unroll
        for (int j = 0; j < 16; ++j) {
            if (bkt[j] >= 0) {
                int idx = lofs[bkt[j]] + lp[j];
                stage[idx] = rec[j];
                stage_b[idx] = (unsigned char)bkt[j];
            }
        }
        if (tid < N_BUCKETS && cnt[tid] > 0) {
            int g = atomicAdd(&gcur[tid], cnt[tid]);
            dstoff[tid] = tid * BUCKET_CAP + g - lofs[tid];
        }
        __syncthreads();
        for (int i = tid; i < ne; i += 256) {
            int b = stage_b[i];
            ebuf[dstoff[b] + i] = stage[i];
        }
        return;
    }

    if (blk < BIN_NB + GEMM1_NB) {
        // ---- gemm1 role: xl1b = bf16(x@W1), esd1 = x@[W1 a_src1 | W1 a_dst1] ----
        typedef unsigned short WtRow[144];
        WtRow* Wt = (WtRow*)smem;   // [80][144]
        for (int i = tid; i < 80 * 128; i += 256) {
            int n = i >> 7, k = i & 127;
            float v;
            if (n < 64) v = W1[k * 64 + n];
            else if (n < 72) {
                int hh = (n - 64) & 3;
                const float* a = ((n - 64) < 4 ? a_src1 : a_dst1) + hh * 16;
                v = 0.f;
                #pragma unroll
                for (int c = 0; c < 16; ++c) v = fmaf(W1[k * 64 + hh * 16 + c], a[c], v);
            } else v = 0.f;
            Wt[n][k] = f2bf(v);
        }
        __syncthreads();
        int lane = tid & 63, wid = tid >> 6;
        int tile = (blk - BIN_NB) * 4 + wid;
        if (tile >= N_TILES) return;
        int m = lane & 15, kg = lane >> 4;
        int base = tile * 16;
        const float* xr = x + (size_t)(base + m) * D_IN + kg * 8;
        f32x4 acc[5];
        #pragma unroll
        for (int t = 0; t < 5; ++t) acc[t] = (f32x4){0.f, 0.f, 0.f, 0.f};
        #pragma unroll
        for (int s = 0; s < 4; ++s) {
            f32x4 p = ((const f32x4*)(xr + s * 32))[0];
            f32x4 q = ((const f32x4*)(xr + s * 32))[1];
            short8 a;
            a[0] = (short)f2bf(p[0]); a[1] = (short)f2bf(p[1]);
            a[2] = (short)f2bf(p[2]); a[3] = (short)f2bf(p[3]);
            a[4] = (short)f2bf(q[0]); a[5] = (short)f2bf(q[1]);
            a[6] = (short)f2bf(q[2]); a[7] = (short)f2bf(q[3]);
            #pragma unroll
            for (int t = 0; t < 5; ++t) {
                short8 b = *(const short8*)&Wt[t * 16 + m][s * 32 + kg * 8];
                acc[t] = __builtin_amdgcn_mfma_f32_16x16x32_bf16(a, b, acc[t], 0, 0, 0);
            }
        }
        #pragma unroll
        for (int r = 0; r < 4; ++r) {
            int node = base + kg * 4 + r;
            #pragma unroll
            for (int t = 0; t < 4; ++t)
                xl1b[(size_t)node * HID + t * 16 + m] = f2bf(acc[t][r]);
            if (m < 8) esd1[node * 8 + m] = acc[4][r];
        }
        return;
    }

    // ---- misc role (one block): gstart, phantoms, zero stats partials ----
    if (tid <= N_GRAPHS) {
        int g = tid;
        int lo = 0, hi = N_NODES;
        while (lo < hi) {
            int mid = (lo + hi) >> 1;
            if (batch[mid] < g) lo = mid + 1; else hi = mid;
        }
        gstart[g] = lo;
    }
    if (tid >= 128 && tid < 192) xl1b[(size_t)PHANTOM * HID + (tid - 128)] = 0;
    if (tid >= 192 && tid < 200) esd1[(size_t)PHANTOM * 8 + (tid - 192)] = -1e30f;
    if (tid >= 200 && tid < 232) xl2b[(size_t)PHANTOM * OUT_C + (tid - 200)] = 0;
    if (tid >= 232 && tid < 234) esd2[(size_t)PHANTOM * 2 + (tid - 232)] = -1e30f;
    for (int i = tid; i < 64 * 128; i += 256) sp1[i] = 0.f;
    for (int i = tid; i < 64 * 64; i += 256) sp2[i] = 0.f;
}

// =============== K2: merged CSR build (count + intra-bucket scan + fill) ===============

__global__ void __launch_bounds__(256) k_csr(
        const unsigned* __restrict__ ebuf, const int* __restrict__ gcur,
        int2* __restrict__ rowinfo, int* __restrict__ col) {
    __shared__ int lcnt[256], lofs[256], lcur[256];
    __shared__ int ws[4];
    int tid = threadIdx.x, b = blockIdx.x;
    lcnt[tid] = 0;
    __syncthreads();
    int ne = gcur[b];
    const unsigned* eb = ebuf + (size_t)b * BUCKET_CAP;
    for (int i = tid; i < ne; i += 256)
        atomicAdd(&lcnt[eb[i] & 255u], 1);
    __syncthreads();
    int raw = lcnt[tid];
    int v = (raw + 3) & ~3;
    int lane = tid & 63, wid = tid >> 6;
    int incl = v;
    #pragma unroll
    for (int off = 1; off < 64; off <<= 1) {
        int t = __shfl_up(incl, off, 64);
        if (lane >= off) incl += t;
    }
    if (lane == 63) ws[wid] = incl;
    __syncthreads();
    if (tid == 0) {
        int a = ws[0];
        #pragma unroll
        for (int j = 1; j < 4; ++j) { a += ws[j]; ws[j] = a; }
    }
    __syncthreads();
    if (wid > 0) incl += ws[wid - 1];
    int js = b * CAP_PAD + (incl - v);
    int node = b * 256 + tid;
    if (node < N_NODES) rowinfo[node] = make_int2(js, js + v);
    lofs[tid] = js;
    lcur[tid] = 0;
    __syncthreads();
    for (int i = tid; i < ne; i += 256) {
        unsigned e = eb[i];
        int li = e & 255u;
        int p = atomicAdd(&lcur[li], 1);
        col[lofs[li] + p] = (int)(e >> 8);
    }
    for (int j = raw; j < v; ++j) col[js + j] = PHANTOM;
}

// =============== K3: layer-1 agg — full wave/edge, scalar col, 8-wide ILP ===============

__global__ void __launch_bounds__(256) k_agg1(
        const unsigned short* __restrict__ xl1b, const float* __restrict__ esd1,
        const int2* __restrict__ rowinfo, const int* __restrict__ col,
        const float* __restrict__ b1, float* __restrict__ h1pre,
        float* __restrict__ sp1) {
    __shared__ float ps[64], pq[64];
    int tid = threadIdx.x;
    if (tid < 64) { ps[tid] = 0.f; pq[tid] = 0.f; }
    __syncthreads();
    int wid = tid >> 6, lane = tid & 63;
    int d = blockIdx.x * 4 + wid;               // grid exact
    int h = lane >> 4;
    float edh = esd1[d * 8 + 4 + h];
    float e0 = esd1[d * 8 + h] + edh;           // self loop
    float w0 = __expf(fmaxf(e0, NEG * e0));
    float acc = w0 * bfus(xl1b[(size_t)d * HID + lane]);
    float wsum = w0;
    int2 ri = rowinfo[d];
    int jb = __builtin_amdgcn_readfirstlane(ri.x);
    int je = __builtin_amdgcn_readfirstlane(ri.y);
    int j = jb;
    for (; j + 8 <= je; j += 8) {
        int4 ca = *(const int4*)(col + j);       // uniform addr -> scalar/broadcast
        int4 cb = *(const int4*)(col + j + 4);
        float x0 = bfus(xl1b[(size_t)ca.x * HID + lane]);
        float x1 = bfus(xl1b[(size_t)ca.y * HID + lane]);
        float x2 = bfus(xl1b[(size_t)ca.z * HID + lane]);
        float x3 = bfus(xl1b[(size_t)ca.w * HID + lane]);
        float x4 = bfus(xl1b[(size_t)cb.x * HID + lane]);
        float x5 = bfus(xl1b[(size_t)cb.y * HID + lane]);
        float x6 = bfus(xl1b[(size_t)cb.z * HID + lane]);
        float x7 = bfus(xl1b[(size_t)cb.w * HID + lane]);
        float g0 = esd1[ca.x * 8 + h] + edh;
        float g1 = esd1[ca.y * 8 + h] + edh;
        float g2 = esd1[ca.z * 8 + h] + edh;
        float g3 = esd1[ca.w * 8 + h] + edh;
        float g4 = esd1[cb.x * 8 + h] + edh;
        float g5 = esd1[cb.y * 8 + h] + edh;
        float g6 = esd1[cb.z * 8 + h] + edh;
        float g7 = esd1[cb.w * 8 + h] + edh;
        float w_0 = __expf(fmaxf(g0, NEG * g0));
        float w_1 = __expf(fmaxf(g1, NEG * g1));
        float w_2 = __expf(fmaxf(g2, NEG * g2));
        float w_3 = __expf(fmaxf(g3, NEG * g3));
        float w_4 = __expf(fmaxf(g4, NEG * g4));
        float w_5 = __expf(fmaxf(g5, NEG * g5));
        float w_6 = __expf(fmaxf(g6, NEG * g6));
        float w_7 = __expf(fmaxf(g7, NEG * g7));
        acc = fmaf(w_0, x0, acc); acc = fmaf(w_1, x1, acc);
        acc = fmaf(w_2, x2, acc); acc = fmaf(w_3, x3, acc);
        acc = fmaf(w_4, x4, acc); acc = fmaf(w_5, x5, acc);
        acc = fmaf(w_6, x6, acc); acc = fmaf(w_7, x7, acc);
        wsum += (w_0 + w_1) + (w_2 + w_3) + (w_4 + w_5) + (w_6 + w_7);
    }
    if (j < je) {   // 4-edge tail (rows padded to %4)
        int4 ca = *(const int4*)(col + j);
        float x0 = bfus(xl1b[(size_t)ca.x * HID + lane]);
        float x1 = bfus(xl1b[(size_t)ca.y * HID + lane]);
        float x2 = bfus(xl1b[(size_t)ca.z * HID + lane]);
        float x3 = bfus(xl1b[(size_t)ca.w * HID + lane]);
        float g0 = esd1[ca.x * 8 + h] + edh;
        float g1 = esd1[ca.y * 8 + h] + edh;
        float g2 = esd1[ca.z * 8 + h] + edh;
        float g3 = esd1[ca.w * 8 + h] + edh;
        float w_0 = __expf(fmaxf(g0, NEG * g0));
        float w_1 = __expf(fmaxf(g1, NEG * g1));
        float w_2 = __expf(fmaxf(g2, NEG * g2));
        float w_3 = __expf(fmaxf(g3, NEG * g3));
        acc = fmaf(w_0, x0, acc); acc = fmaf(w_1, x1, acc);
        acc = fmaf(w_2, x2, acc); acc = fmaf(w_3, x3, acc);
        wsum += (w_0 + w_1) + (w_2 + w_3);
    }
    float r = acc / wsum + b1[lane];
    h1pre[(size_t)d * HID + lane] = r;
    atomicAdd(&ps[lane], r);
    atomicAdd(&pq[lane], r * r);
    __syncthreads();
    int slot = (blockIdx.x & 63) * 128;
    if (tid < 64) atomicAdd(&sp1[slot + tid], ps[tid]);
    else if (tid < 128) atomicAdd(&sp1[slot + tid], pq[tid - 64]);
}

// =============== K4: layer-2 GEMM (bn1+relu fused; stats reduced inline) ===============

__global__ void __launch_bounds__(256) k_gemm2(
        const float* __restrict__ h1pre, const float* __restrict__ sp1,
        const float* __restrict__ g1, const float* __restrict__ be1,
        const float* __restrict__ W2, const float* __restrict__ a_src2,
        const float* __restrict__ a_dst2,
        unsigned short* __restrict__ xl2b, float* __restrict__ esd2) {
    __shared__ unsigned short Wt[48][80];
    __shared__ float A1s[64], B1s[64], red[128];
    int tid = threadIdx.x;
    for (int i = tid; i < 48 * 64; i += 256) {
        int n = i >> 6, k = i & 63;
        float v;
        if (n < 32) v = W2[k * 32 + n];
        else if (n < 34) {
            const float* a = (n == 32) ? a_src2 : a_dst2;
            v = 0.f;
            #pragma unroll
            for (int c = 0; c < 32; ++c) v = fmaf(W2[k * 32 + c], a[c], v);
        } else v = 0.f;
        Wt[n][k] = f2bf(v);
    }
    if (tid < 128) {
        float s = 0.f;
        for (int j = 0; j < 64; ++j) s += sp1[j * 128 + tid];
        red[tid] = s;
    }
    __syncthreads();
    if (tid < 64) {
        float mu = red[tid] * (1.f / N_NODES);
        float var = red[64 + tid] * (1.f / N_NODES) - mu * mu;
        float sc = g1[tid] * rsqrtf(var + BN_EPS);
        A1s[tid] = sc;
        B1s[tid] = be1[tid] - mu * sc;
    }
    __syncthreads();
    int lane = tid & 63, wid = tid >> 6;
    int tile = blockIdx.x * 4 + wid;
    if (tile >= N_TILES) return;
    int m = lane & 15, kg = lane >> 4;
    int base = tile * 16;
    const float* hr = h1pre + (size_t)(base + m) * HID + kg * 8;
    f32x4 acc[3];
    #pragma unroll
    for (int t = 0; t < 3; ++t) acc[t] = (f32x4){0.f, 0.f, 0.f, 0.f};
    #pragma unroll
    for (int s = 0; s < 2; ++s) {
        int k0 = s * 32 + kg * 8;
        f32x4 p = ((const f32x4*)(hr + s * 32))[0];
        f32x4 q = ((const f32x4*)(hr + s * 32))[1];
        f32x4 sa = *(const f32x4*)&A1s[k0];
        f32x4 sb = *(const f32x4*)&B1s[k0];
        f32x4 sa2 = *(const f32x4*)&A1s[k0 + 4];
        f32x4 sb2 = *(const f32x4*)&B1s[k0 + 4];
        short8 a;
        #pragma unroll
        for (int j = 0; j < 4; ++j) {
            float v = fmaf(p[j], sa[j], sb[j]);
            a[j] = (short)f2bf(v > 0.f ? v : 0.f);
        }
        #pragma unroll
        for (int j = 0; j < 4; ++j) {
            float v = fmaf(q[j], sa2[j], sb2[j]);
            a[4 + j] = (short)f2bf(v > 0.f ? v : 0.f);
        }
        #pragma unroll
        for (int t = 0; t < 3; ++t) {
            short8 b = *(const short8*)&Wt[t * 16 + m][s * 32 + kg * 8];
            acc[t] = __builtin_amdgcn_mfma_f32_16x16x32_bf16(a, b, acc[t], 0, 0, 0);
        }
    }
    #pragma unroll
    for (int r = 0; r < 4; ++r) {
        int node = base + kg * 4 + r;
        #pragma unroll
        for (int t = 0; t < 2; ++t)
            xl2b[(size_t)node * OUT_C + t * 16 + m] = f2bf(acc[t][r]);
        if (m < 2) esd2[node * 2 + m] = acc[2][r];
    }
}

// =============== K5: layer-2 agg — wave/node, halves take even/odd edges ===============

__global__ void __launch_bounds__(256) k_agg2(
        const unsigned short* __restrict__ xl2b, const float* __restrict__ esd2,
        const int2* __restrict__ rowinfo, const int* __restrict__ col,
        const float* __restrict__ b2, float* __restrict__ h2pre,
        float* __restrict__ sp2) {
    __shared__ float ps[32], pq[32];
    int tid = threadIdx.x;
    if (tid < 32) { ps[tid] = 0.f; pq[tid] = 0.f; }
    __syncthreads();
    int wid = tid >> 6, lane = tid & 63;
    int d = blockIdx.x * 4 + wid;               // grid exact
    int c2 = lane & 31, half = lane >> 5;
    float edh = esd2[d * 2 + 1];
    float acc = 0.f, wsum = 0.f;
    if (half == 0) {   // self loop on half 0
        float e0 = esd2[d * 2] + edh;
        float w0 = __expf(fmaxf(e0, NEG * e0));
        acc = w0 * bfus(xl2b[(size_t)d * OUT_C + c2]);
        wsum = w0;
    }
    int2 ri = rowinfo[d];
    int jb = __builtin_amdgcn_readfirstlane(ri.x);
    int je = __builtin_amdgcn_readfirstlane(ri.y);
    int j = jb;
    for (; j + 8 <= je; j += 8) {
        int4 ca = *(const int4*)(col + j);
        int4 cb = *(const int4*)(col + j + 4);
        int s0 = half ? ca.y : ca.x;
        int s1 = half ? ca.w : ca.z;
        int s2 = half ? cb.y : cb.x;
        int s3 = half ? cb.w : cb.z;
        float x0 = bfus(xl2b[(size_t)s0 * OUT_C + c2]);
        float x1 = bfus(xl2b[(size_t)s1 * OUT_C + c2]);
        float x2 = bfus(xl2b[(size_t)s2 * OUT_C + c2]);
        float x3 = bfus(xl2b[(size_t)s3 * OUT_C + c2]);
        float g0 = esd2[s0 * 2] + edh;
        float g1 = esd2[s1 * 2] + edh;
        float g2 = esd2[s2 * 2] + edh;
        float g3 = esd2[s3 * 2] + edh;
        float w_0 = __expf(fmaxf(g0, NEG * g0));
        float w_1 = __expf(fmaxf(g1, NEG * g1));
        float w_2 = __expf(fmaxf(g2, NEG * g2));
        float w_3 = __expf(fmaxf(g3, NEG * g3));
        acc = fmaf(w_0, x0, acc); acc = fmaf(w_1, x1, acc);
        acc = fmaf(w_2, x2, acc); acc = fmaf(w_3, x3, acc);
        wsum += (w_0 + w_1) + (w_2 + w_3);
    }
    if (j < je) {   // 4-edge tail
        int4 ca = *(const int4*)(col + j);
        int s0 = half ? ca.y : ca.x;
        int s1 = half ? ca.w : ca.z;
        float x0 = bfus(xl2b[(size_t)s0 * OUT_C + c2]);
        float x1 = bfus(xl2b[(size_t)s1 * OUT_C + c2]);
        float g0 = esd2[s0 * 2] + edh;
        float g1 = esd2[s1 * 2] + edh;
        float w_0 = __expf(fmaxf(g0, NEG * g0));
        float w_1 = __expf(fmaxf(g1, NEG * g1));
        acc = fmaf(w_0, x0, acc); acc = fmaf(w_1, x1, acc);
        wsum += w_0 + w_1;
    }
    acc += __shfl_xor(acc, 32, 64);
    wsum += __shfl_xor(wsum, 32, 64);
    if (half == 0) {
        float r = acc / wsum + b2[c2];
        h2pre[(size_t)d * OUT_C + c2] = r;
        atomicAdd(&ps[c2], r);
        atomicAdd(&pq[c2], r * r);
    }
    __syncthreads();
    int slot = (blockIdx.x & 63) * 64;
    if (tid < 32) atomicAdd(&sp2[slot + tid], ps[tid]);
    else if (tid < 64) atomicAdd(&sp2[slot + tid], pq[tid - 32]);
}

// =============== K6: fused BN2-apply + pool partials (stats reduced inline) ===============

__global__ void __launch_bounds__(256) k_bnpool(
        const float* __restrict__ h2pre, const float* __restrict__ sp2,
        const float* __restrict__ g2, const float* __restrict__ be2,
        const int* __restrict__ gstart, float* __restrict__ out,
        float* __restrict__ pfeat) {
    __shared__ float A2[OUT_C], B2[OUT_C], red[64];
    int tid = threadIdx.x;
    if (tid < 64) {
        float s = 0.f;
        for (int j = 0; j < 64; ++j) s += sp2[j * 64 + tid];
        red[tid] = s;
    }
    __syncthreads();
    if (tid < 32) {
        float mu = red[tid] * (1.f / N_NODES);
        float var = red[32 + tid] * (1.f / N_NODES) - mu * mu;
        float sc = g2[tid] * rsqrtf(var + BN_EPS);
        A2[tid] = sc;
        B2[tid] = be2[tid] - mu * sc;
    }
    __syncthreads();
    int g = blockIdx.x >> 2, part = blockIdx.x & 3;
    int s = gstart[g], e = gstart[g + 1];
    int len = e - s;
    int qq = (len + 3) >> 2;
    int ps = s + part * qq;
    int pe = ps + qq; if (pe > e) pe = e;
    int c = tid & 31, r = tid >> 5;
    float sum = 0.f, mx = -INFINITY;
    for (int n = ps + r; n < pe; n += 8) {
        float v = fmaf(h2pre[(size_t)n * OUT_C + c], A2[c], B2[c]);
        out[(size_t)n * OUT_C + c] = v;
        sum += v;
        mx = fmaxf(mx, v);
    }
    __shared__ float lsum[256], lmax[256];
    lsum[tid] = sum;
    lmax[tid] = mx;
    __syncthreads();
    if (tid < 32) {
        float ts = 0.f, tm = -INFINITY;
        for (int rr = 0; rr < 8; ++rr) {
            ts += lsum[rr * 32 + c];
            tm = fmaxf(tm, lmax[rr * 32 + c]);
        }
        pfeat[blockIdx.x * 64 + c] = ts;
        pfeat[blockIdx.x * 64 + 32 + c] = tm;
    }
}

// =============== K7: MLP head (+pool combine) -> graph_emb ===============

__global__ void __launch_bounds__(256) k_mlp(
        const float* __restrict__ pfeat, const int* __restrict__ gstart,
        const float* __restrict__ fcW1, const float* __restrict__ fcb1,
        const float* __restrict__ fcW2, const float* __restrict__ fcb2,
        float* __restrict__ out) {
    __shared__ float gf[N_GRAPHS * 64];
    __shared__ float t1[N_GRAPHS * OUT_C];
    int tid = threadIdx.x;
    for (int i = tid; i < N_GRAPHS * 32; i += 256) {
        int g = i >> 5, c = i & 31;
        float sm = 0.f, mx = -INFINITY;
        #pragma unroll
        for (int p = 0; p < 4; ++p) {
            sm += pfeat[(g * 4 + p) * 64 + c];
            mx = fmaxf(mx, pfeat[(g * 4 + p) * 64 + 32 + c]);
        }
        int cnt = gstart[g + 1] - gstart[g];
        gf[g * 64 + c] = (cnt > 0) ? sm / (float)cnt : 0.f;
        gf[g * 64 + 32 + c] = (cnt > 0) ? mx : 0.f;
    }
    __syncthreads();
    for (int i = tid; i < N_GRAPHS * OUT_C; i += 256) {
        int g = i >> 5, j = i & 31;
        float a = fcb1[j];
        for (int k = 0; k < 64; ++k) a = fmaf(gf[g * 64 + k], fcW1[k * OUT_C + j], a);
        t1[i] = a > 0.f ? a : 0.f;
    }
    __syncthreads();
    for (int i = tid; i < N_GRAPHS * OUT_C; i += 256) {
        int g = i >> 5, oc = i & 31;
        float a = fcb2[oc];
        for (int k = 0; k < OUT_C; ++k) a = fmaf(t1[g * OUT_C + k], fcW2[k * OUT_C + oc], a);
        out[(size_t)N_NODES * OUT_C + g * OUT_C + oc] = a;
    }
}

// =============== launch ===============

extern "C" void kernel_launch(void* const* d_in, const int* in_sizes, int n_in,
                              void* d_out, int out_size, void* d_ws, size_t ws_size,
                              hipStream_t stream) {
    (void)in_sizes; (void)n_in; (void)out_size; (void)ws_size;
    const float* x      = (const float*)d_in[0];
    const int*   ei     = (const int*)d_in[1];
    const int*   batch  = (const int*)d_in[2];
    const float* W1     = (const float*)d_in[3];
    const float* a_src1 = (const float*)d_in[4];
    const float* a_dst1 = (const float*)d_in[5];
    const float* b1     = (const float*)d_in[6];
    const float* g1     = (const float*)d_in[7];
    const float* be1    = (const float*)d_in[8];
    const float* W2     = (const float*)d_in[9];
    const float* a_src2 = (const float*)d_in[10];
    const float* a_dst2 = (const float*)d_in[11];
    const float* b2     = (const float*)d_in[12];
    const float* g2     = (const float*)d_in[13];
    const float* be2    = (const float*)d_in[14];
    const float* fcW1   = (const float*)d_in[15];
    const float* fcb1   = (const float*)d_in[16];
    const float* fcW2   = (const float*)d_in[17];
    const float* fcb2   = (const float*)d_in[18];
    const int* srcv = ei;
    const int* dstv = ei + N_EDGES;
    float* out = (float*)d_out;

    char* w = (char*)d_ws;
    size_t o = 0;
    #define ALLOC(nbytes) (w + o); o = (o + (size_t)(nbytes) + 15) & ~(size_t)15
    int*   gcur      = (int*)ALLOC(N_BUCKETS * 4);
    size_t zero_bytes = o;                       // only gcur needs pre-zero
    float* sp1       = (float*)ALLOC(64 * 128 * 4);   // zeroed by k_front misc
    float* sp2       = (float*)ALLOC(64 * 64 * 4);    // zeroed by k_front misc
    int2*  rowinfo   = (int2*)ALLOC((size_t)N_NODES * 8);
    int*   gst       = (int*)ALLOC(66 * 4);
    int*   col       = (int*)ALLOC(((size_t)N_BUCKETS * CAP_PAD + 256) * 4);
    unsigned* ebuf   = (unsigned*)ALLOC((size_t)N_BUCKETS * BUCKET_CAP * 4);
    unsigned short* xl1b = (unsigned short*)ALLOC((size_t)(N_NODES + 1) * HID * 2);
    float* esd1      = (float*)ALLOC((size_t)(N_NODES + 1) * 8 * 4);
    float* h1pre     = (float*)ALLOC((size_t)N_NODES * HID * 4);
    unsigned short* xl2b = (unsigned short*)ALLOC((size_t)(N_NODES + 1) * OUT_C * 2);
    float* esd2      = (float*)ALLOC((size_t)(N_NODES + 1) * 2 * 4);
    float* pfeat     = (float*)ALLOC(256 * 64 * 4);
    #undef ALLOC
    float* h2pre = h1pre;   // h1pre dead after k_gemm2

    hipMemsetAsync(d_ws, 0, zero_bytes, stream);
    k_front <<<BIN_NB + GEMM1_NB + 1, 256, 0, stream>>>(
        srcv, dstv, gcur, ebuf, x, W1, a_src1, a_dst1,
        xl1b, esd1, xl2b, esd2, batch, gst, sp1, sp2);
    k_csr   <<<N_BUCKETS, 256, 0, stream>>>(ebuf, gcur, rowinfo, col);
    k_agg1  <<<N_NODES / 4, 256, 0, stream>>>(
        xl1b, esd1, rowinfo, col, b1, h1pre, sp1);
    k_gemm2 <<<(N_TILES + 3) / 4, 256, 0, stream>>>(
        h1pre, sp1, g1, be1, W2, a_src2, a_dst2, xl2b, esd2);
    k_agg2  <<<N_NODES / 4, 256, 0, stream>>>(
        xl2b, esd2, rowinfo, col, b2, h2pre, sp2);
    k_bnpool<<<256, 256, 0, stream>>>(h2pre, sp2, g2, be2, gst, out, pfeat);
    k_mlp   <<<1, 256, 0, stream>>>(pfeat, gst, fcW1, fcb1, fcW2, fcb2, out);
}

// Round 9
// 243.646 us; speedup vs baseline: 2.3138x; 1.0832x over previous
//
#include <hip/hip_runtime.h>
#include <math.h>

#define N_NODES 50000
#define N_EDGES 800000
#define N_GRAPHS 64
#define D_IN 128
#define HID 64
#define OUT_C 32
#define NEG 0.2f
#define BN_EPS 1e-5f
#define N_TILES 3125    // N_NODES / 16
#define N_BUCKETS 196   // bucket = dst >> 8
#define BIN_CHUNK 4096
#define BIN_NB 196      // ceil(N_EDGES / BIN_CHUNK)
#define GEMM1_NB 782    // ceil(N_TILES / 4)
#define BUCKET_CAP 5120 // mean 4082, sd ~64 -> 16 sigma margin
#define CAP_PAD 6144    // fixed col region per bucket
#define PHANTOM N_NODES // sentinel node: xl rows = 0, esd = -1e30 -> weight 0
#define AGG_NB 1024     // persistent agg blocks (4096 waves)
#define N_WAVES (AGG_NB * 4)

typedef __attribute__((ext_vector_type(8))) short short8;
typedef __attribute__((ext_vector_type(4))) float f32x4;

static __device__ inline unsigned short f2bf(float f) {
    unsigned u = __float_as_uint(f);
    u += 0x7FFF + ((u >> 16) & 1);
    return (unsigned short)(u >> 16);
}
static __device__ inline float bfus(unsigned short u) {
    return __uint_as_float((unsigned)u << 16);
}

// =============== K1: fused front (bin | gemm1 | misc), role by blockIdx ===============

__global__ void __launch_bounds__(256) k_front(
        const int* __restrict__ src, const int* __restrict__ dst,
        int* __restrict__ gcur, unsigned* __restrict__ ebuf,
        const float* __restrict__ x, const float* __restrict__ W1,
        const float* __restrict__ a_src1, const float* __restrict__ a_dst1,
        unsigned short* __restrict__ xl1b, float* __restrict__ esd1,
        unsigned short* __restrict__ xl2b, float* __restrict__ esd2,
        const int* __restrict__ batch, int* __restrict__ gstart,
        float* __restrict__ sp1, float* __restrict__ sp2) {
    __shared__ __align__(16) char smem[23616];
    int tid = threadIdx.x;
    int blk = blockIdx.x;

    if (blk < BIN_NB) {
        // ---- bin role: LDS-binned edge partition into ebuf (4B records) ----
        int* cnt = (int*)smem;
        int* lofs = cnt + 256;
        int* dstoff = lofs + 256;
        int* ws4 = dstoff + 256;
        unsigned* stage = (unsigned*)(ws4 + 4);
        unsigned char* stage_b = (unsigned char*)(stage + BIN_CHUNK);
        cnt[tid] = 0;
        __syncthreads();
        int e0 = blk * BIN_CHUNK;
        int ne = N_EDGES - e0; if (ne > BIN_CHUNK) ne = BIN_CHUNK;
        unsigned rec[16]; int bkt[16], lp[16];
        #pragma unroll
        for (int j = 0; j < 16; ++j) {
            int r = j * 256 + tid;
            if (r < ne) {
                int e = e0 + r;
                int s = src[e], d = dst[e];
                rec[j] = ((unsigned)s << 8) | (unsigned)(d & 255);
                bkt[j] = d >> 8;
                lp[j] = atomicAdd(&cnt[bkt[j]], 1);
            } else bkt[j] = -1;
        }
        __syncthreads();
        int v = cnt[tid];
        int lane = tid & 63, wid = tid >> 6;
        int incl = v;
        #pragma unroll
        for (int off = 1; off < 64; off <<= 1) {
            int t = __shfl_up(incl, off, 64);
            if (lane >= off) incl += t;
        }
        if (lane == 63) ws4[wid] = incl;
        __syncthreads();
        if (tid == 0) {
            int a = ws4[0];
            #pragma unroll
            for (int j = 1; j < 4; ++j) { a += ws4[j]; ws4[j] = a; }
        }
        __syncthreads();
        if (wid > 0) incl += ws4[wid - 1];
        lofs[tid] = incl - v;
        __syncthreads();
        #pragma unroll
        for (int j = 0; j < 16; ++j) {
            if (bkt[j] >= 0) {
                int idx = lofs[bkt[j]] + lp[j];
                stage[idx] = rec[j];
                stage_b[idx] = (unsigned char)bkt[j];
            }
        }
        if (tid < N_BUCKETS && cnt[tid] > 0) {
            int g = atomicAdd(&gcur[tid], cnt[tid]);
            dstoff[tid] = tid * BUCKET_CAP + g - lofs[tid];
        }
        __syncthreads();
        for (int i = tid; i < ne; i += 256) {
            int b = stage_b[i];
            ebuf[dstoff[b] + i] = stage[i];
        }
        return;
    }

    if (blk < BIN_NB + GEMM1_NB) {
        // ---- gemm1 role: xl1b = bf16(x@W1), esd1 = x@[W1 a_src1 | W1 a_dst1] ----
        typedef unsigned short WtRow[144];
        WtRow* Wt = (WtRow*)smem;   // [80][144]
        for (int i = tid; i < 80 * 128; i += 256) {
            int n = i >> 7, k = i & 127;
            float v;
            if (n < 64) v = W1[k * 64 + n];
            else if (n < 72) {
                int hh = (n - 64) & 3;
                const float* a = ((n - 64) < 4 ? a_src1 : a_dst1) + hh * 16;
                v = 0.f;
                #pragma unroll
                for (int c = 0; c < 16; ++c) v = fmaf(W1[k * 64 + hh * 16 + c], a[c], v);
            } else v = 0.f;
            Wt[n][k] = f2bf(v);
        }
        __syncthreads();
        int lane = tid & 63, wid = tid >> 6;
        int tile = (blk - BIN_NB) * 4 + wid;
        if (tile >= N_TILES) return;
        int m = lane & 15, kg = lane >> 4;
        int base = tile * 16;
        const float* xr = x + (size_t)(base + m) * D_IN + kg * 8;
        f32x4 acc[5];
        #pragma unroll
        for (int t = 0; t < 5; ++t) acc[t] = (f32x4){0.f, 0.f, 0.f, 0.f};
        #pragma unroll
        for (int s = 0; s < 4; ++s) {
            f32x4 p = ((const f32x4*)(xr + s * 32))[0];
            f32x4 q = ((const f32x4*)(xr + s * 32))[1];
            short8 a;
            a[0] = (short)f2bf(p[0]); a[1] = (short)f2bf(p[1]);
            a[2] = (short)f2bf(p[2]); a[3] = (short)f2bf(p[3]);
            a[4] = (short)f2bf(q[0]); a[5] = (short)f2bf(q[1]);
            a[6] = (short)f2bf(q[2]); a[7] = (short)f2bf(q[3]);
            #pragma unroll
            for (int t = 0; t < 5; ++t) {
                short8 b = *(const short8*)&Wt[t * 16 + m][s * 32 + kg * 8];
                acc[t] = __builtin_amdgcn_mfma_f32_16x16x32_bf16(a, b, acc[t], 0, 0, 0);
            }
        }
        #pragma unroll
        for (int r = 0; r < 4; ++r) {
            int node = base + kg * 4 + r;
            #pragma unroll
            for (int t = 0; t < 4; ++t)
                xl1b[(size_t)node * HID + t * 16 + m] = f2bf(acc[t][r]);
            if (m < 8) esd1[node * 8 + m] = acc[4][r];
        }
        return;
    }

    // ---- misc role (one block): gstart, phantoms, zero stats partials ----
    if (tid <= N_GRAPHS) {
        int g = tid;
        int lo = 0, hi = N_NODES;
        while (lo < hi) {
            int mid = (lo + hi) >> 1;
            if (batch[mid] < g) lo = mid + 1; else hi = mid;
        }
        gstart[g] = lo;
    }
    if (tid >= 128 && tid < 192) xl1b[(size_t)PHANTOM * HID + (tid - 128)] = 0;
    if (tid >= 192 && tid < 200) esd1[(size_t)PHANTOM * 8 + (tid - 192)] = -1e30f;
    if (tid >= 200 && tid < 232) xl2b[(size_t)PHANTOM * OUT_C + (tid - 200)] = 0;
    if (tid >= 232 && tid < 234) esd2[(size_t)PHANTOM * 2 + (tid - 232)] = -1e30f;
    for (int i = tid; i < 64 * 128; i += 256) sp1[i] = 0.f;
    for (int i = tid; i < 64 * 64; i += 256) sp2[i] = 0.f;
}

// =============== K2: merged CSR build (count + intra-bucket scan + fill) ===============

__global__ void __launch_bounds__(256) k_csr(
        const unsigned* __restrict__ ebuf, const int* __restrict__ gcur,
        int2* __restrict__ rowinfo, int* __restrict__ col) {
    __shared__ int lcnt[256], lofs[256], lcur[256];
    __shared__ int ws[4];
    int tid = threadIdx.x, b = blockIdx.x;
    lcnt[tid] = 0;
    __syncthreads();
    int ne = gcur[b];
    const unsigned* eb = ebuf + (size_t)b * BUCKET_CAP;
    for (int i = tid; i < ne; i += 256)
        atomicAdd(&lcnt[eb[i] & 255u], 1);
    __syncthreads();
    int raw = lcnt[tid];
    int v = (raw + 3) & ~3;
    int lane = tid & 63, wid = tid >> 6;
    int incl = v;
    #pragma unroll
    for (int off = 1; off < 64; off <<= 1) {
        int t = __shfl_up(incl, off, 64);
        if (lane >= off) incl += t;
    }
    if (lane == 63) ws[wid] = incl;
    __syncthreads();
    if (tid == 0) {
        int a = ws[0];
        #pragma unroll
        for (int j = 1; j < 4; ++j) { a += ws[j]; ws[j] = a; }
    }
    __syncthreads();
    if (wid > 0) incl += ws[wid - 1];
    int js = b * CAP_PAD + (incl - v);
    int node = b * 256 + tid;
    if (node < N_NODES) rowinfo[node] = make_int2(js, js + v);
    lofs[tid] = js;
    lcur[tid] = 0;
    __syncthreads();
    for (int i = tid; i < ne; i += 256) {
        unsigned e = eb[i];
        int li = e & 255u;
        int p = atomicAdd(&lcur[li], 1);
        col[lofs[li] + p] = (int)(e >> 8);
    }
    for (int j = raw; j < v; ++j) col[js + j] = PHANTOM;
}

// =============== K3: layer-1 agg — persistent waves, pipelined col, reg stats ===============

__global__ void __launch_bounds__(256) k_agg1(
        const unsigned short* __restrict__ xl1b, const float* __restrict__ esd1,
        const int2* __restrict__ rowinfo, const int* __restrict__ col,
        const float* __restrict__ b1, float* __restrict__ h1pre,
        float* __restrict__ sp1) {
    __shared__ float ps[64], pq[64];
    int tid = threadIdx.x;
    if (tid < 64) { ps[tid] = 0.f; pq[tid] = 0.f; }
    __syncthreads();
    int wid = tid >> 6, lane = tid & 63;
    int wave = blockIdx.x * 4 + wid;
    int h = lane >> 4;
    float bl = b1[lane];
    float s = 0.f, q = 0.f;                     // per-lane (=channel) BN partials
    for (int d = wave; d < N_NODES; d += N_WAVES) {
        float edh = esd1[d * 8 + 4 + h];
        float e0 = esd1[d * 8 + h] + edh;       // self loop
        float w0 = __expf(fmaxf(e0, NEG * e0));
        float acc = w0 * bfus(xl1b[(size_t)d * HID + lane]);
        float wsum = w0;
        int2 ri = rowinfo[d];
        int jb = __builtin_amdgcn_readfirstlane(ri.x);
        int je = __builtin_amdgcn_readfirstlane(ri.y);
        int4 ca = *(const int4*)(col + jb);      // rows >=4 edges? rows can be len 0!
        int4 cb = *(const int4*)(col + jb + 4);  // slack-safe overread
        int j = jb;
        for (; j + 8 <= je; j += 8) {
            int4 na = *(const int4*)(col + j + 8);   // prefetch next (slack-safe)
            int4 nb = *(const int4*)(col + j + 12);
            float x0 = bfus(xl1b[(size_t)ca.x * HID + lane]);
            float x1 = bfus(xl1b[(size_t)ca.y * HID + lane]);
            float x2 = bfus(xl1b[(size_t)ca.z * HID + lane]);
            float x3 = bfus(xl1b[(size_t)ca.w * HID + lane]);
            float x4 = bfus(xl1b[(size_t)cb.x * HID + lane]);
            float x5 = bfus(xl1b[(size_t)cb.y * HID + lane]);
            float x6 = bfus(xl1b[(size_t)cb.z * HID + lane]);
            float x7 = bfus(xl1b[(size_t)cb.w * HID + lane]);
            float g0 = esd1[ca.x * 8 + h] + edh;
            float g1 = esd1[ca.y * 8 + h] + edh;
            float g2 = esd1[ca.z * 8 + h] + edh;
            float g3 = esd1[ca.w * 8 + h] + edh;
            float g4 = esd1[cb.x * 8 + h] + edh;
            float g5 = esd1[cb.y * 8 + h] + edh;
            float g6 = esd1[cb.z * 8 + h] + edh;
            float g7 = esd1[cb.w * 8 + h] + edh;
            float w_0 = __expf(fmaxf(g0, NEG * g0));
            float w_1 = __expf(fmaxf(g1, NEG * g1));
            float w_2 = __expf(fmaxf(g2, NEG * g2));
            float w_3 = __expf(fmaxf(g3, NEG * g3));
            float w_4 = __expf(fmaxf(g4, NEG * g4));
            float w_5 = __expf(fmaxf(g5, NEG * g5));
            float w_6 = __expf(fmaxf(g6, NEG * g6));
            float w_7 = __expf(fmaxf(g7, NEG * g7));
            acc = fmaf(w_0, x0, acc); acc = fmaf(w_1, x1, acc);
            acc = fmaf(w_2, x2, acc); acc = fmaf(w_3, x3, acc);
            acc = fmaf(w_4, x4, acc); acc = fmaf(w_5, x5, acc);
            acc = fmaf(w_6, x6, acc); acc = fmaf(w_7, x7, acc);
            wsum += (w_0 + w_1) + (w_2 + w_3) + (w_4 + w_5) + (w_6 + w_7);
            ca = na; cb = nb;
        }
        if (j < je) {   // 4-edge tail (rows padded to %4); ca holds it
            float x0 = bfus(xl1b[(size_t)ca.x * HID + lane]);
            float x1 = bfus(xl1b[(size_t)ca.y * HID + lane]);
            float x2 = bfus(xl1b[(size_t)ca.z * HID + lane]);
            float x3 = bfus(xl1b[(size_t)ca.w * HID + lane]);
            float g0 = esd1[ca.x * 8 + h] + edh;
            float g1 = esd1[ca.y * 8 + h] + edh;
            float g2 = esd1[ca.z * 8 + h] + edh;
            float g3 = esd1[ca.w * 8 + h] + edh;
            float w_0 = __expf(fmaxf(g0, NEG * g0));
            float w_1 = __expf(fmaxf(g1, NEG * g1));
            float w_2 = __expf(fmaxf(g2, NEG * g2));
            float w_3 = __expf(fmaxf(g3, NEG * g3));
            acc = fmaf(w_0, x0, acc); acc = fmaf(w_1, x1, acc);
            acc = fmaf(w_2, x2, acc); acc = fmaf(w_3, x3, acc);
            wsum += (w_0 + w_1) + (w_2 + w_3);
        }
        float r = acc / wsum + bl;
        h1pre[(size_t)d * HID + lane] = r;
        s += r;
        q = fmaf(r, r, q);
    }
    atomicAdd(&ps[lane], s);
    atomicAdd(&pq[lane], q);
    __syncthreads();
    int slot = (blockIdx.x & 63) * 128;
    if (tid < 64) atomicAdd(&sp1[slot + tid], ps[tid]);
    else if (tid < 128) atomicAdd(&sp1[slot + tid], pq[tid - 64]);
}

// =============== K4: layer-2 GEMM (bn1+relu fused; stats reduced inline) ===============

__global__ void __launch_bounds__(256) k_gemm2(
        const float* __restrict__ h1pre, const float* __restrict__ sp1,
        const float* __restrict__ g1, const float* __restrict__ be1,
        const float* __restrict__ W2, const float* __restrict__ a_src2,
        const float* __restrict__ a_dst2,
        unsigned short* __restrict__ xl2b, float* __restrict__ esd2) {
    __shared__ unsigned short Wt[48][80];
    __shared__ float A1s[64], B1s[64], red[128];
    int tid = threadIdx.x;
    for (int i = tid; i < 48 * 64; i += 256) {
        int n = i >> 6, k = i & 63;
        float v;
        if (n < 32) v = W2[k * 32 + n];
        else if (n < 34) {
            const float* a = (n == 32) ? a_src2 : a_dst2;
            v = 0.f;
            #pragma unroll
            for (int c = 0; c < 32; ++c) v = fmaf(W2[k * 32 + c], a[c], v);
        } else v = 0.f;
        Wt[n][k] = f2bf(v);
    }
    if (tid < 128) {
        float s = 0.f;
        for (int j = 0; j < 64; ++j) s += sp1[j * 128 + tid];
        red[tid] = s;
    }
    __syncthreads();
    if (tid < 64) {
        float mu = red[tid] * (1.f / N_NODES);
        float var = red[64 + tid] * (1.f / N_NODES) - mu * mu;
        float sc = g1[tid] * rsqrtf(var + BN_EPS);
        A1s[tid] = sc;
        B1s[tid] = be1[tid] - mu * sc;
    }
    __syncthreads();
    int lane = tid & 63, wid = tid >> 6;
    int tile = blockIdx.x * 4 + wid;
    if (tile >= N_TILES) return;
    int m = lane & 15, kg = lane >> 4;
    int base = tile * 16;
    const float* hr = h1pre + (size_t)(base + m) * HID + kg * 8;
    f32x4 acc[3];
    #pragma unroll
    for (int t = 0; t < 3; ++t) acc[t] = (f32x4){0.f, 0.f, 0.f, 0.f};
    #pragma unroll
    for (int s = 0; s < 2; ++s) {
        int k0 = s * 32 + kg * 8;
        f32x4 p = ((const f32x4*)(hr + s * 32))[0];
        f32x4 q = ((const f32x4*)(hr + s * 32))[1];
        f32x4 sa = *(const f32x4*)&A1s[k0];
        f32x4 sb = *(const f32x4*)&B1s[k0];
        f32x4 sa2 = *(const f32x4*)&A1s[k0 + 4];
        f32x4 sb2 = *(const f32x4*)&B1s[k0 + 4];
        short8 a;
        #pragma unroll
        for (int j = 0; j < 4; ++j) {
            float v = fmaf(p[j], sa[j], sb[j]);
            a[j] = (short)f2bf(v > 0.f ? v : 0.f);
        }
        #pragma unroll
        for (int j = 0; j < 4; ++j) {
            float v = fmaf(q[j], sa2[j], sb2[j]);
            a[4 + j] = (short)f2bf(v > 0.f ? v : 0.f);
        }
        #pragma unroll
        for (int t = 0; t < 3; ++t) {
            short8 b = *(const short8*)&Wt[t * 16 + m][s * 32 + kg * 8];
            acc[t] = __builtin_amdgcn_mfma_f32_16x16x32_bf16(a, b, acc[t], 0, 0, 0);
        }
    }
    #pragma unroll
    for (int r = 0; r < 4; ++r) {
        int node = base + kg * 4 + r;
        #pragma unroll
        for (int t = 0; t < 2; ++t)
            xl2b[(size_t)node * OUT_C + t * 16 + m] = f2bf(acc[t][r]);
        if (m < 2) esd2[node * 2 + m] = acc[2][r];
    }
}

// =============== K5: layer-2 agg — persistent waves, halves take even/odd edges ===============

__global__ void __launch_bounds__(256) k_agg2(
        const unsigned short* __restrict__ xl2b, const float* __restrict__ esd2,
        const int2* __restrict__ rowinfo, const int* __restrict__ col,
        const float* __restrict__ b2, float* __restrict__ h2pre,
        float* __restrict__ sp2) {
    __shared__ float ps[32], pq[32];
    int tid = threadIdx.x;
    if (tid < 32) { ps[tid] = 0.f; pq[tid] = 0.f; }
    __syncthreads();
    int wid = tid >> 6, lane = tid & 63;
    int wave = blockIdx.x * 4 + wid;
    int c2 = lane & 31, half = lane >> 5;
    float bl = b2[c2];
    float s = 0.f, q = 0.f;
    for (int d = wave; d < N_NODES; d += N_WAVES) {
        float edh = esd2[d * 2 + 1];
        float acc = 0.f, wsum = 0.f;
        if (half == 0) {   // self loop on half 0
            float e0 = esd2[d * 2] + edh;
            float w0 = __expf(fmaxf(e0, NEG * e0));
            acc = w0 * bfus(xl2b[(size_t)d * OUT_C + c2]);
            wsum = w0;
        }
        int2 ri = rowinfo[d];
        int jb = __builtin_amdgcn_readfirstlane(ri.x);
        int je = __builtin_amdgcn_readfirstlane(ri.y);
        int4 ca = *(const int4*)(col + jb);
        int4 cb = *(const int4*)(col + jb + 4);
        int j = jb;
        for (; j + 8 <= je; j += 8) {
            int4 na = *(const int4*)(col + j + 8);
            int4 nb = *(const int4*)(col + j + 12);
            int s0 = half ? ca.y : ca.x;
            int s1 = half ? ca.w : ca.z;
            int s2 = half ? cb.y : cb.x;
            int s3 = half ? cb.w : cb.z;
            float x0 = bfus(xl2b[(size_t)s0 * OUT_C + c2]);
            float x1 = bfus(xl2b[(size_t)s1 * OUT_C + c2]);
            float x2 = bfus(xl2b[(size_t)s2 * OUT_C + c2]);
            float x3 = bfus(xl2b[(size_t)s3 * OUT_C + c2]);
            float g0 = esd2[s0 * 2] + edh;
            float g1 = esd2[s1 * 2] + edh;
            float g2 = esd2[s2 * 2] + edh;
            float g3 = esd2[s3 * 2] + edh;
            float w_0 = __expf(fmaxf(g0, NEG * g0));
            float w_1 = __expf(fmaxf(g1, NEG * g1));
            float w_2 = __expf(fmaxf(g2, NEG * g2));
            float w_3 = __expf(fmaxf(g3, NEG * g3));
            acc = fmaf(w_0, x0, acc); acc = fmaf(w_1, x1, acc);
            acc = fmaf(w_2, x2, acc); acc = fmaf(w_3, x3, acc);
            wsum += (w_0 + w_1) + (w_2 + w_3);
            ca = na; cb = nb;
        }
        if (j < je) {   // 4-edge tail; ca holds it
            int s0 = half ? ca.y : ca.x;
            int s1 = half ? ca.w : ca.z;
            float x0 = bfus(xl2b[(size_t)s0 * OUT_C + c2]);
            float x1 = bfus(xl2b[(size_t)s1 * OUT_C + c2]);
            float g0 = esd2[s0 * 2] + edh;
            float g1 = esd2[s1 * 2] + edh;
            float w_0 = __expf(fmaxf(g0, NEG * g0));
            float w_1 = __expf(fmaxf(g1, NEG * g1));
            acc = fmaf(w_0, x0, acc); acc = fmaf(w_1, x1, acc);
            wsum += w_0 + w_1;
        }
        acc += __shfl_xor(acc, 32, 64);
        wsum += __shfl_xor(wsum, 32, 64);
        if (half == 0) {
            float r = acc / wsum + bl;
            h2pre[(size_t)d * OUT_C + c2] = r;
            s += r;
            q = fmaf(r, r, q);
        }
    }
    if (half == 0) {
        atomicAdd(&ps[c2], s);
        atomicAdd(&pq[c2], q);
    }
    __syncthreads();
    int slot = (blockIdx.x & 63) * 64;
    if (tid < 32) atomicAdd(&sp2[slot + tid], ps[tid]);
    else if (tid < 64) atomicAdd(&sp2[slot + tid], pq[tid - 32]);
}

// =============== K6: fused BN2-apply + pool partials (stats reduced inline) ===============

__global__ void __launch_bounds__(256) k_bnpool(
        const float* __restrict__ h2pre, const float* __restrict__ sp2,
        const float* __restrict__ g2, const float* __restrict__ be2,
        const int* __restrict__ gstart, float* __restrict__ out,
        float* __restrict__ pfeat) {
    __shared__ float A2[OUT_C], B2[OUT_C], red[64];
    int tid = threadIdx.x;
    if (tid < 64) {
        float s = 0.f;
        for (int j = 0; j < 64; ++j) s += sp2[j * 64 + tid];
        red[tid] = s;
    }
    __syncthreads();
    if (tid < 32) {
        float mu = red[tid] * (1.f / N_NODES);
        float var = red[32 + tid] * (1.f / N_NODES) - mu * mu;
        float sc = g2[tid] * rsqrtf(var + BN_EPS);
        A2[tid] = sc;
        B2[tid] = be2[tid] - mu * sc;
    }
    __syncthreads();
    int g = blockIdx.x >> 2, part = blockIdx.x & 3;
    int s = gstart[g], e = gstart[g + 1];
    int len = e - s;
    int qq = (len + 3) >> 2;
    int ps = s + part * qq;
    int pe = ps + qq; if (pe > e) pe = e;
    int c = tid & 31, r = tid >> 5;
    float sum = 0.f, mx = -INFINITY;
    for (int n = ps + r; n < pe; n += 8) {
        float v = fmaf(h2pre[(size_t)n * OUT_C + c], A2[c], B2[c]);
        out[(size_t)n * OUT_C + c] = v;
        sum += v;
        mx = fmaxf(mx, v);
    }
    __shared__ float lsum[256], lmax[256];
    lsum[tid] = sum;
    lmax[tid] = mx;
    __syncthreads();
    if (tid < 32) {
        float ts = 0.f, tm = -INFINITY;
        for (int rr = 0; rr < 8; ++rr) {
            ts += lsum[rr * 32 + c];
            tm = fmaxf(tm, lmax[rr * 32 + c]);
        }
        pfeat[blockIdx.x * 64 + c] = ts;
        pfeat[blockIdx.x * 64 + 32 + c] = tm;
    }
}

// =============== K7: MLP head (+pool combine) -> graph_emb ===============

__global__ void __launch_bounds__(256) k_mlp(
        const float* __restrict__ pfeat, const int* __restrict__ gstart,
        const float* __restrict__ fcW1, const float* __restrict__ fcb1,
        const float* __restrict__ fcW2, const float* __restrict__ fcb2,
        float* __restrict__ out) {
    __shared__ float gf[N_GRAPHS * 64];
    __shared__ float t1[N_GRAPHS * OUT_C];
    int tid = threadIdx.x;
    for (int i = tid; i < N_GRAPHS * 32; i += 256) {
        int g = i >> 5, c = i & 31;
        float sm = 0.f, mx = -INFINITY;
        #pragma unroll
        for (int p = 0; p < 4; ++p) {
            sm += pfeat[(g * 4 + p) * 64 + c];
            mx = fmaxf(mx, pfeat[(g * 4 + p) * 64 + 32 + c]);
        }
        int cnt = gstart[g + 1] - gstart[g];
        gf[g * 64 + c] = (cnt > 0) ? sm / (float)cnt : 0.f;
        gf[g * 64 + 32 + c] = (cnt > 0) ? mx : 0.f;
    }
    __syncthreads();
    for (int i = tid; i < N_GRAPHS * OUT_C; i += 256) {
        int g = i >> 5, j = i & 31;
        float a = fcb1[j];
        for (int k = 0; k < 64; ++k) a = fmaf(gf[g * 64 + k], fcW1[k * OUT_C + j], a);
        t1[i] = a > 0.f ? a : 0.f;
    }
    __syncthreads();
    for (int i = tid; i < N_GRAPHS * OUT_C; i += 256) {
        int g = i >> 5, oc = i & 31;
        float a = fcb2[oc];
        for (int k = 0; k < OUT_C; ++k) a = fmaf(t1[g * OUT_C + k], fcW2[k * OUT_C + oc], a);
        out[(size_t)N_NODES * OUT_C + g * OUT_C + oc] = a;
    }
}

// =============== launch ===============

extern "C" void kernel_launch(void* const* d_in, const int* in_sizes, int n_in,
                              void* d_out, int out_size, void* d_ws, size_t ws_size,
                              hipStream_t stream) {
    (void)in_sizes; (void)n_in; (void)out_size; (void)ws_size;
    const float* x      = (const float*)d_in[0];
    const int*   ei     = (const int*)d_in[1];
    const int*   batch  = (const int*)d_in[2];
    const float* W1     = (const float*)d_in[3];
    const float* a_src1 = (const float*)d_in[4];
    const float* a_dst1 = (const float*)d_in[5];
    const float* b1     = (const float*)d_in[6];
    const float* g1     = (const float*)d_in[7];
    const float* be1    = (const float*)d_in[8];
    const float* W2     = (const float*)d_in[9];
    const float* a_src2 = (const float*)d_in[10];
    const float* a_dst2 = (const float*)d_in[11];
    const float* b2     = (const float*)d_in[12];
    const float* g2     = (const float*)d_in[13];
    const float* be2    = (const float*)d_in[14];
    const float* fcW1   = (const float*)d_in[15];
    const float* fcb1   = (const float*)d_in[16];
    const float* fcW2   = (const float*)d_in[17];
    const float* fcb2   = (const float*)d_in[18];
    const int* srcv = ei;
    const int* dstv = ei + N_EDGES;
    float* out = (float*)d_out;

    char* w = (char*)d_ws;
    size_t o = 0;
    #define ALLOC(nbytes) (w + o); o = (o + (size_t)(nbytes) + 15) & ~(size_t)15
    int*   gcur      = (int*)ALLOC(N_BUCKETS * 4);
    size_t zero_bytes = o;                       // only gcur needs pre-zero
    float* sp1       = (float*)ALLOC(64 * 128 * 4);   // zeroed by k_front misc
    float* sp2       = (float*)ALLOC(64 * 64 * 4);    // zeroed by k_front misc
    int2*  rowinfo   = (int2*)ALLOC((size_t)N_NODES * 8);
    int*   gst       = (int*)ALLOC(66 * 4);
    int*   col       = (int*)ALLOC(((size_t)N_BUCKETS * CAP_PAD + 256) * 4);
    unsigned* ebuf   = (unsigned*)ALLOC((size_t)N_BUCKETS * BUCKET_CAP * 4);
    unsigned short* xl1b = (unsigned short*)ALLOC((size_t)(N_NODES + 1) * HID * 2);
    float* esd1      = (float*)ALLOC((size_t)(N_NODES + 1) * 8 * 4);
    float* h1pre     = (float*)ALLOC((size_t)N_NODES * HID * 4);
    unsigned short* xl2b = (unsigned short*)ALLOC((size_t)(N_NODES + 1) * OUT_C * 2);
    float* esd2      = (float*)ALLOC((size_t)(N_NODES + 1) * 2 * 4);
    float* pfeat     = (float*)ALLOC(256 * 64 * 4);
    #undef ALLOC
    float* h2pre = h1pre;   // h1pre dead after k_gemm2

    hipMemsetAsync(d_ws, 0, zero_bytes, stream);
    k_front <<<BIN_NB + GEMM1_NB + 1, 256, 0, stream>>>(
        srcv, dstv, gcur, ebuf, x, W1, a_src1, a_dst1,
        xl1b, esd1, xl2b, esd2, batch, gst, sp1, sp2);
    k_csr   <<<N_BUCKETS, 256, 0, stream>>>(ebuf, gcur, rowinfo, col);
    k_agg1  <<<AGG_NB, 256, 0, stream>>>(
        xl1b, esd1, rowinfo, col, b1, h1pre, sp1);
    k_gemm2 <<<(N_TILES + 3) / 4, 256, 0, stream>>>(
        h1pre, sp1, g1, be1, W2, a_src2, a_dst2, xl2b, esd2);
    k_agg2  <<<AGG_NB, 256, 0, stream>>>(
        xl2b, esd2, rowinfo, col, b2, h2pre, sp2);
    k_bnpool<<<256, 256, 0, stream>>>(h2pre, sp2, g2, be2, gst, out, pfeat);
    k_mlp   <<<1, 256, 0, stream>>>(pfeat, gst, fcW1, fcb1, fcW2, fcb2, out);
}